// Round 2
// baseline (429.665 us; speedup 1.0000x reference)
//
#include <hip/hip_runtime.h>
#include <hip/hip_bf16.h>
#include <math.h>

#define B_   4
#define C_   128
#define H_   48
#define W_   48
#define HW_  2304
#define CG_  64
#define DH_  32
#define SCALE_ 0.17677669529663687f   // 32^-0.5

// d_out layout (floats)
#define Y_OFF   0
#define POS_OFF 1179648
#define REF_OFF 1216512

// workspace layout (floats)
#define WS_Q    0
#define WS_XT   1179648
#define WS_XS   2377728
#define WS_K    3557376
#define WS_V    4737024
#define WS_LEPE 5916672
#define WS_AOUT 7096320
// fp64 aliases (regions not live at the same time):
//   smapd (18432 doubles) sits in WS_AOUT region (written later by k_attn)
//   weff  (258 doubles)   sits in WS_LEPE region (written later by k_lepe)

// ---------------- transpose x (b,c,p) -> xT (b,p,c) ----------------
__global__ __launch_bounds__(256) void k_transpose(const float* __restrict__ x,
                                                   float* __restrict__ xT) {
  __shared__ float tile[64][65];
  int b = blockIdx.z, c0 = blockIdx.y * 64, p0 = blockIdx.x * 64;
  for (int idx = threadIdx.x; idx < 4096; idx += 256) {
    int cr = idx >> 6, pc = idx & 63;
    tile[cr][pc] = x[((size_t)(b * C_) + c0 + cr) * HW_ + p0 + pc];
  }
  __syncthreads();
  for (int idx = threadIdx.x; idx < 4096; idx += 256) {
    int pr = idx >> 6, cc = idx & 63;
    xT[((size_t)(b * HW_) + p0 + pr) * C_ + c0 + cc] = tile[cc][pr];
  }
}

// ---------------- 1x1 conv as SGEMM: O[b,o,m] = sum_i W[o,i] I[b,i,m] + bias[o]
__global__ __launch_bounds__(256) void k_conv1x1(const float* __restrict__ Wm,
                                                 const float* __restrict__ bias,
                                                 const float* __restrict__ I,
                                                 float* __restrict__ O) {
  __shared__ __align__(16) float As[64][68];  // [i][o]
  __shared__ __align__(16) float Bs[64][68];  // [i][m]
  int b = blockIdx.z;
  int o0 = blockIdx.y * 64;
  int m0 = blockIdx.x * 64;
  int t = threadIdx.x;
  int ty = t >> 4, tx = t & 15;
  float acc[4][4] = {{0.f}};
  for (int k0 = 0; k0 < 128; k0 += 64) {
    __syncthreads();
    for (int idx = t; idx < 4096; idx += 256) {
      int o = idx >> 6, i = idx & 63;
      As[i][o] = Wm[(size_t)(o0 + o) * C_ + k0 + i];
    }
    for (int idx = t; idx < 4096; idx += 256) {
      int i = idx >> 6, m = idx & 63;
      Bs[i][m] = I[((size_t)(b * C_) + k0 + i) * HW_ + m0 + m];
    }
    __syncthreads();
#pragma unroll 8
    for (int kk = 0; kk < 64; kk++) {
      float4 a  = *(const float4*)&As[kk][4 * ty];
      float4 bb = *(const float4*)&Bs[kk][4 * tx];
      acc[0][0] += a.x * bb.x; acc[0][1] += a.x * bb.y; acc[0][2] += a.x * bb.z; acc[0][3] += a.x * bb.w;
      acc[1][0] += a.y * bb.x; acc[1][1] += a.y * bb.y; acc[1][2] += a.y * bb.z; acc[1][3] += a.y * bb.w;
      acc[2][0] += a.z * bb.x; acc[2][1] += a.z * bb.y; acc[2][2] += a.z * bb.z; acc[2][3] += a.z * bb.w;
      acc[3][0] += a.w * bb.x; acc[3][1] += a.w * bb.y; acc[3][2] += a.w * bb.z; acc[3][3] += a.w * bb.w;
    }
  }
#pragma unroll
  for (int r = 0; r < 4; r++) {
    int o = o0 + 4 * ty + r;
    float bi = bias[o];
    float4 res = make_float4(acc[r][0] + bi, acc[r][1] + bi, acc[r][2] + bi, acc[r][3] + bi);
    *(float4*)&O[((size_t)(b * C_) + o) * HW_ + m0 + 4 * tx] = res;
  }
}

// ---------------- fold sobel 1x1 through q-proj (fp64, exact-enough) ----------------
__global__ void k_weff(const float* __restrict__ qW, const float* __restrict__ qb,
                       const float* __restrict__ sob_w, const float* __restrict__ sob_b,
                       double* __restrict__ weff) {
  int t = threadIdx.x;            // 0..255
  int g = t >> 7, i = t & 127;
  double acc = 0.0;
  for (int c = 0; c < 64; c++)
    acc += (double)sob_w[c] * (double)qW[(size_t)(g * 64 + c) * C_ + i];
  weff[t] = acc;
  if (t < 2) {
    double bb = (double)sob_b[0];
    for (int c = 0; c < 64; c++) bb += (double)sob_w[c] * (double)qb[t * 64 + c];
    weff[256 + t] = bb;
  }
}

// ---------------- sobel pre-projection s[bg,p] in fp64 ----------------
__global__ __launch_bounds__(256) void k_smapd(const float* __restrict__ x,
                                               const double* __restrict__ weff,
                                               double* __restrict__ smapd) {
  int p = blockIdx.x * 256 + threadIdx.x;
  int bg = blockIdx.y;
  int b = bg >> 1, g = bg & 1;
  const float* xb = x + (size_t)b * C_ * HW_ + p;
  const double* wv = weff + g * 128;
  double acc = weff[256 + g];
#pragma unroll 8
  for (int i = 0; i < 128; i++) acc += wv[i] * (double)xb[(size_t)i * HW_];
  smapd[bg * HW_ + p] = acc;
}

// ---------------- offset branch + sobel gate + pos/reference ----------------
__global__ __launch_bounds__(256) void k_offset_pos(const float* __restrict__ q,
                                                    const double* __restrict__ s_map,
                                                    const float* __restrict__ dw_w,
                                                    const float* __restrict__ dw_b,
                                                    const float* __restrict__ ln_g,
                                                    const float* __restrict__ ln_b,
                                                    const float* __restrict__ pw_w,
                                                    float* __restrict__ out) {
  int widx = blockIdx.x * 4 + (threadIdx.x >> 6);
  int lane = threadIdx.x & 63;
  int bg = widx / HW_;
  int p = widx - bg * HW_;
  int h = p / W_, w = p - h * W_;
  int b = bg >> 1, g = bg & 1;
  const float* qc = q + ((size_t)(b * C_ + g * CG_ + lane)) * HW_;
  // depthwise 3x3 (cross-correlation, zero pad)
  float tv = dw_b[lane];
#pragma unroll
  for (int dy = -1; dy <= 1; dy++)
#pragma unroll
    for (int dx = -1; dx <= 1; dx++) {
      int hh = h + dy, ww = w + dx;
      if (hh >= 0 && hh < H_ && ww >= 0 && ww < W_)
        tv += dw_w[lane * 9 + (dy + 1) * 3 + (dx + 1)] * qc[hh * W_ + ww];
    }
  // LayerNorm over 64 channels (lanes)
  float ssum = tv, ssq = tv * tv;
#pragma unroll
  for (int msk = 32; msk; msk >>= 1) {
    ssum += __shfl_xor(ssum, msk, 64);
    ssq  += __shfl_xor(ssq,  msk, 64);
  }
  float mu  = ssum * (1.0f / 64.0f);
  float var = ssq * (1.0f / 64.0f) - mu * mu;
  float uu  = (tv - mu) * rsqrtf(var + 1e-5f) * ln_g[lane] + ln_b[lane];
  // exact GELU
  float gl = 0.5f * uu * (1.0f + erff(uu * 0.70710678118654752f));
  // 1x1 -> 2 channels (no bias)
  float p0 = pw_w[lane] * gl, p1 = pw_w[64 + lane] * gl;
#pragma unroll
  for (int msk = 32; msk; msk >>= 1) {
    p0 += __shfl_xor(p0, msk, 64);
    p1 += __shfl_xor(p1, msk, 64);
  }
  if (lane == 0) {
    const double sobx[9] = {-1., 0., 1., -2., 0., 2., -1., 0., 1.};
    const double soby[9] = {-1., -2., -1., 0., 0., 0., 1., 2., 1.};
    float off_y = tanhf(p0) * (1.0f / 47.0f);
    float off_x = tanhf(p1) * (1.0f / 47.0f);
    const double* sm = s_map + bg * HW_;
    double gx = 0., gy = 0.;
#pragma unroll
    for (int dy = -1; dy <= 1; dy++)
#pragma unroll
      for (int dx = -1; dx <= 1; dx++) {
        int hh = h + dy, ww = w + dx;
        if (hh >= 0 && hh < H_ && ww >= 0 && ww < W_) {
          double sv = sm[hh * W_ + ww];
          gx += sobx[(dy + 1) * 3 + dx + 1] * sv;
          gy += soby[(dy + 1) * 3 + dx + 1] * sv;
        }
      }
    double mag = sqrt(gx * gx + gy * gy);
    float bin = mag > 0.5 ? 1.0f : 0.0f;
    float ry = ((h + 0.5f) / 47.0f) * 2.0f - 1.0f;
    float rx = ((w + 0.5f) / 47.0f) * 2.0f - 1.0f;
    int pi = (bg * HW_ + p) * 2;
    out[POS_OFF + pi]     = off_y + ry * bin;
    out[POS_OFF + pi + 1] = off_x + rx * bin;
    out[REF_OFF + pi]     = ry;
    out[REF_OFF + pi + 1] = rx;
  }
}

// ---------------- bilinear grid sample (align_corners=True, zero pad) ----------------
__global__ __launch_bounds__(256) void k_sample(const float* __restrict__ xT,
                                                const float* __restrict__ out,
                                                float* __restrict__ xs) {
  int widx = blockIdx.x * 4 + (threadIdx.x >> 6);
  int lane = threadIdx.x & 63;
  int bg = widx / HW_;
  int p = widx - bg * HW_;
  int b = bg >> 1, g = bg & 1;
  float py = out[POS_OFF + (bg * HW_ + p) * 2];
  float px = out[POS_OFF + (bg * HW_ + p) * 2 + 1];
  float gxf = (px + 1.0f) * 0.5f * 47.0f;
  float gyf = (py + 1.0f) * 0.5f * 47.0f;
  float x0 = floorf(gxf), y0 = floorf(gyf);
  float wx1 = gxf - x0, wy1 = gyf - y0;
  float wx0 = 1.0f - wx1, wy0 = 1.0f - wy1;
  const float* base = xT + (size_t)b * HW_ * C_ + g * CG_ + lane;
  float acc = 0.0f;
#pragma unroll
  for (int cy = 0; cy < 2; cy++)
#pragma unroll
    for (int cx = 0; cx < 2; cx++) {
      float yy = y0 + (float)cy, xx = x0 + (float)cx;
      bool valid = (yy >= 0.f) && (yy < 48.f) && (xx >= 0.f) && (xx < 48.f);
      int yc = min(max((int)yy, 0), 47);
      int xc = min(max((int)xx, 0), 47);
      float wgt = (cy ? wy1 : wy0) * (cx ? wx1 : wx0);
      float vv = valid ? base[(size_t)(yc * 48 + xc) * C_] : 0.0f;
      acc += wgt * vv;
    }
  xs[((size_t)(b * C_ + g * CG_ + lane)) * HW_ + p] = acc;
}

// ---------------- LEPE: depthwise 3x3 over q, all 128 channels ----------------
__global__ __launch_bounds__(256) void k_lepe(const float* __restrict__ q,
                                              const float* __restrict__ rpe_w,
                                              const float* __restrict__ rpe_b,
                                              float* __restrict__ lepe) {
  int idx = blockIdx.x * 256 + threadIdx.x;  // B*C*HW
  int p = idx % HW_;
  int bc = idx / HW_;
  int c = bc & (C_ - 1);
  int h = p / W_, w = p - h * W_;
  const float* qc = q + (size_t)bc * HW_;
  float acc = rpe_b[c];
#pragma unroll
  for (int dy = -1; dy <= 1; dy++)
#pragma unroll
    for (int dx = -1; dx <= 1; dx++) {
      int hh = h + dy, ww = w + dx;
      if (hh >= 0 && hh < H_ && ww >= 0 && ww < W_)
        acc += rpe_w[c * 9 + (dy + 1) * 3 + (dx + 1)] * qc[hh * W_ + ww];
    }
  lepe[idx] = acc;
}

// ---------------- flash attention fp32, 64 m-rows per block ----------------
__global__ __launch_bounds__(256) void k_attn(const float* __restrict__ q,
                                              const float* __restrict__ kk_,
                                              const float* __restrict__ vv_,
                                              const float* __restrict__ lepe,
                                              float* __restrict__ aout) {
  __shared__ __align__(16) float qs[32][68];    // [c][m]
  __shared__ __align__(16) float ks[32][68];    // [c][n]
  __shared__ __align__(16) float vsT[64][68];   // [n][c]
  __shared__ __align__(16) float ps[64][68];    // [n][m] (P transposed)
  __shared__ float rowsum[64];
  int bh = blockIdx.y;
  int b = bh >> 2, hd = bh & 3;
  int m0 = blockIdx.x * 64;
  const float* qbase = q   + ((size_t)(b * C_ + hd * DH_)) * HW_;
  const float* kbase = kk_ + ((size_t)(b * C_ + hd * DH_)) * HW_;
  const float* vbase = vv_ + ((size_t)(b * C_ + hd * DH_)) * HW_;
  int t = threadIdx.x;
  int ty = t >> 4, tx = t & 15;
  for (int idx = t; idx < 2048; idx += 256) {
    int c = idx >> 6, mm = idx & 63;
    qs[c][mm] = qbase[(size_t)c * HW_ + m0 + mm] * SCALE_;
  }
  if (t < 64) rowsum[t] = 0.0f;
  float oacc[4][2] = {{0.f}};
  for (int n0 = 0; n0 < HW_; n0 += 64) {
    __syncthreads();
    for (int idx = t; idx < 2048; idx += 256) {
      int c = idx >> 6, nn = idx & 63;
      float kvv = kbase[(size_t)c * HW_ + n0 + nn];
      float vvv = vbase[(size_t)c * HW_ + n0 + nn];
      ks[c][nn] = kvv;
      vsT[nn][c] = vvv;
    }
    __syncthreads();
    float s4[4][4] = {{0.f}};
#pragma unroll 4
    for (int kd = 0; kd < 32; kd++) {
      float4 a  = *(const float4*)&qs[kd][4 * ty];
      float4 bq = *(const float4*)&ks[kd][4 * tx];
      s4[0][0] += a.x * bq.x; s4[0][1] += a.x * bq.y; s4[0][2] += a.x * bq.z; s4[0][3] += a.x * bq.w;
      s4[1][0] += a.y * bq.x; s4[1][1] += a.y * bq.y; s4[1][2] += a.y * bq.z; s4[1][3] += a.y * bq.w;
      s4[2][0] += a.z * bq.x; s4[2][1] += a.z * bq.y; s4[2][2] += a.z * bq.z; s4[2][3] += a.z * bq.w;
      s4[3][0] += a.w * bq.x; s4[3][1] += a.w * bq.y; s4[3][2] += a.w * bq.z; s4[3][3] += a.w * bq.w;
    }
    // exp (logits bounded ~|0.3|, no max-subtraction needed)
#pragma unroll
    for (int r = 0; r < 4; r++)
#pragma unroll
      for (int s_ = 0; s_ < 4; s_++) s4[r][s_] = __expf(s4[r][s_]);
    // write P transposed: ps[n][m]
#pragma unroll
    for (int s_ = 0; s_ < 4; s_++) {
      float4 col = make_float4(s4[0][s_], s4[1][s_], s4[2][s_], s4[3][s_]);
      *(float4*)&ps[4 * tx + s_][4 * ty] = col;
    }
    // row sums (reduce over tx = low 4 lane bits)
#pragma unroll
    for (int r = 0; r < 4; r++) {
      float rs = s4[r][0] + s4[r][1] + s4[r][2] + s4[r][3];
      rs += __shfl_xor(rs, 1, 64);
      rs += __shfl_xor(rs, 2, 64);
      rs += __shfl_xor(rs, 4, 64);
      rs += __shfl_xor(rs, 8, 64);
      if (tx == 0) rowsum[4 * ty + r] += rs;
    }
    __syncthreads();
    // PV: out[m=4*ty+r][c=2*tx+cc] += sum_n P[m][n] * v[c][n]
#pragma unroll 8
    for (int nn = 0; nn < 64; nn++) {
      float4 pv  = *(const float4*)&ps[nn][4 * ty];
      float2 vv2 = *(const float2*)&vsT[nn][2 * tx];
      oacc[0][0] += pv.x * vv2.x; oacc[0][1] += pv.x * vv2.y;
      oacc[1][0] += pv.y * vv2.x; oacc[1][1] += pv.y * vv2.y;
      oacc[2][0] += pv.z * vv2.x; oacc[2][1] += pv.z * vv2.y;
      oacc[3][0] += pv.w * vv2.x; oacc[3][1] += pv.w * vv2.y;
    }
  }
  __syncthreads();
#pragma unroll
  for (int r = 0; r < 4; r++) {
    int m = m0 + 4 * ty + r;
    float inv = 1.0f / rowsum[4 * ty + r];
#pragma unroll
    for (int cc2 = 0; cc2 < 2; cc2++) {
      int c = 2 * tx + cc2;
      size_t oi = ((size_t)(b * C_ + hd * DH_ + c)) * HW_ + m;
      aout[oi] = oacc[r][cc2] * inv + lepe[oi];
    }
  }
}

extern "C" void kernel_launch(void* const* d_in, const int* in_sizes, int n_in,
                              void* d_out, int out_size, void* d_ws, size_t ws_size,
                              hipStream_t stream) {
  const float* x        = (const float*)d_in[0];
  const float* qW       = (const float*)d_in[1];
  const float* qb       = (const float*)d_in[2];
  const float* kW       = (const float*)d_in[3];
  const float* kb       = (const float*)d_in[4];
  const float* vW       = (const float*)d_in[5];
  const float* vb       = (const float*)d_in[6];
  const float* oW       = (const float*)d_in[7];
  const float* ob       = (const float*)d_in[8];
  const float* off_dw_w = (const float*)d_in[9];
  const float* off_dw_b = (const float*)d_in[10];
  const float* ln_g     = (const float*)d_in[11];
  const float* ln_b     = (const float*)d_in[12];
  const float* off_pw_w = (const float*)d_in[13];
  const float* sob_w    = (const float*)d_in[14];
  const float* sob_b    = (const float*)d_in[15];
  const float* rpe_w    = (const float*)d_in[16];
  const float* rpe_b    = (const float*)d_in[17];
  float* out = (float*)d_out;
  float* wsf = (float*)d_ws;
  float* q    = wsf + WS_Q;
  float* xT   = wsf + WS_XT;
  float* xs   = wsf + WS_XS;
  float* kbuf = wsf + WS_K;
  float* vbuf = wsf + WS_V;
  float* lep  = wsf + WS_LEPE;
  float* aoutb= wsf + WS_AOUT;
  double* weff  = (double*)(wsf + WS_LEPE);   // 258 doubles, dead before k_lepe writes
  double* smapd = (double*)(wsf + WS_AOUT);   // 18432 doubles, dead before k_attn writes

  k_transpose<<<dim3(36, 2, 4), 256, 0, stream>>>(x, xT);
  k_conv1x1 <<<dim3(36, 2, 4), 256, 0, stream>>>(qW, qb, x, q);
  k_weff    <<<1,              256, 0, stream>>>(qW, qb, sob_w, sob_b, weff);
  k_smapd   <<<dim3(9, 8),     256, 0, stream>>>(x, weff, smapd);
  k_offset_pos<<<4608,         256, 0, stream>>>(q, smapd, off_dw_w, off_dw_b,
                                                 ln_g, ln_b, off_pw_w, out);
  k_sample  <<<4608,           256, 0, stream>>>(xT, out, xs);
  k_conv1x1 <<<dim3(36, 2, 4), 256, 0, stream>>>(kW, kb, xs, kbuf);
  k_conv1x1 <<<dim3(36, 2, 4), 256, 0, stream>>>(vW, vb, xs, vbuf);
  k_lepe    <<<4608,           256, 0, stream>>>(q, rpe_w, rpe_b, lep);
  k_attn    <<<dim3(36, 16),   256, 0, stream>>>(q, kbuf, vbuf, lep, aoutb);
  k_conv1x1 <<<dim3(36, 2, 4), 256, 0, stream>>>(oW, ob, aoutb, out + Y_OFF);
}

// Round 3
// 253.478 us; speedup vs baseline: 1.6951x; 1.6951x over previous
//
#include <hip/hip_runtime.h>
#include <hip/hip_bf16.h>
#include <math.h>

#define B_   4
#define C_   128
#define H_   48
#define W_   48
#define HW_  2304
#define CG_  64
#define DH_  32
#define SCALE_ 0.17677669529663687f   // 32^-0.5

// d_out layout (floats)
#define Y_OFF   0
#define POS_OFF 1179648
#define REF_OFF 1216512

// workspace layout (float offsets)
#define WS_Q    0
#define WS_XT   1179648   // xT fp32 (dead after k_sample); vbf (ushort) aliased here after
#define WS_XS   2377728
#define WS_K    3557376   // qbf ushort (589824 floats worth)
#define WS_V    4737024   // kbf ushort
#define WS_LEPE 5916672   // weff doubles (early, dead) then lepe fp32
#define WS_AOUT 7096320   // smapd doubles (early, dead) then aout fp32

typedef __attribute__((ext_vector_type(8))) short short8;
typedef __attribute__((ext_vector_type(4))) float f32x4;

__device__ inline unsigned short f2bf(float f) {
  unsigned u = __float_as_uint(f);
  u += 0x7fff + ((u >> 16) & 1);     // RNE
  return (unsigned short)(u >> 16);
}

// ---------------- transpose x (b,c,p) -> xT (b,p,c) ----------------
__global__ __launch_bounds__(256) void k_transpose(const float* __restrict__ x,
                                                   float* __restrict__ xT) {
  __shared__ float tile[64][65];
  int b = blockIdx.z, c0 = blockIdx.y * 64, p0 = blockIdx.x * 64;
  for (int idx = threadIdx.x; idx < 4096; idx += 256) {
    int cr = idx >> 6, pc = idx & 63;
    tile[cr][pc] = x[((size_t)(b * C_) + c0 + cr) * HW_ + p0 + pc];
  }
  __syncthreads();
  for (int idx = threadIdx.x; idx < 4096; idx += 256) {
    int pr = idx >> 6, cc = idx & 63;
    xT[((size_t)(b * HW_) + p0 + pr) * C_ + c0 + cc] = tile[cc][pr];
  }
}

// ---------------- 1x1 conv as SGEMM with optional bf16 side outputs ----------------
// WF32: write O fp32 [b][o][m]; WBFT: write Obf bf16 [b][m][o]*bscale;
// WBFN: write Obf bf16 [b][o][m]*bscale
template<int WF32, int WBFT, int WBFN>
__global__ __launch_bounds__(256) void k_conv1x1(const float* __restrict__ Wm,
                                                 const float* __restrict__ bias,
                                                 const float* __restrict__ I,
                                                 float* __restrict__ O,
                                                 unsigned short* __restrict__ Obf,
                                                 float bscale) {
  __shared__ __align__(16) float As[64][68];  // [i][o]
  __shared__ __align__(16) float Bs[64][68];  // [i][m]
  int b = blockIdx.z;
  int o0 = blockIdx.y * 64;
  int m0 = blockIdx.x * 64;
  int t = threadIdx.x;
  int ty = t >> 4, tx = t & 15;
  float acc[4][4] = {{0.f}};
  for (int k0 = 0; k0 < 128; k0 += 64) {
    __syncthreads();
    for (int idx = t; idx < 4096; idx += 256) {
      int o = idx >> 6, i = idx & 63;
      As[i][o] = Wm[(size_t)(o0 + o) * C_ + k0 + i];
    }
    for (int idx = t; idx < 4096; idx += 256) {
      int i = idx >> 6, m = idx & 63;
      Bs[i][m] = I[((size_t)(b * C_) + k0 + i) * HW_ + m0 + m];
    }
    __syncthreads();
#pragma unroll 8
    for (int kk = 0; kk < 64; kk++) {
      float4 a  = *(const float4*)&As[kk][4 * ty];
      float4 bb = *(const float4*)&Bs[kk][4 * tx];
      acc[0][0] += a.x * bb.x; acc[0][1] += a.x * bb.y; acc[0][2] += a.x * bb.z; acc[0][3] += a.x * bb.w;
      acc[1][0] += a.y * bb.x; acc[1][1] += a.y * bb.y; acc[1][2] += a.y * bb.z; acc[1][3] += a.y * bb.w;
      acc[2][0] += a.z * bb.x; acc[2][1] += a.z * bb.y; acc[2][2] += a.z * bb.z; acc[2][3] += a.z * bb.w;
      acc[3][0] += a.w * bb.x; acc[3][1] += a.w * bb.y; acc[3][2] += a.w * bb.z; acc[3][3] += a.w * bb.w;
    }
  }
#pragma unroll
  for (int r = 0; r < 4; r++) {
    float bi = bias[o0 + 4 * ty + r];
#pragma unroll
    for (int cc = 0; cc < 4; cc++) acc[r][cc] += bi;
  }
  if (WF32) {
#pragma unroll
    for (int r = 0; r < 4; r++) {
      int o = o0 + 4 * ty + r;
      float4 res = make_float4(acc[r][0], acc[r][1], acc[r][2], acc[r][3]);
      *(float4*)&O[((size_t)(b * C_) + o) * HW_ + m0 + 4 * tx] = res;
    }
  }
  if (WBFT) {
#pragma unroll
    for (int cc = 0; cc < 4; cc++) {
      int m = m0 + 4 * tx + cc;
      ushort4 pk = make_ushort4(f2bf(acc[0][cc] * bscale), f2bf(acc[1][cc] * bscale),
                                f2bf(acc[2][cc] * bscale), f2bf(acc[3][cc] * bscale));
      *(ushort4*)&Obf[((size_t)(b * HW_) + m) * C_ + o0 + 4 * ty] = pk;
    }
  }
  if (WBFN) {
#pragma unroll
    for (int r = 0; r < 4; r++) {
      int o = o0 + 4 * ty + r;
      ushort4 pk = make_ushort4(f2bf(acc[r][0] * bscale), f2bf(acc[r][1] * bscale),
                                f2bf(acc[r][2] * bscale), f2bf(acc[r][3] * bscale));
      *(ushort4*)&Obf[((size_t)(b * C_) + o) * HW_ + m0 + 4 * tx] = pk;
    }
  }
}

// ---------------- fold sobel 1x1 through q-proj (fp64) ----------------
__global__ void k_weff(const float* __restrict__ qW, const float* __restrict__ qb,
                       const float* __restrict__ sob_w, const float* __restrict__ sob_b,
                       double* __restrict__ weff) {
  int t = threadIdx.x;            // 0..255
  int g = t >> 7, i = t & 127;
  double acc = 0.0;
  for (int c = 0; c < 64; c++)
    acc += (double)sob_w[c] * (double)qW[(size_t)(g * 64 + c) * C_ + i];
  weff[t] = acc;
  if (t < 2) {
    double bb = (double)sob_b[0];
    for (int c = 0; c < 64; c++) bb += (double)sob_w[c] * (double)qb[t * 64 + c];
    weff[256 + t] = bb;
  }
}

// ---------------- sobel pre-projection s[bg,p] in fp64 ----------------
__global__ __launch_bounds__(256) void k_smapd(const float* __restrict__ x,
                                               const double* __restrict__ weff,
                                               double* __restrict__ smapd) {
  int p = blockIdx.x * 256 + threadIdx.x;
  int bg = blockIdx.y;
  int b = bg >> 1, g = bg & 1;
  const float* xb = x + (size_t)b * C_ * HW_ + p;
  const double* wv = weff + g * 128;
  double acc = weff[256 + g];
#pragma unroll 8
  for (int i = 0; i < 128; i++) acc += wv[i] * (double)xb[(size_t)i * HW_];
  smapd[bg * HW_ + p] = acc;
}

// ---------------- offset branch + sobel gate + pos/reference ----------------
__global__ __launch_bounds__(256) void k_offset_pos(const float* __restrict__ q,
                                                    const double* __restrict__ s_map,
                                                    const float* __restrict__ dw_w,
                                                    const float* __restrict__ dw_b,
                                                    const float* __restrict__ ln_g,
                                                    const float* __restrict__ ln_b,
                                                    const float* __restrict__ pw_w,
                                                    float* __restrict__ out) {
  int widx = blockIdx.x * 4 + (threadIdx.x >> 6);
  int lane = threadIdx.x & 63;
  int bg = widx / HW_;
  int p = widx - bg * HW_;
  int h = p / W_, w = p - h * W_;
  int b = bg >> 1, g = bg & 1;
  const float* qc = q + ((size_t)(b * C_ + g * CG_ + lane)) * HW_;
  float tv = dw_b[lane];
#pragma unroll
  for (int dy = -1; dy <= 1; dy++)
#pragma unroll
    for (int dx = -1; dx <= 1; dx++) {
      int hh = h + dy, ww = w + dx;
      if (hh >= 0 && hh < H_ && ww >= 0 && ww < W_)
        tv += dw_w[lane * 9 + (dy + 1) * 3 + (dx + 1)] * qc[hh * W_ + ww];
    }
  float ssum = tv, ssq = tv * tv;
#pragma unroll
  for (int msk = 32; msk; msk >>= 1) {
    ssum += __shfl_xor(ssum, msk, 64);
    ssq  += __shfl_xor(ssq,  msk, 64);
  }
  float mu  = ssum * (1.0f / 64.0f);
  float var = ssq * (1.0f / 64.0f) - mu * mu;
  float uu  = (tv - mu) * rsqrtf(var + 1e-5f) * ln_g[lane] + ln_b[lane];
  float gl = 0.5f * uu * (1.0f + erff(uu * 0.70710678118654752f));
  float p0 = pw_w[lane] * gl, p1 = pw_w[64 + lane] * gl;
#pragma unroll
  for (int msk = 32; msk; msk >>= 1) {
    p0 += __shfl_xor(p0, msk, 64);
    p1 += __shfl_xor(p1, msk, 64);
  }
  if (lane == 0) {
    const double sobx[9] = {-1., 0., 1., -2., 0., 2., -1., 0., 1.};
    const double soby[9] = {-1., -2., -1., 0., 0., 0., 1., 2., 1.};
    float off_y = tanhf(p0) * (1.0f / 47.0f);
    float off_x = tanhf(p1) * (1.0f / 47.0f);
    const double* sm = s_map + bg * HW_;
    double gx = 0., gy = 0.;
#pragma unroll
    for (int dy = -1; dy <= 1; dy++)
#pragma unroll
      for (int dx = -1; dx <= 1; dx++) {
        int hh = h + dy, ww = w + dx;
        if (hh >= 0 && hh < H_ && ww >= 0 && ww < W_) {
          double sv = sm[hh * W_ + ww];
          gx += sobx[(dy + 1) * 3 + dx + 1] * sv;
          gy += soby[(dy + 1) * 3 + dx + 1] * sv;
        }
      }
    double mag = sqrt(gx * gx + gy * gy);
    float bin = mag > 0.5 ? 1.0f : 0.0f;
    float ry = ((h + 0.5f) / 47.0f) * 2.0f - 1.0f;
    float rx = ((w + 0.5f) / 47.0f) * 2.0f - 1.0f;
    int pi = (bg * HW_ + p) * 2;
    out[POS_OFF + pi]     = off_y + ry * bin;
    out[POS_OFF + pi + 1] = off_x + rx * bin;
    out[REF_OFF + pi]     = ry;
    out[REF_OFF + pi + 1] = rx;
  }
}

// ---------------- bilinear grid sample ----------------
__global__ __launch_bounds__(256) void k_sample(const float* __restrict__ xT,
                                                const float* __restrict__ out,
                                                float* __restrict__ xs) {
  int widx = blockIdx.x * 4 + (threadIdx.x >> 6);
  int lane = threadIdx.x & 63;
  int bg = widx / HW_;
  int p = widx - bg * HW_;
  int b = bg >> 1, g = bg & 1;
  float py = out[POS_OFF + (bg * HW_ + p) * 2];
  float px = out[POS_OFF + (bg * HW_ + p) * 2 + 1];
  float gxf = (px + 1.0f) * 0.5f * 47.0f;
  float gyf = (py + 1.0f) * 0.5f * 47.0f;
  float x0 = floorf(gxf), y0 = floorf(gyf);
  float wx1 = gxf - x0, wy1 = gyf - y0;
  float wx0 = 1.0f - wx1, wy0 = 1.0f - wy1;
  const float* base = xT + (size_t)b * HW_ * C_ + g * CG_ + lane;
  float acc = 0.0f;
#pragma unroll
  for (int cy = 0; cy < 2; cy++)
#pragma unroll
    for (int cx = 0; cx < 2; cx++) {
      float yy = y0 + (float)cy, xx = x0 + (float)cx;
      bool valid = (yy >= 0.f) && (yy < 48.f) && (xx >= 0.f) && (xx < 48.f);
      int yc = min(max((int)yy, 0), 47);
      int xc = min(max((int)xx, 0), 47);
      float wgt = (cy ? wy1 : wy0) * (cx ? wx1 : wx0);
      float vv = valid ? base[(size_t)(yc * 48 + xc) * C_] : 0.0f;
      acc += wgt * vv;
    }
  xs[((size_t)(b * C_ + g * CG_ + lane)) * HW_ + p] = acc;
}

// ---------------- LEPE: depthwise 3x3 over q ----------------
__global__ __launch_bounds__(256) void k_lepe(const float* __restrict__ q,
                                              const float* __restrict__ rpe_w,
                                              const float* __restrict__ rpe_b,
                                              float* __restrict__ lepe) {
  int idx = blockIdx.x * 256 + threadIdx.x;
  int p = idx % HW_;
  int bc = idx / HW_;
  int c = bc & (C_ - 1);
  int h = p / W_, w = p - h * W_;
  const float* qc = q + (size_t)bc * HW_;
  float acc = rpe_b[c];
#pragma unroll
  for (int dy = -1; dy <= 1; dy++)
#pragma unroll
    for (int dx = -1; dx <= 1; dx++) {
      int hh = h + dy, ww = w + dx;
      if (hh >= 0 && hh < H_ && ww >= 0 && ww < W_)
        acc += rpe_w[c * 9 + (dy + 1) * 3 + (dx + 1)] * qc[hh * W_ + ww];
    }
  lepe[idx] = acc;
}

// ---------------- MFMA flash attention ----------------
// qbf [b][m][128] (scaled), kbf [b][n][128], vbf [b][c128][2304]; all bf16.
// Block: 4 waves, each wave owns 16 m-rows; no inter-wave sharing.
__global__ __launch_bounds__(256) void k_attn_mfma(const unsigned short* __restrict__ qbf,
                                                   const unsigned short* __restrict__ kbf,
                                                   const unsigned short* __restrict__ vbf,
                                                   const float* __restrict__ lepe,
                                                   float* __restrict__ aout) {
  __shared__ __align__(16) unsigned short Ps[4][16][72];   // per-wave P tile [m16][n64]
  int t = threadIdx.x;
  int w = t >> 6, l = t & 63;
  int lg = l >> 4, lo = l & 15;
  int bh = blockIdx.y, b = bh >> 2, hd = bh & 3;
  int cb = hd * 32;
  int m0 = blockIdx.x * 64 + w * 16;
  // Q fragment: A[row=lo][k=lg*8+i], one 16B load
  short8 aq = *(const short8*)(qbf + ((size_t)(b * HW_) + m0 + lo) * C_ + cb + lg * 8);
  const unsigned short* kb_ = kbf + (size_t)b * HW_ * C_ + cb + lg * 8;
  const unsigned short* vb_ = vbf + ((size_t)(b * C_) + cb + lo) * HW_ + lg * 8;
  f32x4 acc0 = {0.f, 0.f, 0.f, 0.f}, acc1 = {0.f, 0.f, 0.f, 0.f};
  float racc[4] = {0.f, 0.f, 0.f, 0.f};
  for (int n0 = 0; n0 < HW_; n0 += 64) {
    f32x4 s[4];
#pragma unroll
    for (int sub = 0; sub < 4; sub++) {
      short8 bk = *(const short8*)(kb_ + (size_t)(n0 + sub * 16 + lo) * C_);
      f32x4 z = {0.f, 0.f, 0.f, 0.f};
      s[sub] = __builtin_amdgcn_mfma_f32_16x16x32_bf16(aq, bk, z, 0, 0, 0);
    }
#pragma unroll
    for (int sub = 0; sub < 4; sub++)
#pragma unroll
      for (int r = 0; r < 4; r++) {
        float e = __expf(s[sub][r]);
        s[sub][r] = e;
        Ps[w][lg * 4 + r][sub * 16 + lo] = f2bf(e);
      }
#pragma unroll
    for (int r = 0; r < 4; r++) {
      float rs = s[0][r] + s[1][r] + s[2][r] + s[3][r];
      rs += __shfl_xor(rs, 1, 64);
      rs += __shfl_xor(rs, 2, 64);
      rs += __shfl_xor(rs, 4, 64);
      rs += __shfl_xor(rs, 8, 64);
      racc[r] += rs;
    }
#pragma unroll
    for (int ks = 0; ks < 2; ks++) {
      short8 pa  = *(const short8*)&Ps[w][lo][ks * 32 + lg * 8];
      short8 bv0 = *(const short8*)(vb_ + n0 + ks * 32);
      short8 bv1 = *(const short8*)(vb_ + (size_t)16 * HW_ + n0 + ks * 32);
      acc0 = __builtin_amdgcn_mfma_f32_16x16x32_bf16(pa, bv0, acc0, 0, 0, 0);
      acc1 = __builtin_amdgcn_mfma_f32_16x16x32_bf16(pa, bv1, acc1, 0, 0, 0);
    }
  }
#pragma unroll
  for (int r = 0; r < 4; r++) {
    float inv = 1.0f / racc[r];
    int m = m0 + lg * 4 + r;
    size_t o0i = ((size_t)(b * C_ + cb + lo)) * HW_ + m;
    size_t o1i = o0i + (size_t)16 * HW_;
    aout[o0i] = acc0[r] * inv + lepe[o0i];
    aout[o1i] = acc1[r] * inv + lepe[o1i];
  }
}

extern "C" void kernel_launch(void* const* d_in, const int* in_sizes, int n_in,
                              void* d_out, int out_size, void* d_ws, size_t ws_size,
                              hipStream_t stream) {
  const float* x        = (const float*)d_in[0];
  const float* qW       = (const float*)d_in[1];
  const float* qb       = (const float*)d_in[2];
  const float* kW       = (const float*)d_in[3];
  const float* kb       = (const float*)d_in[4];
  const float* vW       = (const float*)d_in[5];
  const float* vb       = (const float*)d_in[6];
  const float* oW       = (const float*)d_in[7];
  const float* ob       = (const float*)d_in[8];
  const float* off_dw_w = (const float*)d_in[9];
  const float* off_dw_b = (const float*)d_in[10];
  const float* ln_g     = (const float*)d_in[11];
  const float* ln_b     = (const float*)d_in[12];
  const float* off_pw_w = (const float*)d_in[13];
  const float* sob_w    = (const float*)d_in[14];
  const float* sob_b    = (const float*)d_in[15];
  const float* rpe_w    = (const float*)d_in[16];
  const float* rpe_b    = (const float*)d_in[17];
  float* out = (float*)d_out;
  float* wsf = (float*)d_ws;
  float* q    = wsf + WS_Q;
  float* xT   = wsf + WS_XT;
  float* xs   = wsf + WS_XS;
  float* lep  = wsf + WS_LEPE;
  float* aoutb= wsf + WS_AOUT;
  unsigned short* qbf = (unsigned short*)(wsf + WS_K);
  unsigned short* kbf = (unsigned short*)(wsf + WS_V);
  unsigned short* vbf = (unsigned short*)(wsf + WS_XT);  // xT dead after k_sample
  double* weff  = (double*)(wsf + WS_LEPE);  // dead before k_lepe
  double* smapd = (double*)(wsf + WS_AOUT);  // dead before k_attn_mfma

  k_transpose<<<dim3(36, 2, 4), 256, 0, stream>>>(x, xT);
  k_conv1x1<1,1,0><<<dim3(36, 2, 4), 256, 0, stream>>>(qW, qb, x, q, qbf, SCALE_);
  k_weff    <<<1,              256, 0, stream>>>(qW, qb, sob_w, sob_b, weff);
  k_smapd   <<<dim3(9, 8),     256, 0, stream>>>(x, weff, smapd);
  k_offset_pos<<<4608,         256, 0, stream>>>(q, smapd, off_dw_w, off_dw_b,
                                                 ln_g, ln_b, off_pw_w, out);
  k_sample  <<<4608,           256, 0, stream>>>(xT, out, xs);
  k_conv1x1<0,1,0><<<dim3(36, 2, 4), 256, 0, stream>>>(kW, kb, xs, nullptr, kbf, 1.0f);
  k_conv1x1<0,0,1><<<dim3(36, 2, 4), 256, 0, stream>>>(vW, vb, xs, nullptr, vbf, 1.0f);
  k_lepe    <<<4608,           256, 0, stream>>>(q, rpe_w, rpe_b, lep);
  k_attn_mfma<<<dim3(36, 16),  256, 0, stream>>>(qbf, kbf, vbf, lep, aoutb);
  k_conv1x1<1,0,0><<<dim3(36, 2, 4), 256, 0, stream>>>(oW, ob, aoutb, out + Y_OFF, nullptr, 1.0f);
}

// Round 4
// 242.755 us; speedup vs baseline: 1.7700x; 1.0442x over previous
//
#include <hip/hip_runtime.h>
#include <hip/hip_bf16.h>
#include <math.h>

#define B_   4
#define C_   128
#define H_   48
#define W_   48
#define HW_  2304
#define CG_  64
#define DH_  32
#define SCALE_ 0.17677669529663687f   // 32^-0.5

// d_out layout (floats)
#define Y_OFF   0
#define POS_OFF 1179648
#define REF_OFF 1216512

// workspace layout (float offsets)
#define WS_Q    0         // q fp32 (dead after k_lepe) -> prO1 for attn
#define WS_XT   1179648   // xT fp32 (dead after k_sample) -> vbf ushort
#define WS_XS   2377728   // xs fp32 (dead after k/v conv) -> prS
#define WS_K    3557376   // qbf ushort
#define WS_V    4737024   // kbf ushort
#define WS_LEPE 5916672   // weff doubles (early, dead) then lepe fp32
#define WS_AOUT 7096320   // smapd doubles (early, dead) then prO0 / aout fp32

typedef __attribute__((ext_vector_type(8))) short short8;
typedef __attribute__((ext_vector_type(4))) float f32x4;

__device__ inline unsigned short f2bf(float f) {
  unsigned u = __float_as_uint(f);
  u += 0x7fff + ((u >> 16) & 1);     // RNE
  return (unsigned short)(u >> 16);
}

// ---------------- transpose x (b,c,p) -> xT (b,p,c) ----------------
__global__ __launch_bounds__(256) void k_transpose(const float* __restrict__ x,
                                                   float* __restrict__ xT) {
  __shared__ float tile[64][65];
  int b = blockIdx.z, c0 = blockIdx.y * 64, p0 = blockIdx.x * 64;
  for (int idx = threadIdx.x; idx < 4096; idx += 256) {
    int cr = idx >> 6, pc = idx & 63;
    tile[cr][pc] = x[((size_t)(b * C_) + c0 + cr) * HW_ + p0 + pc];
  }
  __syncthreads();
  for (int idx = threadIdx.x; idx < 4096; idx += 256) {
    int pr = idx >> 6, cc = idx & 63;
    xT[((size_t)(b * HW_) + p0 + pr) * C_ + c0 + cc] = tile[cc][pr];
  }
}

// ---------------- 1x1 conv as SGEMM with optional bf16 side outputs ----------------
template<int WF32, int WBFT, int WBFN>
__global__ __launch_bounds__(256) void k_conv1x1(const float* __restrict__ Wm,
                                                 const float* __restrict__ bias,
                                                 const float* __restrict__ I,
                                                 float* __restrict__ O,
                                                 unsigned short* __restrict__ Obf,
                                                 float bscale) {
  __shared__ __align__(16) float As[64][68];  // [i][o]
  __shared__ __align__(16) float Bs[64][68];  // [i][m]
  int b = blockIdx.z;
  int o0 = blockIdx.y * 64;
  int m0 = blockIdx.x * 64;
  int t = threadIdx.x;
  int ty = t >> 4, tx = t & 15;
  float acc[4][4] = {{0.f}};
  for (int k0 = 0; k0 < 128; k0 += 64) {
    __syncthreads();
    for (int idx = t; idx < 4096; idx += 256) {
      int o = idx >> 6, i = idx & 63;
      As[i][o] = Wm[(size_t)(o0 + o) * C_ + k0 + i];
    }
    for (int idx = t; idx < 4096; idx += 256) {
      int i = idx >> 6, m = idx & 63;
      Bs[i][m] = I[((size_t)(b * C_) + k0 + i) * HW_ + m0 + m];
    }
    __syncthreads();
#pragma unroll 8
    for (int kk = 0; kk < 64; kk++) {
      float4 a  = *(const float4*)&As[kk][4 * ty];
      float4 bb = *(const float4*)&Bs[kk][4 * tx];
      acc[0][0] += a.x * bb.x; acc[0][1] += a.x * bb.y; acc[0][2] += a.x * bb.z; acc[0][3] += a.x * bb.w;
      acc[1][0] += a.y * bb.x; acc[1][1] += a.y * bb.y; acc[1][2] += a.y * bb.z; acc[1][3] += a.y * bb.w;
      acc[2][0] += a.z * bb.x; acc[2][1] += a.z * bb.y; acc[2][2] += a.z * bb.z; acc[2][3] += a.z * bb.w;
      acc[3][0] += a.w * bb.x; acc[3][1] += a.w * bb.y; acc[3][2] += a.w * bb.z; acc[3][3] += a.w * bb.w;
    }
  }
#pragma unroll
  for (int r = 0; r < 4; r++) {
    float bi = bias[o0 + 4 * ty + r];
#pragma unroll
    for (int cc = 0; cc < 4; cc++) acc[r][cc] += bi;
  }
  if (WF32) {
#pragma unroll
    for (int r = 0; r < 4; r++) {
      int o = o0 + 4 * ty + r;
      float4 res = make_float4(acc[r][0], acc[r][1], acc[r][2], acc[r][3]);
      *(float4*)&O[((size_t)(b * C_) + o) * HW_ + m0 + 4 * tx] = res;
    }
  }
  if (WBFT) {
#pragma unroll
    for (int cc = 0; cc < 4; cc++) {
      int m = m0 + 4 * tx + cc;
      ushort4 pk = make_ushort4(f2bf(acc[0][cc] * bscale), f2bf(acc[1][cc] * bscale),
                                f2bf(acc[2][cc] * bscale), f2bf(acc[3][cc] * bscale));
      *(ushort4*)&Obf[((size_t)(b * HW_) + m) * C_ + o0 + 4 * ty] = pk;
    }
  }
  if (WBFN) {
#pragma unroll
    for (int r = 0; r < 4; r++) {
      int o = o0 + 4 * ty + r;
      ushort4 pk = make_ushort4(f2bf(acc[r][0] * bscale), f2bf(acc[r][1] * bscale),
                                f2bf(acc[r][2] * bscale), f2bf(acc[r][3] * bscale));
      *(ushort4*)&Obf[((size_t)(b * C_) + o) * HW_ + m0 + 4 * tx] = pk;
    }
  }
}

// ---------------- fold sobel 1x1 through q-proj (fp64) ----------------
__global__ void k_weff(const float* __restrict__ qW, const float* __restrict__ qb,
                       const float* __restrict__ sob_w, const float* __restrict__ sob_b,
                       double* __restrict__ weff) {
  int t = threadIdx.x;            // 0..255
  int g = t >> 7, i = t & 127;
  double acc = 0.0;
  for (int c = 0; c < 64; c++)
    acc += (double)sob_w[c] * (double)qW[(size_t)(g * 64 + c) * C_ + i];
  weff[t] = acc;
  if (t < 2) {
    double bb = (double)sob_b[0];
    for (int c = 0; c < 64; c++) bb += (double)sob_w[c] * (double)qb[t * 64 + c];
    weff[256 + t] = bb;
  }
}

// ---------------- sobel pre-projection s[bg,p] in fp64 ----------------
__global__ __launch_bounds__(256) void k_smapd(const float* __restrict__ x,
                                               const double* __restrict__ weff,
                                               double* __restrict__ smapd) {
  int p = blockIdx.x * 256 + threadIdx.x;
  int bg = blockIdx.y;
  int b = bg >> 1, g = bg & 1;
  const float* xb = x + (size_t)b * C_ * HW_ + p;
  const double* wv = weff + g * 128;
  double acc = weff[256 + g];
#pragma unroll 8
  for (int i = 0; i < 128; i++) acc += wv[i] * (double)xb[(size_t)i * HW_];
  smapd[bg * HW_ + p] = acc;
}

// ---------------- offset branch + sobel gate + pos/reference ----------------
__global__ __launch_bounds__(256) void k_offset_pos(const float* __restrict__ q,
                                                    const double* __restrict__ s_map,
                                                    const float* __restrict__ dw_w,
                                                    const float* __restrict__ dw_b,
                                                    const float* __restrict__ ln_g,
                                                    const float* __restrict__ ln_b,
                                                    const float* __restrict__ pw_w,
                                                    float* __restrict__ out) {
  int widx = blockIdx.x * 4 + (threadIdx.x >> 6);
  int lane = threadIdx.x & 63;
  int bg = widx / HW_;
  int p = widx - bg * HW_;
  int h = p / W_, w = p - h * W_;
  int b = bg >> 1, g = bg & 1;
  const float* qc = q + ((size_t)(b * C_ + g * CG_ + lane)) * HW_;
  float tv = dw_b[lane];
#pragma unroll
  for (int dy = -1; dy <= 1; dy++)
#pragma unroll
    for (int dx = -1; dx <= 1; dx++) {
      int hh = h + dy, ww = w + dx;
      if (hh >= 0 && hh < H_ && ww >= 0 && ww < W_)
        tv += dw_w[lane * 9 + (dy + 1) * 3 + (dx + 1)] * qc[hh * W_ + ww];
    }
  float ssum = tv, ssq = tv * tv;
#pragma unroll
  for (int msk = 32; msk; msk >>= 1) {
    ssum += __shfl_xor(ssum, msk, 64);
    ssq  += __shfl_xor(ssq,  msk, 64);
  }
  float mu  = ssum * (1.0f / 64.0f);
  float var = ssq * (1.0f / 64.0f) - mu * mu;
  float uu  = (tv - mu) * rsqrtf(var + 1e-5f) * ln_g[lane] + ln_b[lane];
  float gl = 0.5f * uu * (1.0f + erff(uu * 0.70710678118654752f));
  float p0 = pw_w[lane] * gl, p1 = pw_w[64 + lane] * gl;
#pragma unroll
  for (int msk = 32; msk; msk >>= 1) {
    p0 += __shfl_xor(p0, msk, 64);
    p1 += __shfl_xor(p1, msk, 64);
  }
  if (lane == 0) {
    const double sobx[9] = {-1., 0., 1., -2., 0., 2., -1., 0., 1.};
    const double soby[9] = {-1., -2., -1., 0., 0., 0., 1., 2., 1.};
    float off_y = tanhf(p0) * (1.0f / 47.0f);
    float off_x = tanhf(p1) * (1.0f / 47.0f);
    const double* sm = s_map + bg * HW_;
    double gx = 0., gy = 0.;
#pragma unroll
    for (int dy = -1; dy <= 1; dy++)
#pragma unroll
      for (int dx = -1; dx <= 1; dx++) {
        int hh = h + dy, ww = w + dx;
        if (hh >= 0 && hh < H_ && ww >= 0 && ww < W_) {
          double sv = sm[hh * W_ + ww];
          gx += sobx[(dy + 1) * 3 + dx + 1] * sv;
          gy += soby[(dy + 1) * 3 + dx + 1] * sv;
        }
      }
    double mag = sqrt(gx * gx + gy * gy);
    float bin = mag > 0.5 ? 1.0f : 0.0f;
    float ry = ((h + 0.5f) / 47.0f) * 2.0f - 1.0f;
    float rx = ((w + 0.5f) / 47.0f) * 2.0f - 1.0f;
    int pi = (bg * HW_ + p) * 2;
    out[POS_OFF + pi]     = off_y + ry * bin;
    out[POS_OFF + pi + 1] = off_x + rx * bin;
    out[REF_OFF + pi]     = ry;
    out[REF_OFF + pi + 1] = rx;
  }
}

// ---------------- bilinear grid sample ----------------
__global__ __launch_bounds__(256) void k_sample(const float* __restrict__ xT,
                                                const float* __restrict__ out,
                                                float* __restrict__ xs) {
  int widx = blockIdx.x * 4 + (threadIdx.x >> 6);
  int lane = threadIdx.x & 63;
  int bg = widx / HW_;
  int p = widx - bg * HW_;
  int b = bg >> 1, g = bg & 1;
  float py = out[POS_OFF + (bg * HW_ + p) * 2];
  float px = out[POS_OFF + (bg * HW_ + p) * 2 + 1];
  float gxf = (px + 1.0f) * 0.5f * 47.0f;
  float gyf = (py + 1.0f) * 0.5f * 47.0f;
  float x0 = floorf(gxf), y0 = floorf(gyf);
  float wx1 = gxf - x0, wy1 = gyf - y0;
  float wx0 = 1.0f - wx1, wy0 = 1.0f - wy1;
  const float* base = xT + (size_t)b * HW_ * C_ + g * CG_ + lane;
  float acc = 0.0f;
#pragma unroll
  for (int cy = 0; cy < 2; cy++)
#pragma unroll
    for (int cx = 0; cx < 2; cx++) {
      float yy = y0 + (float)cy, xx = x0 + (float)cx;
      bool valid = (yy >= 0.f) && (yy < 48.f) && (xx >= 0.f) && (xx < 48.f);
      int yc = min(max((int)yy, 0), 47);
      int xc = min(max((int)xx, 0), 47);
      float wgt = (cy ? wy1 : wy0) * (cx ? wx1 : wx0);
      float vv = valid ? base[(size_t)(yc * 48 + xc) * C_] : 0.0f;
      acc += wgt * vv;
    }
  xs[((size_t)(b * C_ + g * CG_ + lane)) * HW_ + p] = acc;
}

// ---------------- LEPE: depthwise 3x3 over q ----------------
__global__ __launch_bounds__(256) void k_lepe(const float* __restrict__ q,
                                              const float* __restrict__ rpe_w,
                                              const float* __restrict__ rpe_b,
                                              float* __restrict__ lepe) {
  int idx = blockIdx.x * 256 + threadIdx.x;
  int p = idx % HW_;
  int bc = idx / HW_;
  int c = bc & (C_ - 1);
  int h = p / W_, w = p - h * W_;
  const float* qc = q + (size_t)bc * HW_;
  float acc = rpe_b[c];
#pragma unroll
  for (int dy = -1; dy <= 1; dy++)
#pragma unroll
    for (int dx = -1; dx <= 1; dx++) {
      int hh = h + dy, ww = w + dx;
      if (hh >= 0 && hh < H_ && ww >= 0 && ww < W_)
        acc += rpe_w[c * 9 + (dy + 1) * 3 + (dx + 1)] * qc[hh * W_ + ww];
    }
  lepe[idx] = acc;
}

// ---------------- MFMA flash attention, n-split x2, K-prefetch ----------------
// qbf [b][m][128] (scaled), kbf [b][n][128], vbf [b][c128][2304]; all bf16.
__global__ __launch_bounds__(256, 4) void k_attn_mfma(const unsigned short* __restrict__ qbf,
                                                      const unsigned short* __restrict__ kbf,
                                                      const unsigned short* __restrict__ vbf,
                                                      float* __restrict__ prO0,
                                                      float* __restrict__ prO1,
                                                      float* __restrict__ prS) {
  __shared__ __align__(16) unsigned short Ps[4][16][72];   // per-wave P tile [m16][n64]
  int t = threadIdx.x;
  int w = t >> 6, l = t & 63;
  int lg = l >> 4, lo = l & 15;
  int bh = blockIdx.y, b = bh >> 2, hd = bh & 3;
  int nz = blockIdx.z;
  int cb = hd * 32;
  int m0 = blockIdx.x * 64 + w * 16;
  short8 aq = *(const short8*)(qbf + ((size_t)(b * HW_) + m0 + lo) * C_ + cb + lg * 8);
  const unsigned short* kb_ = kbf + (size_t)b * HW_ * C_ + cb + lg * 8;
  const unsigned short* vb_ = vbf + ((size_t)(b * C_) + cb + lo) * HW_ + lg * 8;
  f32x4 acc0 = {0.f, 0.f, 0.f, 0.f}, acc1 = {0.f, 0.f, 0.f, 0.f};
  float rsp[4] = {0.f, 0.f, 0.f, 0.f};
  int n0 = nz * 1152;
  short8 bk[4];
#pragma unroll
  for (int sub = 0; sub < 4; sub++)
    bk[sub] = *(const short8*)(kb_ + (size_t)(n0 + sub * 16 + lo) * C_);
  for (int it = 0; it < 18; it++, n0 += 64) {
    f32x4 z = {0.f, 0.f, 0.f, 0.f};
    f32x4 s[4];
#pragma unroll
    for (int sub = 0; sub < 4; sub++)
      s[sub] = __builtin_amdgcn_mfma_f32_16x16x32_bf16(aq, bk[sub], z, 0, 0, 0);
    if (it < 17) {
#pragma unroll
      for (int sub = 0; sub < 4; sub++)
        bk[sub] = *(const short8*)(kb_ + (size_t)(n0 + 64 + sub * 16 + lo) * C_);
    }
    // V loads for this tile (issued before exp section to cover L2 latency)
    short8 bv00 = *(const short8*)(vb_ + n0);
    short8 bv01 = *(const short8*)(vb_ + n0 + 32);
    short8 bv10 = *(const short8*)(vb_ + (size_t)16 * HW_ + n0);
    short8 bv11 = *(const short8*)(vb_ + (size_t)16 * HW_ + n0 + 32);
#pragma unroll
    for (int sub = 0; sub < 4; sub++)
#pragma unroll
      for (int r = 0; r < 4; r++) {
        float e = __expf(s[sub][r]);
        s[sub][r] = e;
        Ps[w][lg * 4 + r][sub * 16 + lo] = f2bf(e);
      }
#pragma unroll
    for (int r = 0; r < 4; r++)
      rsp[r] += (s[0][r] + s[1][r]) + (s[2][r] + s[3][r]);
    short8 pa0 = *(const short8*)&Ps[w][lo][lg * 8];
    short8 pa1 = *(const short8*)&Ps[w][lo][32 + lg * 8];
    acc0 = __builtin_amdgcn_mfma_f32_16x16x32_bf16(pa0, bv00, acc0, 0, 0, 0);
    acc0 = __builtin_amdgcn_mfma_f32_16x16x32_bf16(pa1, bv01, acc0, 0, 0, 0);
    acc1 = __builtin_amdgcn_mfma_f32_16x16x32_bf16(pa0, bv10, acc1, 0, 0, 0);
    acc1 = __builtin_amdgcn_mfma_f32_16x16x32_bf16(pa1, bv11, acc1, 0, 0, 0);
  }
#pragma unroll
  for (int r = 0; r < 4; r++) {
    rsp[r] += __shfl_xor(rsp[r], 1, 64);
    rsp[r] += __shfl_xor(rsp[r], 2, 64);
    rsp[r] += __shfl_xor(rsp[r], 4, 64);
    rsp[r] += __shfl_xor(rsp[r], 8, 64);
  }
  float* prO = nz ? prO1 : prO0;
#pragma unroll
  for (int r = 0; r < 4; r++) {
    int m = m0 + lg * 4 + r;
    size_t o0i = ((size_t)(b * C_ + cb + lo)) * HW_ + m;
    prO[o0i] = acc0[r];
    prO[o0i + (size_t)16 * HW_] = acc1[r];
  }
  if (lo == 0) {
#pragma unroll
    for (int r = 0; r < 4; r++)
      prS[(size_t)nz * 16 * HW_ + (size_t)bh * HW_ + m0 + lg * 4 + r] = rsp[r];
  }
}

// ---------------- combine partials: aout = (O0+O1)/(r0+r1) + lepe ----------------
__global__ __launch_bounds__(256) void k_combine(const float* __restrict__ prO0,
                                                 const float* __restrict__ prO1,
                                                 const float* __restrict__ prS,
                                                 const float* __restrict__ lepe,
                                                 float* __restrict__ aout) {
  size_t oi = ((size_t)blockIdx.x * 256 + threadIdx.x) * 4;
  int m = (int)(oi % HW_);
  int bc = (int)(oi / HW_);
  int c = bc & 127, b = bc >> 7;
  int hd = c >> 5;
  size_t rsi = ((size_t)(b * 4 + hd)) * HW_ + m;
  float4 o0 = *(const float4*)(prO0 + oi);
  float4 o1 = *(const float4*)(prO1 + oi);
  float4 r0 = *(const float4*)(prS + rsi);
  float4 r1 = *(const float4*)(prS + (size_t)16 * HW_ + rsi);
  float4 lp = *(const float4*)(lepe + oi);
  float4 res;
  res.x = (o0.x + o1.x) / (r0.x + r1.x) + lp.x;
  res.y = (o0.y + o1.y) / (r0.y + r1.y) + lp.y;
  res.z = (o0.z + o1.z) / (r0.z + r1.z) + lp.z;
  res.w = (o0.w + o1.w) / (r0.w + r1.w) + lp.w;
  *(float4*)(aout + oi) = res;
}

extern "C" void kernel_launch(void* const* d_in, const int* in_sizes, int n_in,
                              void* d_out, int out_size, void* d_ws, size_t ws_size,
                              hipStream_t stream) {
  const float* x        = (const float*)d_in[0];
  const float* qW       = (const float*)d_in[1];
  const float* qb       = (const float*)d_in[2];
  const float* kW       = (const float*)d_in[3];
  const float* kb       = (const float*)d_in[4];
  const float* vW       = (const float*)d_in[5];
  const float* vb       = (const float*)d_in[6];
  const float* oW       = (const float*)d_in[7];
  const float* ob       = (const float*)d_in[8];
  const float* off_dw_w = (const float*)d_in[9];
  const float* off_dw_b = (const float*)d_in[10];
  const float* ln_g     = (const float*)d_in[11];
  const float* ln_b     = (const float*)d_in[12];
  const float* off_pw_w = (const float*)d_in[13];
  const float* sob_w    = (const float*)d_in[14];
  const float* sob_b    = (const float*)d_in[15];
  const float* rpe_w    = (const float*)d_in[16];
  const float* rpe_b    = (const float*)d_in[17];
  float* out = (float*)d_out;
  float* wsf = (float*)d_ws;
  float* q    = wsf + WS_Q;
  float* xT   = wsf + WS_XT;
  float* xs   = wsf + WS_XS;
  float* lep  = wsf + WS_LEPE;
  unsigned short* qbf = (unsigned short*)(wsf + WS_K);
  unsigned short* kbf = (unsigned short*)(wsf + WS_V);
  unsigned short* vbf = (unsigned short*)(wsf + WS_XT);  // xT dead after k_sample
  double* weff  = (double*)(wsf + WS_LEPE);  // dead before k_lepe
  double* smapd = (double*)(wsf + WS_AOUT);  // dead before k_attn_mfma
  float* prO0 = wsf + WS_AOUT;               // also final aout (combine in-place)
  float* prO1 = wsf + WS_Q;                  // q fp32 dead after k_lepe
  float* prS  = wsf + WS_XS;                 // xs dead after k/v convs

  k_transpose<<<dim3(36, 2, 4), 256, 0, stream>>>(x, xT);
  k_conv1x1<1,1,0><<<dim3(36, 2, 4), 256, 0, stream>>>(qW, qb, x, q, qbf, SCALE_);
  k_weff    <<<1,              256, 0, stream>>>(qW, qb, sob_w, sob_b, weff);
  k_smapd   <<<dim3(9, 8),     256, 0, stream>>>(x, weff, smapd);
  k_offset_pos<<<4608,         256, 0, stream>>>(q, smapd, off_dw_w, off_dw_b,
                                                 ln_g, ln_b, off_pw_w, out);
  k_sample  <<<4608,           256, 0, stream>>>(xT, out, xs);
  k_conv1x1<0,1,0><<<dim3(36, 2, 4), 256, 0, stream>>>(kW, kb, xs, nullptr, kbf, 1.0f);
  k_conv1x1<0,0,1><<<dim3(36, 2, 4), 256, 0, stream>>>(vW, vb, xs, nullptr, vbf, 1.0f);
  k_lepe    <<<4608,           256, 0, stream>>>(q, rpe_w, rpe_b, lep);
  k_attn_mfma<<<dim3(36, 16, 2), 256, 0, stream>>>(qbf, kbf, vbf, prO0, prO1, prS);
  k_combine <<<1152,           256, 0, stream>>>(prO0, prO1, prS, lep, prO0);
  k_conv1x1<1,0,0><<<dim3(36, 2, 4), 256, 0, stream>>>(oW, ob, prO0, out + Y_OFF, nullptr, 1.0f);
}

// Round 5
// 217.737 us; speedup vs baseline: 1.9733x; 1.1149x over previous
//
#include <hip/hip_runtime.h>
#include <hip/hip_bf16.h>
#include <math.h>

#define B_   4
#define C_   128
#define H_   48
#define W_   48
#define HW_  2304
#define CG_  64
#define DH_  32
#define SCALE_ 0.17677669529663687f   // 32^-0.5
#define INVS_  5.656854249492381f     // 32^0.5

// d_out layout (floats)
#define Y_OFF   0
#define POS_OFF 1179648
#define REF_OFF 1216512

// workspace layout (float offsets). No aliasing; total 7,221,764 < prior 8.27M footprint.
#define OFF_XTBF  0         // ushort[4][2304][128]  x^T bf16
#define OFF_QBF   589824    // ushort[4][2304][128]  q*SCALE bf16 [m][c]
#define OFF_KBF   1179648   // ushort[4][2304][128]  k bf16 [n][c]
#define OFF_VBF   1769472   // ushort[4][128][2304]  v bf16 [c][n]
#define OFF_XST   2359296   // ushort[4][2304][128]  xs bf16 [p][c]
#define OFF_WBF   2949120   // ushort[4][16384]      qW,kW,vW,oW bf16
#define OFF_LEPET 2981888   // float[4][2304][128]   lepe^T
#define OFF_PRO0  4161536   // float[4][2304][128]
#define OFF_PRO1  5341184   // float[4][2304][128]
#define OFF_PRS   6520832   // float[2][16][2304]
#define OFF_AOUTT 6594560   // ushort[4][2304][128]
#define OFF_SMAPD 7184384   // double[8][2304]
#define OFF_WEFF  7221248   // double[258]

typedef __attribute__((ext_vector_type(8))) short short8;
typedef __attribute__((ext_vector_type(4))) float f32x4;
union VU { ushort4 u4[2]; short8 s8; };

__device__ inline unsigned short f2bf(float f) {
  unsigned u = __float_as_uint(f);
  u += 0x7fff + ((u >> 16) & 1);     // RNE
  return (unsigned short)(u >> 16);
}
__device__ inline float bf2f(unsigned short s) {
  return __uint_as_float(((unsigned)s) << 16);
}

// ---------------- weights -> bf16 ----------------
__global__ __launch_bounds__(256) void k_wbf(const float* __restrict__ qW, const float* __restrict__ kW,
                                             const float* __restrict__ vW, const float* __restrict__ oW,
                                             unsigned short* __restrict__ wbf) {
  int t = blockIdx.x * 256 + threadIdx.x;   // 65536
  int which = t >> 14, i = t & 16383;
  const float* src = which == 0 ? qW : which == 1 ? kW : which == 2 ? vW : oW;
  wbf[t] = f2bf(src[i]);
}

// ---------------- transpose x (b,c,p) -> xTbf (b,p,c) bf16 ----------------
__global__ __launch_bounds__(256) void k_transpose_bf(const float* __restrict__ x,
                                                      unsigned short* __restrict__ xTbf) {
  __shared__ float tile[64][65];
  int b = blockIdx.z, c0 = blockIdx.y * 64, p0 = blockIdx.x * 64;
  for (int idx = threadIdx.x; idx < 4096; idx += 256) {
    int cr = idx >> 6, pc = idx & 63;
    tile[cr][pc] = x[((size_t)(b * C_) + c0 + cr) * HW_ + p0 + pc];
  }
  __syncthreads();
  for (int idx = threadIdx.x; idx < 4096; idx += 256) {
    int pr = idx >> 6, cc = idx & 63;
    xTbf[((size_t)(b * HW_) + p0 + pr) * C_ + c0 + cc] = f2bf(tile[cc][pr]);
  }
}

// ---------------- q-conv (MFMA): qbf[m][c] = bf16(SCALE*(qW·x + qb)) ----------------
__global__ __launch_bounds__(256, 4) void k_qconv(const unsigned short* __restrict__ xTbf,
                                                  const unsigned short* __restrict__ wbf,
                                                  const float* __restrict__ qb,
                                                  unsigned short* __restrict__ qbf) {
  int t = threadIdx.x, w = t >> 6, l = t & 63, lg = l >> 4, lo = l & 15;
  int m0 = blockIdx.x * 16, b = blockIdx.y, o0 = w * 32;
  const unsigned short* xrow = xTbf + ((size_t)(b * HW_) + m0 + lo) * C_ + lg * 8;
  f32x4 acc[2] = {{0.f,0.f,0.f,0.f},{0.f,0.f,0.f,0.f}};
#pragma unroll
  for (int kb = 0; kb < 4; kb++) {
    short8 xf = *(const short8*)(xrow + kb * 32);
#pragma unroll
    for (int os = 0; os < 2; os++) {
      short8 wf = *(const short8*)(wbf + (size_t)(o0 + os * 16 + lo) * C_ + kb * 32 + lg * 8);
      acc[os] = __builtin_amdgcn_mfma_f32_16x16x32_bf16(xf, wf, acc[os], 0, 0, 0);
    }
  }
#pragma unroll
  for (int os = 0; os < 2; os++) {
    int o = o0 + os * 16 + lo;
    float bi = qb[o];
#pragma unroll
    for (int r = 0; r < 4; r++) {
      int m = m0 + lg * 4 + r;
      qbf[((size_t)(b * HW_) + m) * C_ + o] = f2bf((acc[os][r] + bi) * SCALE_);
    }
  }
}

// ---------------- k/v conv (MFMA, shared X frags): kbf[n][c], vbf[c][n] ----------------
__global__ __launch_bounds__(256, 4) void k_kvconv(const unsigned short* __restrict__ xsT,
                                                   const unsigned short* __restrict__ wbf,
                                                   const float* __restrict__ kbias,
                                                   const float* __restrict__ vbias,
                                                   unsigned short* __restrict__ kbf,
                                                   unsigned short* __restrict__ vbf) {
  int t = threadIdx.x, w = t >> 6, l = t & 63, lg = l >> 4, lo = l & 15;
  int n0 = blockIdx.x * 16, b = blockIdx.y, o0 = w * 32;
  const unsigned short* xrow = xsT + ((size_t)(b * HW_) + n0 + lo) * C_ + lg * 8;
  const unsigned short* wk = wbf + 16384;
  const unsigned short* wv = wbf + 32768;
  f32x4 ak[2] = {{0.f,0.f,0.f,0.f},{0.f,0.f,0.f,0.f}};
  f32x4 av[2] = {{0.f,0.f,0.f,0.f},{0.f,0.f,0.f,0.f}};
#pragma unroll
  for (int kb = 0; kb < 4; kb++) {
    short8 xf = *(const short8*)(xrow + kb * 32);
#pragma unroll
    for (int os = 0; os < 2; os++) {
      size_t wo = (size_t)(o0 + os * 16 + lo) * C_ + kb * 32 + lg * 8;
      short8 wkf = *(const short8*)(wk + wo);
      short8 wvf = *(const short8*)(wv + wo);
      ak[os] = __builtin_amdgcn_mfma_f32_16x16x32_bf16(xf, wkf, ak[os], 0, 0, 0);
      av[os] = __builtin_amdgcn_mfma_f32_16x16x32_bf16(wvf, xf, av[os], 0, 0, 0);
    }
  }
#pragma unroll
  for (int os = 0; os < 2; os++) {
    int ok = o0 + os * 16 + lo;
    float bk_ = kbias[ok];
#pragma unroll
    for (int r = 0; r < 4; r++) {
      int n = n0 + lg * 4 + r;
      kbf[((size_t)(b * HW_) + n) * C_ + ok] = f2bf(ak[os][r] + bk_);
      int ov = o0 + os * 16 + lg * 4 + r;
      vbf[((size_t)(b * C_) + ov) * HW_ + n0 + lo] = f2bf(av[os][r] + vbias[ov]);
    }
  }
}

// ---------------- o-conv (MFMA): y[c][m] = oW·aoutT + ob ----------------
__global__ __launch_bounds__(256, 4) void k_oconv(const unsigned short* __restrict__ aoutT,
                                                  const unsigned short* __restrict__ wbf,
                                                  const float* __restrict__ ob_,
                                                  float* __restrict__ y) {
  int t = threadIdx.x, w = t >> 6, l = t & 63, lg = l >> 4, lo = l & 15;
  int m0 = blockIdx.x * 16, b = blockIdx.y, o0 = w * 32;
  const unsigned short* xrow = aoutT + ((size_t)(b * HW_) + m0 + lo) * C_ + lg * 8;
  const unsigned short* wo = wbf + 49152;
  f32x4 acc[2] = {{0.f,0.f,0.f,0.f},{0.f,0.f,0.f,0.f}};
#pragma unroll
  for (int kb = 0; kb < 4; kb++) {
    short8 xf = *(const short8*)(xrow + kb * 32);
#pragma unroll
    for (int os = 0; os < 2; os++) {
      short8 wf = *(const short8*)(wo + (size_t)(o0 + os * 16 + lo) * C_ + kb * 32 + lg * 8);
      acc[os] = __builtin_amdgcn_mfma_f32_16x16x32_bf16(wf, xf, acc[os], 0, 0, 0);
    }
  }
#pragma unroll
  for (int os = 0; os < 2; os++)
#pragma unroll
    for (int r = 0; r < 4; r++) {
      int o = o0 + os * 16 + lg * 4 + r;
      y[((size_t)(b * C_) + o) * HW_ + m0 + lo] = acc[os][r] + ob_[o];
    }
}

// ---------------- fold sobel 1x1 through q-proj (fp64) ----------------
__global__ void k_weff(const float* __restrict__ qW, const float* __restrict__ qb,
                       const float* __restrict__ sob_w, const float* __restrict__ sob_b,
                       double* __restrict__ weff) {
  int t = threadIdx.x;
  int g = t >> 7, i = t & 127;
  double acc = 0.0;
  for (int c = 0; c < 64; c++)
    acc += (double)sob_w[c] * (double)qW[(size_t)(g * 64 + c) * C_ + i];
  weff[t] = acc;
  if (t < 2) {
    double bb = (double)sob_b[0];
    for (int c = 0; c < 64; c++) bb += (double)sob_w[c] * (double)qb[t * 64 + c];
    weff[256 + t] = bb;
  }
}

// ---------------- sobel pre-projection s[bg,p] in fp64 ----------------
__global__ __launch_bounds__(256) void k_smapd(const float* __restrict__ x,
                                               const double* __restrict__ weff,
                                               double* __restrict__ smapd) {
  int p = blockIdx.x * 256 + threadIdx.x;
  int bg = blockIdx.y;
  int b = bg >> 1, g = bg & 1;
  const float* xb = x + (size_t)b * C_ * HW_ + p;
  const double* wv = weff + g * 128;
  double acc = weff[256 + g];
#pragma unroll 8
  for (int i = 0; i < 128; i++) acc += wv[i] * (double)xb[(size_t)i * HW_];
  smapd[bg * HW_ + p] = acc;
}

// ---------------- offset branch (reads qbf) + sobel gate + pos/reference ----------------
__global__ __launch_bounds__(256) void k_offset_pos(const unsigned short* __restrict__ qbf,
                                                    const double* __restrict__ s_map,
                                                    const float* __restrict__ dw_w,
                                                    const float* __restrict__ dw_b,
                                                    const float* __restrict__ ln_g,
                                                    const float* __restrict__ ln_b,
                                                    const float* __restrict__ pw_w,
                                                    float* __restrict__ out) {
  int widx = blockIdx.x * 4 + (threadIdx.x >> 6);
  int lane = threadIdx.x & 63;
  int bg = widx / HW_;
  int p = widx - bg * HW_;
  int h = p / W_, w = p - h * W_;
  int b = bg >> 1, g = bg & 1;
  const unsigned short* qc = qbf + (size_t)(b * HW_) * C_ + g * 64 + lane;
  float tv = dw_b[lane];
#pragma unroll
  for (int dy = -1; dy <= 1; dy++)
#pragma unroll
    for (int dx = -1; dx <= 1; dx++) {
      int hh = h + dy, ww = w + dx;
      if (hh >= 0 && hh < H_ && ww >= 0 && ww < W_) {
        float wgt = dw_w[lane * 9 + (dy + 1) * 3 + (dx + 1)] * INVS_;
        tv += wgt * bf2f(qc[(size_t)(hh * W_ + ww) * C_]);
      }
    }
  float ssum = tv, ssq = tv * tv;
#pragma unroll
  for (int msk = 32; msk; msk >>= 1) {
    ssum += __shfl_xor(ssum, msk, 64);
    ssq  += __shfl_xor(ssq,  msk, 64);
  }
  float mu  = ssum * (1.0f / 64.0f);
  float var = ssq * (1.0f / 64.0f) - mu * mu;
  float uu  = (tv - mu) * rsqrtf(var + 1e-5f) * ln_g[lane] + ln_b[lane];
  float gl = 0.5f * uu * (1.0f + erff(uu * 0.70710678118654752f));
  float p0 = pw_w[lane] * gl, p1 = pw_w[64 + lane] * gl;
#pragma unroll
  for (int msk = 32; msk; msk >>= 1) {
    p0 += __shfl_xor(p0, msk, 64);
    p1 += __shfl_xor(p1, msk, 64);
  }
  if (lane == 0) {
    const double sobx[9] = {-1., 0., 1., -2., 0., 2., -1., 0., 1.};
    const double soby[9] = {-1., -2., -1., 0., 0., 0., 1., 2., 1.};
    float off_y = tanhf(p0) * (1.0f / 47.0f);
    float off_x = tanhf(p1) * (1.0f / 47.0f);
    const double* sm = s_map + bg * HW_;
    double gx = 0., gy = 0.;
#pragma unroll
    for (int dy = -1; dy <= 1; dy++)
#pragma unroll
      for (int dx = -1; dx <= 1; dx++) {
        int hh = h + dy, ww = w + dx;
        if (hh >= 0 && hh < H_ && ww >= 0 && ww < W_) {
          double sv = sm[hh * W_ + ww];
          gx += sobx[(dy + 1) * 3 + dx + 1] * sv;
          gy += soby[(dy + 1) * 3 + dx + 1] * sv;
        }
      }
    double mag = sqrt(gx * gx + gy * gy);
    float bin = mag > 0.5 ? 1.0f : 0.0f;
    float ry = ((h + 0.5f) / 47.0f) * 2.0f - 1.0f;
    float rx = ((w + 0.5f) / 47.0f) * 2.0f - 1.0f;
    int pi = (bg * HW_ + p) * 2;
    out[POS_OFF + pi]     = off_y + ry * bin;
    out[POS_OFF + pi + 1] = off_x + rx * bin;
    out[REF_OFF + pi]     = ry;
    out[REF_OFF + pi + 1] = rx;
  }
}

// ---------------- bilinear grid sample: xTbf -> xsT (both bf16 [p][c]) ----------------
__global__ __launch_bounds__(256) void k_sample(const unsigned short* __restrict__ xTbf,
                                                const float* __restrict__ out,
                                                unsigned short* __restrict__ xsT) {
  int widx = blockIdx.x * 4 + (threadIdx.x >> 6);
  int lane = threadIdx.x & 63;
  int bg = widx / HW_;
  int p = widx - bg * HW_;
  int b = bg >> 1, g = bg & 1;
  float py = out[POS_OFF + (bg * HW_ + p) * 2];
  float px = out[POS_OFF + (bg * HW_ + p) * 2 + 1];
  float gxf = (px + 1.0f) * 0.5f * 47.0f;
  float gyf = (py + 1.0f) * 0.5f * 47.0f;
  float x0 = floorf(gxf), y0 = floorf(gyf);
  float wx1 = gxf - x0, wy1 = gyf - y0;
  float wx0 = 1.0f - wx1, wy0 = 1.0f - wy1;
  const unsigned short* base = xTbf + (size_t)(b * HW_) * C_ + g * 64 + lane;
  float acc = 0.0f;
#pragma unroll
  for (int cy = 0; cy < 2; cy++)
#pragma unroll
    for (int cx = 0; cx < 2; cx++) {
      float yy = y0 + (float)cy, xx = x0 + (float)cx;
      bool valid = (yy >= 0.f) && (yy < 48.f) && (xx >= 0.f) && (xx < 48.f);
      int yc = min(max((int)yy, 0), 47);
      int xc = min(max((int)xx, 0), 47);
      float wgt = (cy ? wy1 : wy0) * (cx ? wx1 : wx0);
      float vv = valid ? bf2f(base[(size_t)(yc * 48 + xc) * C_]) : 0.0f;
      acc += wgt * vv;
    }
  xsT[((size_t)(b * HW_) + p) * C_ + g * 64 + lane] = f2bf(acc);
}

// ---------------- LEPE from qbf -> lepeT [m][c] fp32 ----------------
__global__ __launch_bounds__(256) void k_lepe_t(const unsigned short* __restrict__ qbf,
                                                const float* __restrict__ rpe_w,
                                                const float* __restrict__ rpe_b,
                                                float* __restrict__ lepeT) {
  int t = threadIdx.x;
  int c = t & 127, ps = t >> 7;
  int bp = blockIdx.x * 2 + ps;         // b*HW + p
  int b = bp / HW_;
  int p = bp - b * HW_;
  int h = p / W_, w = p - h * W_;
  const unsigned short* qc = qbf + (size_t)(b * HW_) * C_ + c;
  float acc = rpe_b[c];
#pragma unroll
  for (int dy = -1; dy <= 1; dy++)
#pragma unroll
    for (int dx = -1; dx <= 1; dx++) {
      int hh = h + dy, ww = w + dx;
      if (hh >= 0 && hh < H_ && ww >= 0 && ww < W_) {
        float wgt = rpe_w[c * 9 + (dy + 1) * 3 + (dx + 1)] * INVS_;
        acc += wgt * bf2f(qc[(size_t)(hh * W_ + ww) * C_]);
      }
    }
  lepeT[(size_t)bp * C_ + c] = acc;
}

// ---------------- MFMA flash attention v2: LDS-free via operand swap ----------------
__global__ __launch_bounds__(256, 4) void k_attn2(const unsigned short* __restrict__ qbf,
                                                  const unsigned short* __restrict__ kbf,
                                                  const unsigned short* __restrict__ vbf,
                                                  float* __restrict__ prO0,
                                                  float* __restrict__ prO1,
                                                  float* __restrict__ prS) {
  int t = threadIdx.x, w = t >> 6, l = t & 63, lg = l >> 4, lo = l & 15;
  int bh = blockIdx.y, b = bh >> 2, hd = bh & 3, nz = blockIdx.z;
  int cb = hd * 32;
  int m0 = blockIdx.x * 64 + w * 16;
  short8 aq = *(const short8*)(qbf + ((size_t)(b * HW_) + m0 + lo) * C_ + cb + lg * 8);
  const unsigned short* kb_ = kbf + (size_t)(b * HW_) * C_ + cb + lg * 8;
  const unsigned short* vrow0 = vbf + (size_t)(b * C_ + cb + lo) * HW_;
  const unsigned short* vrow1 = vrow0 + (size_t)16 * HW_;
  f32x4 acc0 = {0.f,0.f,0.f,0.f}, acc1 = {0.f,0.f,0.f,0.f};
  float rsum = 0.f;
  int n0 = nz * 1152;
  short8 bk[4];
#pragma unroll
  for (int sub = 0; sub < 4; sub++)
    bk[sub] = *(const short8*)(kb_ + (size_t)(n0 + sub * 16 + lo) * C_);
  for (int it = 0; it < 18; it++, n0 += 64) {
    f32x4 z = {0.f,0.f,0.f,0.f};
    // S^T = K·Q: lane (lg,lo) reg r of s[sub] = S[n0+sub*16+lg*4+r][m0+lo]
    f32x4 s0 = __builtin_amdgcn_mfma_f32_16x16x32_bf16(bk[0], aq, z, 0, 0, 0);
    f32x4 s1 = __builtin_amdgcn_mfma_f32_16x16x32_bf16(bk[1], aq, z, 0, 0, 0);
    f32x4 s2 = __builtin_amdgcn_mfma_f32_16x16x32_bf16(bk[2], aq, z, 0, 0, 0);
    f32x4 s3 = __builtin_amdgcn_mfma_f32_16x16x32_bf16(bk[3], aq, z, 0, 0, 0);
    if (it < 17) {
#pragma unroll
      for (int sub = 0; sub < 4; sub++)
        bk[sub] = *(const short8*)(kb_ + (size_t)(n0 + 64 + sub * 16 + lo) * C_);
    }
    // V fragments (k-slot order matches P packing below): slots j<4 -> n0+32ks+4lg+j, j>=4 -> +16
    VU bv00, bv01, bv10, bv11;
    bv00.u4[0] = *(const ushort4*)(vrow0 + n0 + lg * 4);
    bv00.u4[1] = *(const ushort4*)(vrow0 + n0 + 16 + lg * 4);
    bv01.u4[0] = *(const ushort4*)(vrow0 + n0 + 32 + lg * 4);
    bv01.u4[1] = *(const ushort4*)(vrow0 + n0 + 48 + lg * 4);
    bv10.u4[0] = *(const ushort4*)(vrow1 + n0 + lg * 4);
    bv10.u4[1] = *(const ushort4*)(vrow1 + n0 + 16 + lg * 4);
    bv11.u4[0] = *(const ushort4*)(vrow1 + n0 + 32 + lg * 4);
    bv11.u4[1] = *(const ushort4*)(vrow1 + n0 + 48 + lg * 4);
    // exp (logits bounded ~|0.3|) + accumulate rowsum + pack P fragments
#pragma unroll
    for (int r = 0; r < 4; r++) {
      s0[r] = __expf(s0[r]); s1[r] = __expf(s1[r]);
      s2[r] = __expf(s2[r]); s3[r] = __expf(s3[r]);
      rsum += (s0[r] + s1[r]) + (s2[r] + s3[r]);
    }
    short8 pa0, pa1;
#pragma unroll
    for (int j = 0; j < 4; j++) {
      pa0[j]     = (short)f2bf(s0[j]);
      pa0[j + 4] = (short)f2bf(s1[j]);
      pa1[j]     = (short)f2bf(s2[j]);
      pa1[j + 4] = (short)f2bf(s3[j]);
    }
    acc0 = __builtin_amdgcn_mfma_f32_16x16x32_bf16(pa0, bv00.s8, acc0, 0, 0, 0);
    acc0 = __builtin_amdgcn_mfma_f32_16x16x32_bf16(pa1, bv01.s8, acc0, 0, 0, 0);
    acc1 = __builtin_amdgcn_mfma_f32_16x16x32_bf16(pa0, bv10.s8, acc1, 0, 0, 0);
    acc1 = __builtin_amdgcn_mfma_f32_16x16x32_bf16(pa1, bv11.s8, acc1, 0, 0, 0);
  }
  rsum += __shfl_xor(rsum, 16, 64);
  rsum += __shfl_xor(rsum, 32, 64);
  float* prO = nz ? prO1 : prO0;
#pragma unroll
  for (int r = 0; r < 4; r++) {
    int m = m0 + lg * 4 + r;
    size_t oi = ((size_t)(b * HW_) + m) * C_ + cb;
    prO[oi + lo] = acc0[r];
    prO[oi + 16 + lo] = acc1[r];
  }
  if (l < 16)
    prS[((size_t)(nz * 16) + bh) * HW_ + m0 + lo] = rsum;
}

// ---------------- combine: aoutT[m][c] = bf16((O0+O1)/(r0+r1) + lepeT) ----------------
__global__ __launch_bounds__(256) void k_combine_t(const float* __restrict__ prO0,
                                                   const float* __restrict__ prO1,
                                                   const float* __restrict__ prS,
                                                   const float* __restrict__ lepeT,
                                                   unsigned short* __restrict__ aoutT) {
  size_t oi = ((size_t)blockIdx.x * 256 + threadIdx.x) * 4;
  int c = (int)(oi & 127);
  size_t bm = oi >> 7;                 // b*HW + m
  int b = (int)(bm / HW_);
  int m = (int)(bm - (size_t)b * HW_);
  int hd = c >> 5;
  size_t rsi = ((size_t)(b * 4 + hd)) * HW_ + m;
  float inv = 1.0f / (prS[rsi] + prS[(size_t)16 * HW_ + rsi]);
  float4 o0 = *(const float4*)(prO0 + oi);
  float4 o1 = *(const float4*)(prO1 + oi);
  float4 lp = *(const float4*)(lepeT + oi);
  ushort4 pk;
  pk.x = f2bf((o0.x + o1.x) * inv + lp.x);
  pk.y = f2bf((o0.y + o1.y) * inv + lp.y);
  pk.z = f2bf((o0.z + o1.z) * inv + lp.z);
  pk.w = f2bf((o0.w + o1.w) * inv + lp.w);
  *(ushort4*)(aoutT + oi) = pk;
}

extern "C" void kernel_launch(void* const* d_in, const int* in_sizes, int n_in,
                              void* d_out, int out_size, void* d_ws, size_t ws_size,
                              hipStream_t stream) {
  const float* x        = (const float*)d_in[0];
  const float* qW       = (const float*)d_in[1];
  const float* qb       = (const float*)d_in[2];
  const float* kW       = (const float*)d_in[3];
  const float* kb       = (const float*)d_in[4];
  const float* vW       = (const float*)d_in[5];
  const float* vb       = (const float*)d_in[6];
  const float* oW       = (const float*)d_in[7];
  const float* ob       = (const float*)d_in[8];
  const float* off_dw_w = (const float*)d_in[9];
  const float* off_dw_b = (const float*)d_in[10];
  const float* ln_g     = (const float*)d_in[11];
  const float* ln_b     = (const float*)d_in[12];
  const float* off_pw_w = (const float*)d_in[13];
  const float* sob_w    = (const float*)d_in[14];
  const float* sob_b    = (const float*)d_in[15];
  const float* rpe_w    = (const float*)d_in[16];
  const float* rpe_b    = (const float*)d_in[17];
  float* out = (float*)d_out;
  float* wsf = (float*)d_ws;
  unsigned short* xTbf  = (unsigned short*)(wsf + OFF_XTBF);
  unsigned short* qbf   = (unsigned short*)(wsf + OFF_QBF);
  unsigned short* kbf   = (unsigned short*)(wsf + OFF_KBF);
  unsigned short* vbf   = (unsigned short*)(wsf + OFF_VBF);
  unsigned short* xsT   = (unsigned short*)(wsf + OFF_XST);
  unsigned short* wbf   = (unsigned short*)(wsf + OFF_WBF);
  unsigned short* aoutT = (unsigned short*)(wsf + OFF_AOUTT);
  float* lepeT = wsf + OFF_LEPET;
  float* prO0  = wsf + OFF_PRO0;
  float* prO1  = wsf + OFF_PRO1;
  float* prS   = wsf + OFF_PRS;
  double* smapd = (double*)(wsf + OFF_SMAPD);
  double* weff  = (double*)(wsf + OFF_WEFF);

  k_wbf         <<<256,             256, 0, stream>>>(qW, kW, vW, oW, wbf);
  k_transpose_bf<<<dim3(36, 2, 4),  256, 0, stream>>>(x, xTbf);
  k_qconv       <<<dim3(144, 4),    256, 0, stream>>>(xTbf, wbf, qb, qbf);
  k_weff        <<<1,               256, 0, stream>>>(qW, qb, sob_w, sob_b, weff);
  k_smapd       <<<dim3(9, 8),      256, 0, stream>>>(x, weff, smapd);
  k_offset_pos  <<<4608,            256, 0, stream>>>(qbf, smapd, off_dw_w, off_dw_b,
                                                      ln_g, ln_b, off_pw_w, out);
  k_sample      <<<4608,            256, 0, stream>>>(xTbf, out, xsT);
  k_kvconv      <<<dim3(144, 4),    256, 0, stream>>>(xsT, wbf, kb, vb, kbf, vbf);
  k_lepe_t      <<<4608,            256, 0, stream>>>(qbf, rpe_w, rpe_b, lepeT);
  k_attn2       <<<dim3(36, 16, 2), 256, 0, stream>>>(qbf, kbf, vbf, prO0, prO1, prS);
  k_combine_t   <<<1152,            256, 0, stream>>>(prO0, prO1, prS, lepeT, aoutT);
  k_oconv       <<<dim3(144, 4),    256, 0, stream>>>(aoutT, wbf, ob, out + Y_OFF);
}

// Round 6
// 174.376 us; speedup vs baseline: 2.4640x; 1.2487x over previous
//
#include <hip/hip_runtime.h>
#include <hip/hip_bf16.h>
#include <math.h>

#define B_   4
#define C_   128
#define H_   48
#define W_   48
#define HW_  2304
#define CG_  64
#define DH_  32
#define SCALE_ 0.17677669529663687f   // 32^-0.5
#define INVS_  5.656854249492381f     // 32^0.5

// d_out layout (floats)
#define Y_OFF   0
#define POS_OFF 1179648
#define REF_OFF 1216512

// workspace layout (float offsets)
#define OFF_XTBF  0         // ushort[4][2304][128]  x^T bf16
#define OFF_QBF   589824    // ushort[4][2304][128]  q*SCALE bf16 [m][c]
#define OFF_KBF   1179648   // ushort[4][2304][128]  k bf16 [n][c]
#define OFF_VBF   1769472   // ushort[4][128][2304]  v bf16 [c][n] (k-slot permuted per 32-n group)
#define OFF_XST   2359296   // ushort[4][2304][128]  xs bf16 [p][c]
#define OFF_WBF   2949120   // ushort[4][16384]      qW,kW,vW,oW bf16
#define OFF_LEPET 2981888   // float[4][2304][128]   lepe^T
#define OFF_PRO0  4161536   // float[4][2304][128]
#define OFF_PRO1  5341184   // float[4][2304][128]
#define OFF_PRS   6520832   // float[2][16][2304]
#define OFF_AOUTT 6594560   // ushort[4][2304][128]
#define OFF_SMAPD 7184384   // double[8][2304]
#define OFF_WEFF  7221248   // double[258]

typedef __attribute__((ext_vector_type(8))) short short8;
typedef __attribute__((ext_vector_type(4))) float f32x4;

__device__ inline unsigned short f2bf(float f) {
  unsigned u = __float_as_uint(f);
  u += 0x7fff + ((u >> 16) & 1);     // RNE
  return (unsigned short)(u >> 16);
}
__device__ inline float bf2f(unsigned short s) {
  return __uint_as_float(((unsigned)s) << 16);
}

// pack 8 f32 -> short8 of bf16 via v_cvt_pk_bf16_f32 (RNE), 4 ops
__device__ inline short8 pack8(const f32x4 a, const f32x4 b) {
  union { unsigned u[4]; short8 s; } r;
  asm("v_cvt_pk_bf16_f32 %0, %1, %2" : "=v"(r.u[0]) : "v"(a[0]), "v"(a[1]));
  asm("v_cvt_pk_bf16_f32 %0, %1, %2" : "=v"(r.u[1]) : "v"(a[2]), "v"(a[3]));
  asm("v_cvt_pk_bf16_f32 %0, %1, %2" : "=v"(r.u[2]) : "v"(b[0]), "v"(b[1]));
  asm("v_cvt_pk_bf16_f32 %0, %1, %2" : "=v"(r.u[3]) : "v"(b[2]), "v"(b[3]));
  return r.s;
}

// ---------------- prep: weights->bf16 (blocks 0..255) + sobel weff fp64 (block 256) ----------------
__global__ __launch_bounds__(256) void k_prep(const float* __restrict__ qW, const float* __restrict__ kW,
                                              const float* __restrict__ vW, const float* __restrict__ oW,
                                              const float* __restrict__ qb,
                                              const float* __restrict__ sob_w, const float* __restrict__ sob_b,
                                              unsigned short* __restrict__ wbf,
                                              double* __restrict__ weff) {
  if (blockIdx.x < 256) {
    int t = blockIdx.x * 256 + threadIdx.x;   // 65536
    int which = t >> 14, i = t & 16383;
    const float* src = which == 0 ? qW : which == 1 ? kW : which == 2 ? vW : oW;
    wbf[t] = f2bf(src[i]);
  } else {
    int t = threadIdx.x;
    int g = t >> 7, i = t & 127;
    double acc = 0.0;
    for (int c = 0; c < 64; c++)
      acc += (double)sob_w[c] * (double)qW[(size_t)(g * 64 + c) * C_ + i];
    weff[t] = acc;
    if (t < 2) {
      double bb = (double)sob_b[0];
      for (int c = 0; c < 64; c++) bb += (double)sob_w[c] * (double)qb[t * 64 + c];
      weff[256 + t] = bb;
    }
  }
}

// ---------------- transpose x (b,c,p) -> xTbf (b,p,c) bf16 ----------------
__global__ __launch_bounds__(256) void k_transpose_bf(const float* __restrict__ x,
                                                      unsigned short* __restrict__ xTbf) {
  __shared__ float tile[64][65];
  int b = blockIdx.z, c0 = blockIdx.y * 64, p0 = blockIdx.x * 64;
  for (int idx = threadIdx.x; idx < 4096; idx += 256) {
    int cr = idx >> 6, pc = idx & 63;
    tile[cr][pc] = x[((size_t)(b * C_) + c0 + cr) * HW_ + p0 + pc];
  }
  __syncthreads();
  for (int idx = threadIdx.x; idx < 4096; idx += 256) {
    int pr = idx >> 6, cc = idx & 63;
    xTbf[((size_t)(b * HW_) + p0 + pr) * C_ + c0 + cc] = f2bf(tile[cc][pr]);
  }
}

// ---------------- q-conv (MFMA): qbf[m][c] = bf16(SCALE*(qW·x + qb)) ----------------
__global__ __launch_bounds__(256, 4) void k_qconv(const unsigned short* __restrict__ xTbf,
                                                  const unsigned short* __restrict__ wbf,
                                                  const float* __restrict__ qb,
                                                  unsigned short* __restrict__ qbf) {
  int t = threadIdx.x, w = t >> 6, l = t & 63, lg = l >> 4, lo = l & 15;
  int m0 = blockIdx.x * 16, b = blockIdx.y, o0 = w * 32;
  const unsigned short* xrow = xTbf + ((size_t)(b * HW_) + m0 + lo) * C_ + lg * 8;
  f32x4 acc[2] = {{0.f,0.f,0.f,0.f},{0.f,0.f,0.f,0.f}};
#pragma unroll
  for (int kb = 0; kb < 4; kb++) {
    short8 xf = *(const short8*)(xrow + kb * 32);
#pragma unroll
    for (int os = 0; os < 2; os++) {
      short8 wf = *(const short8*)(wbf + (size_t)(o0 + os * 16 + lo) * C_ + kb * 32 + lg * 8);
      acc[os] = __builtin_amdgcn_mfma_f32_16x16x32_bf16(xf, wf, acc[os], 0, 0, 0);
    }
  }
#pragma unroll
  for (int os = 0; os < 2; os++) {
    int o = o0 + os * 16 + lo;
    float bi = qb[o];
#pragma unroll
    for (int r = 0; r < 4; r++) {
      int m = m0 + lg * 4 + r;
      qbf[((size_t)(b * HW_) + m) * C_ + o] = f2bf((acc[os][r] + bi) * SCALE_);
    }
  }
}

// ---------------- k/v conv (MFMA): kbf[n][c]; vbf[c][n] written k-slot-permuted ----------------
__global__ __launch_bounds__(256, 4) void k_kvconv(const unsigned short* __restrict__ xsT,
                                                   const unsigned short* __restrict__ wbf,
                                                   const float* __restrict__ kbias,
                                                   const float* __restrict__ vbias,
                                                   unsigned short* __restrict__ kbf,
                                                   unsigned short* __restrict__ vbf) {
  int t = threadIdx.x, w = t >> 6, l = t & 63, lg = l >> 4, lo = l & 15;
  int n0 = blockIdx.x * 16, b = blockIdx.y, o0 = w * 32;
  const unsigned short* xrow = xsT + ((size_t)(b * HW_) + n0 + lo) * C_ + lg * 8;
  const unsigned short* wk = wbf + 16384;
  const unsigned short* wv = wbf + 32768;
  f32x4 ak[2] = {{0.f,0.f,0.f,0.f},{0.f,0.f,0.f,0.f}};
  f32x4 av[2] = {{0.f,0.f,0.f,0.f},{0.f,0.f,0.f,0.f}};
#pragma unroll
  for (int kb = 0; kb < 4; kb++) {
    short8 xf = *(const short8*)(xrow + kb * 32);
#pragma unroll
    for (int os = 0; os < 2; os++) {
      size_t wo = (size_t)(o0 + os * 16 + lo) * C_ + kb * 32 + lg * 8;
      short8 wkf = *(const short8*)(wk + wo);
      short8 wvf = *(const short8*)(wv + wo);
      ak[os] = __builtin_amdgcn_mfma_f32_16x16x32_bf16(xf, wkf, ak[os], 0, 0, 0);
      av[os] = __builtin_amdgcn_mfma_f32_16x16x32_bf16(wvf, xf, av[os], 0, 0, 0);
    }
  }
  // permuted V position within its 32-n group: slots j<4 -> n=4lg+j, j>=4 -> 16+4lg+(j-4)
  int o32 = (n0 & 16) + lo;
  int vpos = (n0 & ~31) + ((o32 & 12) << 1) + (o32 & 3) + ((o32 >> 4) << 2);
#pragma unroll
  for (int os = 0; os < 2; os++) {
    int ok = o0 + os * 16 + lo;
    float bk_ = kbias[ok];
#pragma unroll
    for (int r = 0; r < 4; r++) {
      int n = n0 + lg * 4 + r;
      kbf[((size_t)(b * HW_) + n) * C_ + ok] = f2bf(ak[os][r] + bk_);
      int ov = o0 + os * 16 + lg * 4 + r;
      vbf[((size_t)(b * C_) + ov) * HW_ + vpos] = f2bf(av[os][r] + vbias[ov]);
    }
  }
}

// ---------------- o-conv (MFMA): y[c][m] = oW·aoutT + ob ----------------
__global__ __launch_bounds__(256, 4) void k_oconv(const unsigned short* __restrict__ aoutT,
                                                  const unsigned short* __restrict__ wbf,
                                                  const float* __restrict__ ob_,
                                                  float* __restrict__ y) {
  int t = threadIdx.x, w = t >> 6, l = t & 63, lg = l >> 4, lo = l & 15;
  int m0 = blockIdx.x * 16, b = blockIdx.y, o0 = w * 32;
  const unsigned short* xrow = aoutT + ((size_t)(b * HW_) + m0 + lo) * C_ + lg * 8;
  const unsigned short* wo = wbf + 49152;
  f32x4 acc[2] = {{0.f,0.f,0.f,0.f},{0.f,0.f,0.f,0.f}};
#pragma unroll
  for (int kb = 0; kb < 4; kb++) {
    short8 xf = *(const short8*)(xrow + kb * 32);
#pragma unroll
    for (int os = 0; os < 2; os++) {
      short8 wf = *(const short8*)(wo + (size_t)(o0 + os * 16 + lo) * C_ + kb * 32 + lg * 8);
      acc[os] = __builtin_amdgcn_mfma_f32_16x16x32_bf16(wf, xf, acc[os], 0, 0, 0);
    }
  }
#pragma unroll
  for (int os = 0; os < 2; os++)
#pragma unroll
    for (int r = 0; r < 4; r++) {
      int o = o0 + os * 16 + lg * 4 + r;
      y[((size_t)(b * C_) + o) * HW_ + m0 + lo] = acc[os][r] + ob_[o];
    }
}

// ---------------- sobel pre-projection s[bg,p] in fp64 ----------------
__global__ __launch_bounds__(256) void k_smapd(const float* __restrict__ x,
                                               const double* __restrict__ weff,
                                               double* __restrict__ smapd) {
  int p = blockIdx.x * 256 + threadIdx.x;
  int bg = blockIdx.y;
  int b = bg >> 1, g = bg & 1;
  const float* xb = x + (size_t)b * C_ * HW_ + p;
  const double* wv = weff + g * 128;
  double acc = weff[256 + g];
#pragma unroll 8
  for (int i = 0; i < 128; i++) acc += wv[i] * (double)xb[(size_t)i * HW_];
  smapd[bg * HW_ + p] = acc;
}

// ---------------- offset branch (reads qbf) + sobel gate + pos/reference ----------------
__global__ __launch_bounds__(256) void k_offset_pos(const unsigned short* __restrict__ qbf,
                                                    const double* __restrict__ s_map,
                                                    const float* __restrict__ dw_w,
                                                    const float* __restrict__ dw_b,
                                                    const float* __restrict__ ln_g,
                                                    const float* __restrict__ ln_b,
                                                    const float* __restrict__ pw_w,
                                                    float* __restrict__ out) {
  int widx = blockIdx.x * 4 + (threadIdx.x >> 6);
  int lane = threadIdx.x & 63;
  int bg = widx / HW_;
  int p = widx - bg * HW_;
  int h = p / W_, w = p - h * W_;
  int b = bg >> 1, g = bg & 1;
  const unsigned short* qc = qbf + (size_t)(b * HW_) * C_ + g * 64 + lane;
  float tv = dw_b[lane];
#pragma unroll
  for (int dy = -1; dy <= 1; dy++)
#pragma unroll
    for (int dx = -1; dx <= 1; dx++) {
      int hh = h + dy, ww = w + dx;
      if (hh >= 0 && hh < H_ && ww >= 0 && ww < W_) {
        float wgt = dw_w[lane * 9 + (dy + 1) * 3 + (dx + 1)] * INVS_;
        tv += wgt * bf2f(qc[(size_t)(hh * W_ + ww) * C_]);
      }
    }
  float ssum = tv, ssq = tv * tv;
#pragma unroll
  for (int msk = 32; msk; msk >>= 1) {
    ssum += __shfl_xor(ssum, msk, 64);
    ssq  += __shfl_xor(ssq,  msk, 64);
  }
  float mu  = ssum * (1.0f / 64.0f);
  float var = ssq * (1.0f / 64.0f) - mu * mu;
  float uu  = (tv - mu) * rsqrtf(var + 1e-5f) * ln_g[lane] + ln_b[lane];
  float gl = 0.5f * uu * (1.0f + erff(uu * 0.70710678118654752f));
  float p0 = pw_w[lane] * gl, p1 = pw_w[64 + lane] * gl;
#pragma unroll
  for (int msk = 32; msk; msk >>= 1) {
    p0 += __shfl_xor(p0, msk, 64);
    p1 += __shfl_xor(p1, msk, 64);
  }
  if (lane == 0) {
    const double sobx[9] = {-1., 0., 1., -2., 0., 2., -1., 0., 1.};
    const double soby[9] = {-1., -2., -1., 0., 0., 0., 1., 2., 1.};
    float off_y = tanhf(p0) * (1.0f / 47.0f);
    float off_x = tanhf(p1) * (1.0f / 47.0f);
    const double* sm = s_map + bg * HW_;
    double gx = 0., gy = 0.;
#pragma unroll
    for (int dy = -1; dy <= 1; dy++)
#pragma unroll
      for (int dx = -1; dx <= 1; dx++) {
        int hh = h + dy, ww = w + dx;
        if (hh >= 0 && hh < H_ && ww >= 0 && ww < W_) {
          double sv = sm[hh * W_ + ww];
          gx += sobx[(dy + 1) * 3 + dx + 1] * sv;
          gy += soby[(dy + 1) * 3 + dx + 1] * sv;
        }
      }
    double mag = sqrt(gx * gx + gy * gy);
    float bin = mag > 0.5 ? 1.0f : 0.0f;
    float ry = ((h + 0.5f) / 47.0f) * 2.0f - 1.0f;
    float rx = ((w + 0.5f) / 47.0f) * 2.0f - 1.0f;
    int pi = (bg * HW_ + p) * 2;
    out[POS_OFF + pi]     = off_y + ry * bin;
    out[POS_OFF + pi + 1] = off_x + rx * bin;
    out[REF_OFF + pi]     = ry;
    out[REF_OFF + pi + 1] = rx;
  }
}

// ---------------- bilinear grid sample: xTbf -> xsT (both bf16 [p][c]) ----------------
__global__ __launch_bounds__(256) void k_sample(const unsigned short* __restrict__ xTbf,
                                                const float* __restrict__ out,
                                                unsigned short* __restrict__ xsT) {
  int widx = blockIdx.x * 4 + (threadIdx.x >> 6);
  int lane = threadIdx.x & 63;
  int bg = widx / HW_;
  int p = widx - bg * HW_;
  int b = bg >> 1, g = bg & 1;
  float py = out[POS_OFF + (bg * HW_ + p) * 2];
  float px = out[POS_OFF + (bg * HW_ + p) * 2 + 1];
  float gxf = (px + 1.0f) * 0.5f * 47.0f;
  float gyf = (py + 1.0f) * 0.5f * 47.0f;
  float x0 = floorf(gxf), y0 = floorf(gyf);
  float wx1 = gxf - x0, wy1 = gyf - y0;
  float wx0 = 1.0f - wx1, wy0 = 1.0f - wy1;
  const unsigned short* base = xTbf + (size_t)(b * HW_) * C_ + g * 64 + lane;
  float acc = 0.0f;
#pragma unroll
  for (int cy = 0; cy < 2; cy++)
#pragma unroll
    for (int cx = 0; cx < 2; cx++) {
      float yy = y0 + (float)cy, xx = x0 + (float)cx;
      bool valid = (yy >= 0.f) && (yy < 48.f) && (xx >= 0.f) && (xx < 48.f);
      int yc = min(max((int)yy, 0), 47);
      int xc = min(max((int)xx, 0), 47);
      float wgt = (cy ? wy1 : wy0) * (cx ? wx1 : wx0);
      float vv = valid ? bf2f(base[(size_t)(yc * 48 + xc) * C_]) : 0.0f;
      acc += wgt * vv;
    }
  xsT[((size_t)(b * HW_) + p) * C_ + g * 64 + lane] = f2bf(acc);
}

// ---------------- LEPE from qbf -> lepeT [m][c] fp32 ----------------
__global__ __launch_bounds__(256) void k_lepe_t(const unsigned short* __restrict__ qbf,
                                                const float* __restrict__ rpe_w,
                                                const float* __restrict__ rpe_b,
                                                float* __restrict__ lepeT) {
  int t = threadIdx.x;
  int c = t & 127, ps = t >> 7;
  int bp = blockIdx.x * 2 + ps;         // b*HW + p
  int b = bp / HW_;
  int p = bp - b * HW_;
  int h = p / W_, w = p - h * W_;
  const unsigned short* qc = qbf + (size_t)(b * HW_) * C_ + c;
  float acc = rpe_b[c];
#pragma unroll
  for (int dy = -1; dy <= 1; dy++)
#pragma unroll
    for (int dx = -1; dx <= 1; dx++) {
      int hh = h + dy, ww = w + dx;
      if (hh >= 0 && hh < H_ && ww >= 0 && ww < W_) {
        float wgt = rpe_w[c * 9 + (dy + 1) * 3 + (dx + 1)] * INVS_;
        acc += wgt * bf2f(qc[(size_t)(hh * W_ + ww) * C_]);
      }
    }
  lepeT[(size_t)bp * C_ + c] = acc;
}

// ---------------- MFMA flash attention v3: full K+V prefetch, cvt_pk pack ----------------
#define ATTN_BODY(BK, BV, BKN, BVN, DOPREF)                                         \
  {                                                                                 \
    if (DOPREF) {                                                                   \
      _Pragma("unroll")                                                             \
      for (int sub = 0; sub < 4; sub++)                                             \
        BKN[sub] = *(const short8*)(kb_ + (size_t)(n0 + 64 + sub * 16 + lo) * C_);  \
      BVN[0] = *(const short8*)(vr0 + n0 + 64);                                     \
      BVN[1] = *(const short8*)(vr0 + n0 + 96);                                     \
      BVN[2] = *(const short8*)(vr1 + n0 + 64);                                     \
      BVN[3] = *(const short8*)(vr1 + n0 + 96);                                     \
    }                                                                               \
    f32x4 z = {0.f, 0.f, 0.f, 0.f};                                                 \
    f32x4 s0 = __builtin_amdgcn_mfma_f32_16x16x32_bf16(BK[0], aq, z, 0, 0, 0);      \
    f32x4 s1 = __builtin_amdgcn_mfma_f32_16x16x32_bf16(BK[1], aq, z, 0, 0, 0);      \
    f32x4 s2 = __builtin_amdgcn_mfma_f32_16x16x32_bf16(BK[2], aq, z, 0, 0, 0);      \
    f32x4 s3 = __builtin_amdgcn_mfma_f32_16x16x32_bf16(BK[3], aq, z, 0, 0, 0);      \
    _Pragma("unroll")                                                               \
    for (int r = 0; r < 4; r++) {                                                   \
      s0[r] = __expf(s0[r]); s1[r] = __expf(s1[r]);                                 \
      s2[r] = __expf(s2[r]); s3[r] = __expf(s3[r]);                                 \
      rsum += (s0[r] + s1[r]) + (s2[r] + s3[r]);                                    \
    }                                                                               \
    short8 pa0 = pack8(s0, s1), pa1 = pack8(s2, s3);                                \
    acc0 = __builtin_amdgcn_mfma_f32_16x16x32_bf16(pa0, BV[0], acc0, 0, 0, 0);      \
    acc0 = __builtin_amdgcn_mfma_f32_16x16x32_bf16(pa1, BV[1], acc0, 0, 0, 0);      \
    acc1 = __builtin_amdgcn_mfma_f32_16x16x32_bf16(pa0, BV[2], acc1, 0, 0, 0);      \
    acc1 = __builtin_amdgcn_mfma_f32_16x16x32_bf16(pa1, BV[3], acc1, 0, 0, 0);      \
    n0 += 64;                                                                       \
  }

__global__ __launch_bounds__(256, 4) void k_attn3(const unsigned short* __restrict__ qbf,
                                                  const unsigned short* __restrict__ kbf,
                                                  const unsigned short* __restrict__ vpf,
                                                  float* __restrict__ prO0,
                                                  float* __restrict__ prO1,
                                                  float* __restrict__ prS) {
  int t = threadIdx.x, w = t >> 6, l = t & 63, lg = l >> 4, lo = l & 15;
  int bh = blockIdx.y, b = bh >> 2, hd = bh & 3, nz = blockIdx.z;
  int cb = hd * 32;
  int m0 = blockIdx.x * 64 + w * 16;
  short8 aq = *(const short8*)(qbf + ((size_t)(b * HW_) + m0 + lo) * C_ + cb + lg * 8);
  const unsigned short* kb_ = kbf + (size_t)(b * HW_) * C_ + cb + lg * 8;
  const unsigned short* vr0 = vpf + (size_t)(b * C_ + cb + lo) * HW_ + lg * 8;
  const unsigned short* vr1 = vr0 + (size_t)16 * HW_;
  f32x4 acc0 = {0.f,0.f,0.f,0.f}, acc1 = {0.f,0.f,0.f,0.f};
  float rsum = 0.f;
  int n0 = nz * 1152;
  short8 bkA[4], bkB[4], bvA[4], bvB[4];
#pragma unroll
  for (int sub = 0; sub < 4; sub++)
    bkA[sub] = *(const short8*)(kb_ + (size_t)(n0 + sub * 16 + lo) * C_);
  bvA[0] = *(const short8*)(vr0 + n0);
  bvA[1] = *(const short8*)(vr0 + n0 + 32);
  bvA[2] = *(const short8*)(vr1 + n0);
  bvA[3] = *(const short8*)(vr1 + n0 + 32);
  for (int i9 = 0; i9 < 9; i9++) {
    ATTN_BODY(bkA, bvA, bkB, bvB, true)
    ATTN_BODY(bkB, bvB, bkA, bvA, (i9 < 8))
  }
  rsum += __shfl_xor(rsum, 16, 64);
  rsum += __shfl_xor(rsum, 32, 64);
  float* prO = nz ? prO1 : prO0;
#pragma unroll
  for (int r = 0; r < 4; r++) {
    int m = m0 + lg * 4 + r;
    size_t oi = ((size_t)(b * HW_) + m) * C_ + cb;
    prO[oi + lo] = acc0[r];
    prO[oi + 16 + lo] = acc1[r];
  }
  if (l < 16)
    prS[((size_t)(nz * 16) + bh) * HW_ + m0 + lo] = rsum;
}

// ---------------- combine: aoutT[m][c] = bf16((O0+O1)/(r0+r1) + lepeT) ----------------
__global__ __launch_bounds__(256) void k_combine_t(const float* __restrict__ prO0,
                                                   const float* __restrict__ prO1,
                                                   const float* __restrict__ prS,
                                                   const float* __restrict__ lepeT,
                                                   unsigned short* __restrict__ aoutT) {
  size_t oi = ((size_t)blockIdx.x * 256 + threadIdx.x) * 4;
  int c = (int)(oi & 127);
  size_t bm = oi >> 7;                 // b*HW + m
  int b = (int)(bm / HW_);
  int m = (int)(bm - (size_t)b * HW_);
  int hd = c >> 5;
  size_t rsi = ((size_t)(b * 4 + hd)) * HW_ + m;
  float inv = 1.0f / (prS[rsi] + prS[(size_t)16 * HW_ + rsi]);
  float4 o0 = *(const float4*)(prO0 + oi);
  float4 o1 = *(const float4*)(prO1 + oi);
  float4 lp = *(const float4*)(lepeT + oi);
  ushort4 pk;
  pk.x = f2bf((o0.x + o1.x) * inv + lp.x);
  pk.y = f2bf((o0.y + o1.y) * inv + lp.y);
  pk.z = f2bf((o0.z + o1.z) * inv + lp.z);
  pk.w = f2bf((o0.w + o1.w) * inv + lp.w);
  *(ushort4*)(aoutT + oi) = pk;
}

extern "C" void kernel_launch(void* const* d_in, const int* in_sizes, int n_in,
                              void* d_out, int out_size, void* d_ws, size_t ws_size,
                              hipStream_t stream) {
  const float* x        = (const float*)d_in[0];
  const float* qW       = (const float*)d_in[1];
  const float* qb       = (const float*)d_in[2];
  const float* kW       = (const float*)d_in[3];
  const float* kb       = (const float*)d_in[4];
  const float* vW       = (const float*)d_in[5];
  const float* vb       = (const float*)d_in[6];
  const float* oW       = (const float*)d_in[7];
  const float* ob       = (const float*)d_in[8];
  const float* off_dw_w = (const float*)d_in[9];
  const float* off_dw_b = (const float*)d_in[10];
  const float* ln_g     = (const float*)d_in[11];
  const float* ln_b     = (const float*)d_in[12];
  const float* off_pw_w = (const float*)d_in[13];
  const float* sob_w    = (const float*)d_in[14];
  const float* sob_b    = (const float*)d_in[15];
  const float* rpe_w    = (const float*)d_in[16];
  const float* rpe_b    = (const float*)d_in[17];
  float* out = (float*)d_out;
  float* wsf = (float*)d_ws;
  unsigned short* xTbf  = (unsigned short*)(wsf + OFF_XTBF);
  unsigned short* qbf   = (unsigned short*)(wsf + OFF_QBF);
  unsigned short* kbf   = (unsigned short*)(wsf + OFF_KBF);
  unsigned short* vbf   = (unsigned short*)(wsf + OFF_VBF);
  unsigned short* xsT   = (unsigned short*)(wsf + OFF_XST);
  unsigned short* wbf   = (unsigned short*)(wsf + OFF_WBF);
  unsigned short* aoutT = (unsigned short*)(wsf + OFF_AOUTT);
  float* lepeT = wsf + OFF_LEPET;
  float* prO0  = wsf + OFF_PRO0;
  float* prO1  = wsf + OFF_PRO1;
  float* prS   = wsf + OFF_PRS;
  double* smapd = (double*)(wsf + OFF_SMAPD);
  double* weff  = (double*)(wsf + OFF_WEFF);

  k_prep        <<<257,             256, 0, stream>>>(qW, kW, vW, oW, qb, sob_w, sob_b, wbf, weff);
  k_transpose_bf<<<dim3(36, 2, 4),  256, 0, stream>>>(x, xTbf);
  k_qconv       <<<dim3(144, 4),    256, 0, stream>>>(xTbf, wbf, qb, qbf);
  k_smapd       <<<dim3(9, 8),      256, 0, stream>>>(x, weff, smapd);
  k_offset_pos  <<<4608,            256, 0, stream>>>(qbf, smapd, off_dw_w, off_dw_b,
                                                      ln_g, ln_b, off_pw_w, out);
  k_sample      <<<4608,            256, 0, stream>>>(xTbf, out, xsT);
  k_kvconv      <<<dim3(144, 4),    256, 0, stream>>>(xsT, wbf, kb, vb, kbf, vbf);
  k_lepe_t      <<<4608,            256, 0, stream>>>(qbf, rpe_w, rpe_b, lepeT);
  k_attn3       <<<dim3(36, 16, 2), 256, 0, stream>>>(qbf, kbf, vbf, prO0, prO1, prS);
  k_combine_t   <<<1152,            256, 0, stream>>>(prO0, prO1, prS, lepeT, aoutT);
  k_oconv       <<<dim3(144, 4),    256, 0, stream>>>(aoutT, wbf, ob, out + Y_OFF);
}

// Round 7
// 150.449 us; speedup vs baseline: 2.8559x; 1.1590x over previous
//
#include <hip/hip_runtime.h>
#include <hip/hip_bf16.h>
#include <math.h>

#define B_   4
#define C_   128
#define H_   48
#define W_   48
#define HW_  2304
#define CG_  64
#define DH_  32
#define SCALE_ 0.17677669529663687f   // 32^-0.5
#define QS_    (0.17677669529663687f * 1.4426950408889634f)  // SCALE * log2(e)
#define INVQ_  (1.0f / QS_)

// d_out layout (floats)
#define Y_OFF   0
#define POS_OFF 1179648
#define REF_OFF 1216512

// workspace layout (float offsets)
#define OFF_XTBF  0         // ushort[4][2304][128]  x^T bf16
#define OFF_QBF   589824    // ushort[4][2304][128]  q*QS bf16 [m][c]
#define OFF_KBF   1179648   // ushort[4][2304][128]  k bf16 [n][c]
#define OFF_VBF   1769472   // ushort[4][128][2304]  v bf16 [c][n] (k-slot permuted per 32-n group)
#define OFF_XST   2359296   // ushort[4][2304][128]  xs bf16 [p][c]
#define OFF_WBF   2949120   // ushort[4][16384]      qW,kW,vW,oW bf16
#define OFF_PRS   2981888   // float[4][16][2304]    partial rowsums
#define OFF_PROH  4161536   // _Float16[4][4·2304·128] partial O (fp16), 2359296 float-space
#define OFF_AOUTT 6594560   // ushort[4][2304][128]
#define OFF_SMAPD 7184384   // double[8][2304]
#define OFF_WEFF  7221248   // double[258]

typedef __attribute__((ext_vector_type(8))) short short8;
typedef __attribute__((ext_vector_type(4))) float f32x4;
typedef __attribute__((ext_vector_type(4))) _Float16 f16x4;

__device__ inline unsigned short f2bf(float f) {
  unsigned u = __float_as_uint(f);
  u += 0x7fff + ((u >> 16) & 1);     // RNE
  return (unsigned short)(u >> 16);
}
__device__ inline float bf2f(unsigned short s) {
  return __uint_as_float(((unsigned)s) << 16);
}

// pack 8 f32 -> short8 of bf16 via v_cvt_pk_bf16_f32 (RNE), 4 ops
__device__ inline short8 pack8(const f32x4 a, const f32x4 b) {
  union { unsigned u[4]; short8 s; } r;
  asm("v_cvt_pk_bf16_f32 %0, %1, %2" : "=v"(r.u[0]) : "v"(a[0]), "v"(a[1]));
  asm("v_cvt_pk_bf16_f32 %0, %1, %2" : "=v"(r.u[1]) : "v"(a[2]), "v"(a[3]));
  asm("v_cvt_pk_bf16_f32 %0, %1, %2" : "=v"(r.u[2]) : "v"(b[0]), "v"(b[1]));
  asm("v_cvt_pk_bf16_f32 %0, %1, %2" : "=v"(r.u[3]) : "v"(b[2]), "v"(b[3]));
  return r.s;
}

// ---------------- fused: transpose x -> xTbf (blocks 0..287), weights->bf16 (288..543), weff (544) ----------------
__global__ __launch_bounds__(256) void k_pre(const float* __restrict__ x,
                                             const float* __restrict__ qW, const float* __restrict__ kW,
                                             const float* __restrict__ vW, const float* __restrict__ oW,
                                             const float* __restrict__ qb,
                                             const float* __restrict__ sob_w, const float* __restrict__ sob_b,
                                             unsigned short* __restrict__ xTbf,
                                             unsigned short* __restrict__ wbf,
                                             double* __restrict__ weff) {
  int bx = blockIdx.x;
  if (bx < 288) {
    __shared__ float tile[64][65];
    int p0 = (bx % 36) * 64, c0 = ((bx / 36) & 1) * 64, b = bx / 72;
    for (int idx = threadIdx.x; idx < 4096; idx += 256) {
      int cr = idx >> 6, pc = idx & 63;
      tile[cr][pc] = x[((size_t)(b * C_) + c0 + cr) * HW_ + p0 + pc];
    }
    __syncthreads();
    for (int idx = threadIdx.x; idx < 4096; idx += 256) {
      int pr = idx >> 6, cc = idx & 63;
      xTbf[((size_t)(b * HW_) + p0 + pr) * C_ + c0 + cc] = f2bf(tile[cc][pr]);
    }
  } else if (bx < 544) {
    int t = (bx - 288) * 256 + threadIdx.x;   // 65536
    int which = t >> 14, i = t & 16383;
    const float* src = which == 0 ? qW : which == 1 ? kW : which == 2 ? vW : oW;
    wbf[t] = f2bf(src[i]);
  } else {
    int t = threadIdx.x;
    int g = t >> 7, i = t & 127;
    double acc = 0.0;
    for (int c = 0; c < 64; c++)
      acc += (double)sob_w[c] * (double)qW[(size_t)(g * 64 + c) * C_ + i];
    weff[t] = acc;
    if (t < 2) {
      double bb = (double)sob_b[0];
      for (int c = 0; c < 64; c++) bb += (double)sob_w[c] * (double)qb[t * 64 + c];
      weff[256 + t] = bb;
    }
  }
}

// ---------------- fused: q-conv MFMA (blocks 0..575) + fp64 sobel s-map (576..647) ----------------
__global__ __launch_bounds__(256, 4) void k_qconv_smapd(const unsigned short* __restrict__ xTbf,
                                                        const unsigned short* __restrict__ wbf,
                                                        const float* __restrict__ qb,
                                                        const float* __restrict__ x,
                                                        const double* __restrict__ weff,
                                                        unsigned short* __restrict__ qbf,
                                                        double* __restrict__ smapd) {
  int bx = blockIdx.x;
  if (bx < 576) {
    int t = threadIdx.x, w = t >> 6, l = t & 63, lg = l >> 4, lo = l & 15;
    int m0 = (bx % 144) * 16, b = bx / 144, o0 = w * 32;
    const unsigned short* xrow = xTbf + ((size_t)(b * HW_) + m0 + lo) * C_ + lg * 8;
    f32x4 acc[2] = {{0.f,0.f,0.f,0.f},{0.f,0.f,0.f,0.f}};
#pragma unroll
    for (int kb = 0; kb < 4; kb++) {
      short8 xf = *(const short8*)(xrow + kb * 32);
#pragma unroll
      for (int os = 0; os < 2; os++) {
        short8 wf = *(const short8*)(wbf + (size_t)(o0 + os * 16 + lo) * C_ + kb * 32 + lg * 8);
        acc[os] = __builtin_amdgcn_mfma_f32_16x16x32_bf16(xf, wf, acc[os], 0, 0, 0);
      }
    }
#pragma unroll
    for (int os = 0; os < 2; os++) {
      int o = o0 + os * 16 + lo;
      float bi = qb[o];
#pragma unroll
      for (int r = 0; r < 4; r++) {
        int m = m0 + lg * 4 + r;
        qbf[((size_t)(b * HW_) + m) * C_ + o] = f2bf((acc[os][r] + bi) * QS_);
      }
    }
  } else {
    int bb = bx - 576;
    int p = (bb % 9) * 256 + threadIdx.x;
    int bg = bb / 9;
    int b = bg >> 1, g = bg & 1;
    const float* xb = x + (size_t)b * C_ * HW_ + p;
    const double* wv = weff + g * 128;
    double acc = weff[256 + g];
#pragma unroll 8
    for (int i = 0; i < 128; i++) acc += wv[i] * (double)xb[(size_t)i * HW_];
    smapd[bg * HW_ + p] = acc;
  }
}

// ---------------- fused offset branch + sobel gate + pos/ref + bilinear sample ----------------
__global__ __launch_bounds__(256) void k_offpos_sample(const unsigned short* __restrict__ qbf,
                                                       const double* __restrict__ s_map,
                                                       const float* __restrict__ dw_w,
                                                       const float* __restrict__ dw_b,
                                                       const float* __restrict__ ln_g,
                                                       const float* __restrict__ ln_b,
                                                       const float* __restrict__ pw_w,
                                                       const unsigned short* __restrict__ xTbf,
                                                       float* __restrict__ out,
                                                       unsigned short* __restrict__ xsT) {
  int widx = blockIdx.x * 4 + (threadIdx.x >> 6);
  int lane = threadIdx.x & 63;
  int bg = widx / HW_;
  int p = widx - bg * HW_;
  int h = p / W_, w = p - h * W_;
  int b = bg >> 1, g = bg & 1;
  const unsigned short* qc = qbf + (size_t)(b * HW_) * C_ + g * 64 + lane;
  float tv = dw_b[lane];
#pragma unroll
  for (int dy = -1; dy <= 1; dy++)
#pragma unroll
    for (int dx = -1; dx <= 1; dx++) {
      int hh = h + dy, ww = w + dx;
      if (hh >= 0 && hh < H_ && ww >= 0 && ww < W_) {
        float wgt = dw_w[lane * 9 + (dy + 1) * 3 + (dx + 1)] * INVQ_;
        tv += wgt * bf2f(qc[(size_t)(hh * W_ + ww) * C_]);
      }
    }
  float ssum = tv, ssq = tv * tv;
#pragma unroll
  for (int msk = 32; msk; msk >>= 1) {
    ssum += __shfl_xor(ssum, msk, 64);
    ssq  += __shfl_xor(ssq,  msk, 64);
  }
  float mu  = ssum * (1.0f / 64.0f);
  float var = ssq * (1.0f / 64.0f) - mu * mu;
  float uu  = (tv - mu) * rsqrtf(var + 1e-5f) * ln_g[lane] + ln_b[lane];
  float gl = 0.5f * uu * (1.0f + erff(uu * 0.70710678118654752f));
  float p0 = pw_w[lane] * gl, p1 = pw_w[64 + lane] * gl;
#pragma unroll
  for (int msk = 32; msk; msk >>= 1) {
    p0 += __shfl_xor(p0, msk, 64);
    p1 += __shfl_xor(p1, msk, 64);
  }
  // all lanes now hold full sums; compute gate redundantly (broadcast loads)
  const double sobx[9] = {-1., 0., 1., -2., 0., 2., -1., 0., 1.};
  const double soby[9] = {-1., -2., -1., 0., 0., 0., 1., 2., 1.};
  float off_y = tanhf(p0) * (1.0f / 47.0f);
  float off_x = tanhf(p1) * (1.0f / 47.0f);
  const double* sm = s_map + bg * HW_;
  double gx = 0., gy = 0.;
#pragma unroll
  for (int dy = -1; dy <= 1; dy++)
#pragma unroll
    for (int dx = -1; dx <= 1; dx++) {
      int hh = h + dy, ww = w + dx;
      if (hh >= 0 && hh < H_ && ww >= 0 && ww < W_) {
        double sv = sm[hh * W_ + ww];
        gx += sobx[(dy + 1) * 3 + dx + 1] * sv;
        gy += soby[(dy + 1) * 3 + dx + 1] * sv;
      }
    }
  double mag = sqrt(gx * gx + gy * gy);
  float bin = mag > 0.5 ? 1.0f : 0.0f;
  float ry = ((h + 0.5f) / 47.0f) * 2.0f - 1.0f;
  float rx = ((w + 0.5f) / 47.0f) * 2.0f - 1.0f;
  float py = off_y + ry * bin;
  float px = off_x + rx * bin;
  if (lane == 0) {
    int pi = (bg * HW_ + p) * 2;
    out[POS_OFF + pi]     = py;
    out[POS_OFF + pi + 1] = px;
    out[REF_OFF + pi]     = ry;
    out[REF_OFF + pi + 1] = rx;
  }
  // bilinear sample with in-register pos
  float gxf = (px + 1.0f) * 0.5f * 47.0f;
  float gyf = (py + 1.0f) * 0.5f * 47.0f;
  float x0 = floorf(gxf), y0 = floorf(gyf);
  float wx1 = gxf - x0, wy1 = gyf - y0;
  float wx0 = 1.0f - wx1, wy0 = 1.0f - wy1;
  const unsigned short* base = xTbf + (size_t)(b * HW_) * C_ + g * 64 + lane;
  float acc = 0.0f;
#pragma unroll
  for (int cy = 0; cy < 2; cy++)
#pragma unroll
    for (int cx = 0; cx < 2; cx++) {
      float yy = y0 + (float)cy, xx = x0 + (float)cx;
      bool valid = (yy >= 0.f) && (yy < 48.f) && (xx >= 0.f) && (xx < 48.f);
      int yc = min(max((int)yy, 0), 47);
      int xc = min(max((int)xx, 0), 47);
      float wgt = (cy ? wy1 : wy0) * (cx ? wx1 : wx0);
      float vv = valid ? bf2f(base[(size_t)(yc * 48 + xc) * C_]) : 0.0f;
      acc += wgt * vv;
    }
  xsT[((size_t)(b * HW_) + p) * C_ + g * 64 + lane] = f2bf(acc);
}

// ---------------- k/v conv (MFMA): kbf[n][c]; vbf[c][n] written k-slot-permuted ----------------
__global__ __launch_bounds__(256, 4) void k_kvconv(const unsigned short* __restrict__ xsT,
                                                   const unsigned short* __restrict__ wbf,
                                                   const float* __restrict__ kbias,
                                                   const float* __restrict__ vbias,
                                                   unsigned short* __restrict__ kbf,
                                                   unsigned short* __restrict__ vbf) {
  int t = threadIdx.x, w = t >> 6, l = t & 63, lg = l >> 4, lo = l & 15;
  int n0 = blockIdx.x * 16, b = blockIdx.y, o0 = w * 32;
  const unsigned short* xrow = xsT + ((size_t)(b * HW_) + n0 + lo) * C_ + lg * 8;
  const unsigned short* wk = wbf + 16384;
  const unsigned short* wv = wbf + 32768;
  f32x4 ak[2] = {{0.f,0.f,0.f,0.f},{0.f,0.f,0.f,0.f}};
  f32x4 av[2] = {{0.f,0.f,0.f,0.f},{0.f,0.f,0.f,0.f}};
#pragma unroll
  for (int kb = 0; kb < 4; kb++) {
    short8 xf = *(const short8*)(xrow + kb * 32);
#pragma unroll
    for (int os = 0; os < 2; os++) {
      size_t wo = (size_t)(o0 + os * 16 + lo) * C_ + kb * 32 + lg * 8;
      short8 wkf = *(const short8*)(wk + wo);
      short8 wvf = *(const short8*)(wv + wo);
      ak[os] = __builtin_amdgcn_mfma_f32_16x16x32_bf16(xf, wkf, ak[os], 0, 0, 0);
      av[os] = __builtin_amdgcn_mfma_f32_16x16x32_bf16(wvf, xf, av[os], 0, 0, 0);
    }
  }
  int o32 = (n0 & 16) + lo;
  int vpos = (n0 & ~31) + ((o32 & 12) << 1) + (o32 & 3) + ((o32 >> 4) << 2);
#pragma unroll
  for (int os = 0; os < 2; os++) {
    int ok = o0 + os * 16 + lo;
    float bk_ = kbias[ok];
#pragma unroll
    for (int r = 0; r < 4; r++) {
      int n = n0 + lg * 4 + r;
      kbf[((size_t)(b * HW_) + n) * C_ + ok] = f2bf(ak[os][r] + bk_);
      int ov = o0 + os * 16 + lg * 4 + r;
      vbf[((size_t)(b * C_) + ov) * HW_ + vpos] = f2bf(av[os][r] + vbias[ov]);
    }
  }
}

// ---------------- MFMA flash attention v4: nsplit=4, full K+V prefetch, hw exp2 ----------------
#define ATTN_BODY(BK, BV, BKN, BVN, DOPREF)                                         \
  {                                                                                 \
    if (DOPREF) {                                                                   \
      _Pragma("unroll")                                                             \
      for (int sub = 0; sub < 4; sub++)                                             \
        BKN[sub] = *(const short8*)(kb_ + (size_t)(n0 + 64 + sub * 16 + lo) * C_);  \
      BVN[0] = *(const short8*)(vr0 + n0 + 64);                                     \
      BVN[1] = *(const short8*)(vr0 + n0 + 96);                                     \
      BVN[2] = *(const short8*)(vr1 + n0 + 64);                                     \
      BVN[3] = *(const short8*)(vr1 + n0 + 96);                                     \
    }                                                                               \
    f32x4 z = {0.f, 0.f, 0.f, 0.f};                                                 \
    f32x4 s0 = __builtin_amdgcn_mfma_f32_16x16x32_bf16(BK[0], aq, z, 0, 0, 0);      \
    f32x4 s1 = __builtin_amdgcn_mfma_f32_16x16x32_bf16(BK[1], aq, z, 0, 0, 0);      \
    f32x4 s2 = __builtin_amdgcn_mfma_f32_16x16x32_bf16(BK[2], aq, z, 0, 0, 0);      \
    f32x4 s3 = __builtin_amdgcn_mfma_f32_16x16x32_bf16(BK[3], aq, z, 0, 0, 0);      \
    _Pragma("unroll")                                                               \
    for (int r = 0; r < 4; r++) {                                                   \
      float e0, e1, e2, e3;                                                         \
      asm("v_exp_f32 %0, %1" : "=v"(e0) : "v"(s0[r]));                              \
      asm("v_exp_f32 %0, %1" : "=v"(e1) : "v"(s1[r]));                              \
      asm("v_exp_f32 %0, %1" : "=v"(e2) : "v"(s2[r]));                              \
      asm("v_exp_f32 %0, %1" : "=v"(e3) : "v"(s3[r]));                              \
      s0[r] = e0; s1[r] = e1; s2[r] = e2; s3[r] = e3;                               \
      rsum += (e0 + e1) + (e2 + e3);                                                \
    }                                                                               \
    short8 pa0 = pack8(s0, s1), pa1 = pack8(s2, s3);                                \
    acc0 = __builtin_amdgcn_mfma_f32_16x16x32_bf16(pa0, BV[0], acc0, 0, 0, 0);      \
    acc0 = __builtin_amdgcn_mfma_f32_16x16x32_bf16(pa1, BV[1], acc0, 0, 0, 0);      \
    acc1 = __builtin_amdgcn_mfma_f32_16x16x32_bf16(pa0, BV[2], acc1, 0, 0, 0);      \
    acc1 = __builtin_amdgcn_mfma_f32_16x16x32_bf16(pa1, BV[3], acc1, 0, 0, 0);      \
    n0 += 64;                                                                       \
  }

__global__ __launch_bounds__(256, 4) void k_attn4(const unsigned short* __restrict__ qbf,
                                                  const unsigned short* __restrict__ kbf,
                                                  const unsigned short* __restrict__ vpf,
                                                  _Float16* __restrict__ prOh,
                                                  float* __restrict__ prS) {
  int t = threadIdx.x, w = t >> 6, l = t & 63, lg = l >> 4, lo = l & 15;
  int bh = blockIdx.y, b = bh >> 2, hd = bh & 3, nz = blockIdx.z;
  int cb = hd * 32;
  int m0 = blockIdx.x * 64 + w * 16;
  short8 aq = *(const short8*)(qbf + ((size_t)(b * HW_) + m0 + lo) * C_ + cb + lg * 8);
  const unsigned short* kb_ = kbf + (size_t)(b * HW_) * C_ + cb + lg * 8;
  const unsigned short* vr0 = vpf + (size_t)(b * C_ + cb + lo) * HW_ + lg * 8;
  const unsigned short* vr1 = vr0 + (size_t)16 * HW_;
  f32x4 acc0 = {0.f,0.f,0.f,0.f}, acc1 = {0.f,0.f,0.f,0.f};
  float rsum = 0.f;
  int n0 = nz * 576;
  short8 bkA[4], bkB[4], bvA[4], bvB[4];
#pragma unroll
  for (int sub = 0; sub < 4; sub++)
    bkA[sub] = *(const short8*)(kb_ + (size_t)(n0 + sub * 16 + lo) * C_);
  bvA[0] = *(const short8*)(vr0 + n0);
  bvA[1] = *(const short8*)(vr0 + n0 + 32);
  bvA[2] = *(const short8*)(vr1 + n0);
  bvA[3] = *(const short8*)(vr1 + n0 + 32);
  for (int i4 = 0; i4 < 4; i4++) {
    ATTN_BODY(bkA, bvA, bkB, bvB, true)
    ATTN_BODY(bkB, bvB, bkA, bvA, (i4 < 3))
  }
  ATTN_BODY(bkA, bvA, bkB, bvB, false)
  rsum += __shfl_xor(rsum, 16, 64);
  rsum += __shfl_xor(rsum, 32, 64);
  _Float16* pr = prOh + (size_t)nz * (B_ * HW_ * C_);
#pragma unroll
  for (int r = 0; r < 4; r++) {
    int m = m0 + lg * 4 + r;
    size_t oi = ((size_t)(b * HW_) + m) * C_ + cb;
    pr[oi + lo] = (_Float16)acc0[r];
    pr[oi + 16 + lo] = (_Float16)acc1[r];
  }
  if (l < 16)
    prS[((size_t)(nz * 16) + bh) * HW_ + m0 + lo] = rsum;
}

// ---------------- combine + inline LEPE: aoutT[m][c] = bf16(ΣO/Σr + lepe) ----------------
__global__ __launch_bounds__(256) void k_combine2(const _Float16* __restrict__ prOh,
                                                  const float* __restrict__ prS,
                                                  const unsigned short* __restrict__ qbf,
                                                  const float* __restrict__ rpe_w,
                                                  const float* __restrict__ rpe_b,
                                                  unsigned short* __restrict__ aoutT) {
  size_t oi = ((size_t)blockIdx.x * 256 + threadIdx.x) * 4;
  int c = (int)(oi & 127);
  size_t bm = oi >> 7;                 // b*HW + m
  int b = (int)(bm / HW_);
  int m = (int)(bm - (size_t)b * HW_);
  int hd = c >> 5;
  int bh = b * 4 + hd;
  float rs = 0.f;
  float o[4] = {0.f, 0.f, 0.f, 0.f};
#pragma unroll
  for (int nz = 0; nz < 4; nz++) {
    rs += prS[((size_t)(nz * 16) + bh) * HW_ + m];
    f16x4 v = *(const f16x4*)(prOh + (size_t)nz * (B_ * HW_ * C_) + oi);
#pragma unroll
    for (int j = 0; j < 4; j++) o[j] += (float)v[j];
  }
  float inv = 1.0f / rs;
  // LEPE: depthwise 3x3 over q at (h,w), channels c..c+3
  int h = m / W_, w = m - (m / W_) * W_;
  float lp[4] = {rpe_b[c], rpe_b[c + 1], rpe_b[c + 2], rpe_b[c + 3]};
#pragma unroll
  for (int dy = -1; dy <= 1; dy++)
#pragma unroll
    for (int dx = -1; dx <= 1; dx++) {
      int hh = h + dy, ww = w + dx;
      if (hh >= 0 && hh < H_ && ww >= 0 && ww < W_) {
        int idx = (dy + 1) * 3 + (dx + 1);
        ushort4 q4 = *(const ushort4*)(qbf + ((size_t)(b * HW_) + hh * W_ + ww) * C_ + c);
        lp[0] += rpe_w[(c + 0) * 9 + idx] * INVQ_ * bf2f(q4.x);
        lp[1] += rpe_w[(c + 1) * 9 + idx] * INVQ_ * bf2f(q4.y);
        lp[2] += rpe_w[(c + 2) * 9 + idx] * INVQ_ * bf2f(q4.z);
        lp[3] += rpe_w[(c + 3) * 9 + idx] * INVQ_ * bf2f(q4.w);
      }
    }
  ushort4 pk;
  pk.x = f2bf(o[0] * inv + lp[0]);
  pk.y = f2bf(o[1] * inv + lp[1]);
  pk.z = f2bf(o[2] * inv + lp[2]);
  pk.w = f2bf(o[3] * inv + lp[3]);
  *(ushort4*)(aoutT + oi) = pk;
}

// ---------------- o-conv (MFMA): y[c][m] = oW·aoutT + ob ----------------
__global__ __launch_bounds__(256, 4) void k_oconv(const unsigned short* __restrict__ aoutT,
                                                  const unsigned short* __restrict__ wbf,
                                                  const float* __restrict__ ob_,
                                                  float* __restrict__ y) {
  int t = threadIdx.x, w = t >> 6, l = t & 63, lg = l >> 4, lo = l & 15;
  int m0 = blockIdx.x * 16, b = blockIdx.y, o0 = w * 32;
  const unsigned short* xrow = aoutT + ((size_t)(b * HW_) + m0 + lo) * C_ + lg * 8;
  const unsigned short* wo = wbf + 49152;
  f32x4 acc[2] = {{0.f,0.f,0.f,0.f},{0.f,0.f,0.f,0.f}};
#pragma unroll
  for (int kb = 0; kb < 4; kb++) {
    short8 xf = *(const short8*)(xrow + kb * 32);
#pragma unroll
    for (int os = 0; os < 2; os++) {
      short8 wf = *(const short8*)(wo + (size_t)(o0 + os * 16 + lo) * C_ + kb * 32 + lg * 8);
      acc[os] = __builtin_amdgcn_mfma_f32_16x16x32_bf16(wf, xf, acc[os], 0, 0, 0);
    }
  }
#pragma unroll
  for (int os = 0; os < 2; os++)
#pragma unroll
    for (int r = 0; r < 4; r++) {
      int o = o0 + os * 16 + lg * 4 + r;
      y[((size_t)(b * C_) + o) * HW_ + m0 + lo] = acc[os][r] + ob_[o];
    }
}

extern "C" void kernel_launch(void* const* d_in, const int* in_sizes, int n_in,
                              void* d_out, int out_size, void* d_ws, size_t ws_size,
                              hipStream_t stream) {
  const float* x        = (const float*)d_in[0];
  const float* qW       = (const float*)d_in[1];
  const float* qb       = (const float*)d_in[2];
  const float* kW       = (const float*)d_in[3];
  const float* kb       = (const float*)d_in[4];
  const float* vW       = (const float*)d_in[5];
  const float* vb       = (const float*)d_in[6];
  const float* oW       = (const float*)d_in[7];
  const float* ob       = (const float*)d_in[8];
  const float* off_dw_w = (const float*)d_in[9];
  const float* off_dw_b = (const float*)d_in[10];
  const float* ln_g     = (const float*)d_in[11];
  const float* ln_b     = (const float*)d_in[12];
  const float* off_pw_w = (const float*)d_in[13];
  const float* sob_w    = (const float*)d_in[14];
  const float* sob_b    = (const float*)d_in[15];
  const float* rpe_w    = (const float*)d_in[16];
  const float* rpe_b    = (const float*)d_in[17];
  float* out = (float*)d_out;
  float* wsf = (float*)d_ws;
  unsigned short* xTbf  = (unsigned short*)(wsf + OFF_XTBF);
  unsigned short* qbf   = (unsigned short*)(wsf + OFF_QBF);
  unsigned short* kbf   = (unsigned short*)(wsf + OFF_KBF);
  unsigned short* vbf   = (unsigned short*)(wsf + OFF_VBF);
  unsigned short* xsT   = (unsigned short*)(wsf + OFF_XST);
  unsigned short* wbf   = (unsigned short*)(wsf + OFF_WBF);
  unsigned short* aoutT = (unsigned short*)(wsf + OFF_AOUTT);
  float* prS   = wsf + OFF_PRS;
  _Float16* prOh = (_Float16*)(wsf + OFF_PROH);
  double* smapd = (double*)(wsf + OFF_SMAPD);
  double* weff  = (double*)(wsf + OFF_WEFF);

  k_pre          <<<545,             256, 0, stream>>>(x, qW, kW, vW, oW, qb, sob_w, sob_b,
                                                       xTbf, wbf, weff);
  k_qconv_smapd  <<<648,             256, 0, stream>>>(xTbf, wbf, qb, x, weff, qbf, smapd);
  k_offpos_sample<<<4608,            256, 0, stream>>>(qbf, smapd, off_dw_w, off_dw_b,
                                                       ln_g, ln_b, off_pw_w, xTbf, out, xsT);
  k_kvconv       <<<dim3(144, 4),    256, 0, stream>>>(xsT, wbf, kb, vb, kbf, vbf);
  k_attn4        <<<dim3(36, 16, 4), 256, 0, stream>>>(qbf, kbf, vbf, prOh, prS);
  k_combine2     <<<1152,            256, 0, stream>>>(prOh, prS, qbf, rpe_w, rpe_b, aoutT);
  k_oconv        <<<dim3(144, 4),    256, 0, stream>>>(aoutT, wbf, ob, out + Y_OFF);
}

// Round 8
// 124.644 us; speedup vs baseline: 3.4471x; 1.2070x over previous
//
#include <hip/hip_runtime.h>
#include <hip/hip_bf16.h>
#include <math.h>

#define B_   4
#define C_   128
#define H_   48
#define W_   48
#define HW_  2304
#define CG_  64
#define DH_  32
#define SCALE_ 0.17677669529663687f   // 32^-0.5
#define QS_    (0.17677669529663687f * 1.4426950408889634f)  // SCALE * log2(e)
#define INVQ_  (1.0f / QS_)

// d_out layout (floats)
#define Y_OFF   0
#define POS_OFF 1179648
#define REF_OFF 1216512

// workspace layout (float offsets)
#define OFF_XTBF  0         // ushort[4][2304][128]  x^T bf16
#define OFF_QBF   589824    // ushort[4][2304][128]  q*QS bf16 [m][c]
#define OFF_KBF   1179648   // ushort[4][2304][128]  k bf16 [n][c]
#define OFF_VBF   1769472   // ushort[4][128][2304]  v bf16 [c][n] (k-slot permuted per 32-n group)
#define OFF_XST   2359296   // ushort[4][2304][128]  xs bf16 [p][c]
#define OFF_WBF   2949120   // ushort[4][16384]      qW,kW,vW,oW bf16
#define OFF_PRS   2981888   // float[4][16][2304]    partial rowsums
#define OFF_PROH  4161536   // _Float16[4][4·2304·128] partial O (fp16), 2359296 float-space
#define OFF_AOUTT 6594560   // ushort[4][2304][128]
#define OFF_SMAPD 7184384   // double[8][2304]
#define OFF_WEFF  7221248   // double[258]

typedef __attribute__((ext_vector_type(8))) short short8;
typedef __attribute__((ext_vector_type(4))) float f32x4;
typedef __attribute__((ext_vector_type(4))) _Float16 f16x4;

__device__ inline unsigned short f2bf(float f) {
  unsigned u = __float_as_uint(f);
  u += 0x7fff + ((u >> 16) & 1);     // RNE
  return (unsigned short)(u >> 16);
}
__device__ inline float bf2f(unsigned short s) {
  return __uint_as_float(((unsigned)s) << 16);
}

// pack 8 f32 -> short8 of bf16 via v_cvt_pk_bf16_f32 (RNE), 4 ops
__device__ inline short8 pack8(const f32x4 a, const f32x4 b) {
  union { unsigned u[4]; short8 s; } r;
  asm("v_cvt_pk_bf16_f32 %0, %1, %2" : "=v"(r.u[0]) : "v"(a[0]), "v"(a[1]));
  asm("v_cvt_pk_bf16_f32 %0, %1, %2" : "=v"(r.u[1]) : "v"(a[2]), "v"(a[3]));
  asm("v_cvt_pk_bf16_f32 %0, %1, %2" : "=v"(r.u[2]) : "v"(b[0]), "v"(b[1]));
  asm("v_cvt_pk_bf16_f32 %0, %1, %2" : "=v"(r.u[3]) : "v"(b[2]), "v"(b[3]));
  return r.s;
}

// ---------------- fused: transpose x -> xTbf (blocks 0..287), weights->bf16 (288..543), weff (544) ----------------
__global__ __launch_bounds__(256) void k_pre(const float* __restrict__ x,
                                             const float* __restrict__ qW, const float* __restrict__ kW,
                                             const float* __restrict__ vW, const float* __restrict__ oW,
                                             const float* __restrict__ qb,
                                             const float* __restrict__ sob_w, const float* __restrict__ sob_b,
                                             unsigned short* __restrict__ xTbf,
                                             unsigned short* __restrict__ wbf,
                                             double* __restrict__ weff) {
  int bx = blockIdx.x;
  if (bx < 288) {
    __shared__ float tile[64][65];
    int p0 = (bx % 36) * 64, c0 = ((bx / 36) & 1) * 64, b = bx / 72;
    for (int idx = threadIdx.x; idx < 4096; idx += 256) {
      int cr = idx >> 6, pc = idx & 63;
      tile[cr][pc] = x[((size_t)(b * C_) + c0 + cr) * HW_ + p0 + pc];
    }
    __syncthreads();
    for (int idx = threadIdx.x; idx < 4096; idx += 256) {
      int pr = idx >> 6, cc = idx & 63;
      xTbf[((size_t)(b * HW_) + p0 + pr) * C_ + c0 + cc] = f2bf(tile[cc][pr]);
    }
  } else if (bx < 544) {
    int t = (bx - 288) * 256 + threadIdx.x;   // 65536
    int which = t >> 14, i = t & 16383;
    const float* src = which == 0 ? qW : which == 1 ? kW : which == 2 ? vW : oW;
    wbf[t] = f2bf(src[i]);
  } else {
    int t = threadIdx.x;
    int g = t >> 7, i = t & 127;
    double acc = 0.0;
    for (int c = 0; c < 64; c++)
      acc += (double)sob_w[c] * (double)qW[(size_t)(g * 64 + c) * C_ + i];
    weff[t] = acc;
    if (t < 2) {
      double bb = (double)sob_b[0];
      for (int c = 0; c < 64; c++) bb += (double)sob_w[c] * (double)qb[t * 64 + c];
      weff[256 + t] = bb;
    }
  }
}

// ---------------- fused: q-conv MFMA (blocks 0..575) + fp64 sobel s-map (576..647) ----------------
__global__ __launch_bounds__(256, 4) void k_qconv_smapd(const unsigned short* __restrict__ xTbf,
                                                        const unsigned short* __restrict__ wbf,
                                                        const float* __restrict__ qb,
                                                        const float* __restrict__ x,
                                                        const double* __restrict__ weff,
                                                        unsigned short* __restrict__ qbf,
                                                        double* __restrict__ smapd) {
  int bx = blockIdx.x;
  if (bx < 576) {
    int t = threadIdx.x, w = t >> 6, l = t & 63, lg = l >> 4, lo = l & 15;
    int m0 = (bx % 144) * 16, b = bx / 144, o0 = w * 32;
    const unsigned short* xrow = xTbf + ((size_t)(b * HW_) + m0 + lo) * C_ + lg * 8;
    f32x4 acc[2] = {{0.f,0.f,0.f,0.f},{0.f,0.f,0.f,0.f}};
#pragma unroll
    for (int kb = 0; kb < 4; kb++) {
      short8 xf = *(const short8*)(xrow + kb * 32);
#pragma unroll
      for (int os = 0; os < 2; os++) {
        short8 wf = *(const short8*)(wbf + (size_t)(o0 + os * 16 + lo) * C_ + kb * 32 + lg * 8);
        acc[os] = __builtin_amdgcn_mfma_f32_16x16x32_bf16(xf, wf, acc[os], 0, 0, 0);
      }
    }
#pragma unroll
    for (int os = 0; os < 2; os++) {
      int o = o0 + os * 16 + lo;
      float bi = qb[o];
#pragma unroll
      for (int r = 0; r < 4; r++) {
        int m = m0 + lg * 4 + r;
        qbf[((size_t)(b * HW_) + m) * C_ + o] = f2bf((acc[os][r] + bi) * QS_);
      }
    }
  } else {
    int bb = bx - 576;
    int p = (bb % 9) * 256 + threadIdx.x;
    int bg = bb / 9;
    int b = bg >> 1, g = bg & 1;
    const float* xb = x + (size_t)b * C_ * HW_ + p;
    const double* wv = weff + g * 128;
    double acc = weff[256 + g];
#pragma unroll 8
    for (int i = 0; i < 128; i++) acc += wv[i] * (double)xb[(size_t)i * HW_];
    smapd[bg * HW_ + p] = acc;
  }
}

// ---------------- fused offset branch + sobel gate + pos/ref + bilinear sample ----------------
__global__ __launch_bounds__(256) void k_offpos_sample(const unsigned short* __restrict__ qbf,
                                                       const double* __restrict__ s_map,
                                                       const float* __restrict__ dw_w,
                                                       const float* __restrict__ dw_b,
                                                       const float* __restrict__ ln_g,
                                                       const float* __restrict__ ln_b,
                                                       const float* __restrict__ pw_w,
                                                       const unsigned short* __restrict__ xTbf,
                                                       float* __restrict__ out,
                                                       unsigned short* __restrict__ xsT) {
  int widx = blockIdx.x * 4 + (threadIdx.x >> 6);
  int lane = threadIdx.x & 63;
  int bg = widx / HW_;
  int p = widx - bg * HW_;
  int h = p / W_, w = p - h * W_;
  int b = bg >> 1, g = bg & 1;
  const unsigned short* qc = qbf + (size_t)(b * HW_) * C_ + g * 64 + lane;
  float tv = dw_b[lane];
#pragma unroll
  for (int dy = -1; dy <= 1; dy++)
#pragma unroll
    for (int dx = -1; dx <= 1; dx++) {
      int hh = h + dy, ww = w + dx;
      if (hh >= 0 && hh < H_ && ww >= 0 && ww < W_) {
        float wgt = dw_w[lane * 9 + (dy + 1) * 3 + (dx + 1)] * INVQ_;
        tv += wgt * bf2f(qc[(size_t)(hh * W_ + ww) * C_]);
      }
    }
  float ssum = tv, ssq = tv * tv;
#pragma unroll
  for (int msk = 32; msk; msk >>= 1) {
    ssum += __shfl_xor(ssum, msk, 64);
    ssq  += __shfl_xor(ssq,  msk, 64);
  }
  float mu  = ssum * (1.0f / 64.0f);
  float var = ssq * (1.0f / 64.0f) - mu * mu;
  float uu  = (tv - mu) * rsqrtf(var + 1e-5f) * ln_g[lane] + ln_b[lane];
  float gl = 0.5f * uu * (1.0f + erff(uu * 0.70710678118654752f));
  float p0 = pw_w[lane] * gl, p1 = pw_w[64 + lane] * gl;
#pragma unroll
  for (int msk = 32; msk; msk >>= 1) {
    p0 += __shfl_xor(p0, msk, 64);
    p1 += __shfl_xor(p1, msk, 64);
  }
  // all lanes now hold full sums; compute gate redundantly (broadcast loads)
  const double sobx[9] = {-1., 0., 1., -2., 0., 2., -1., 0., 1.};
  const double soby[9] = {-1., -2., -1., 0., 0., 0., 1., 2., 1.};
  float off_y = tanhf(p0) * (1.0f / 47.0f);
  float off_x = tanhf(p1) * (1.0f / 47.0f);
  const double* sm = s_map + bg * HW_;
  double gx = 0., gy = 0.;
#pragma unroll
  for (int dy = -1; dy <= 1; dy++)
#pragma unroll
    for (int dx = -1; dx <= 1; dx++) {
      int hh = h + dy, ww = w + dx;
      if (hh >= 0 && hh < H_ && ww >= 0 && ww < W_) {
        double sv = sm[hh * W_ + ww];
        gx += sobx[(dy + 1) * 3 + dx + 1] * sv;
        gy += soby[(dy + 1) * 3 + dx + 1] * sv;
      }
    }
  double mag = sqrt(gx * gx + gy * gy);
  float bin = mag > 0.5 ? 1.0f : 0.0f;
  float ry = ((h + 0.5f) / 47.0f) * 2.0f - 1.0f;
  float rx = ((w + 0.5f) / 47.0f) * 2.0f - 1.0f;
  float py = off_y + ry * bin;
  float px = off_x + rx * bin;
  if (lane == 0) {
    int pi = (bg * HW_ + p) * 2;
    out[POS_OFF + pi]     = py;
    out[POS_OFF + pi + 1] = px;
    out[REF_OFF + pi]     = ry;
    out[REF_OFF + pi + 1] = rx;
  }
  // bilinear sample with in-register pos
  float gxf = (px + 1.0f) * 0.5f * 47.0f;
  float gyf = (py + 1.0f) * 0.5f * 47.0f;
  float x0 = floorf(gxf), y0 = floorf(gyf);
  float wx1 = gxf - x0, wy1 = gyf - y0;
  float wx0 = 1.0f - wx1, wy0 = 1.0f - wy1;
  const unsigned short* base = xTbf + (size_t)(b * HW_) * C_ + g * 64 + lane;
  float acc = 0.0f;
#pragma unroll
  for (int cy = 0; cy < 2; cy++)
#pragma unroll
    for (int cx = 0; cx < 2; cx++) {
      float yy = y0 + (float)cy, xx = x0 + (float)cx;
      bool valid = (yy >= 0.f) && (yy < 48.f) && (xx >= 0.f) && (xx < 48.f);
      int yc = min(max((int)yy, 0), 47);
      int xc = min(max((int)xx, 0), 47);
      float wgt = (cy ? wy1 : wy0) * (cx ? wx1 : wx0);
      float vv = valid ? bf2f(base[(size_t)(yc * 48 + xc) * C_]) : 0.0f;
      acc += wgt * vv;
    }
  xsT[((size_t)(b * HW_) + p) * C_ + g * 64 + lane] = f2bf(acc);
}

// ---------------- k/v conv (MFMA): kbf[n][c]; vbf[c][n] written k-slot-permuted ----------------
__global__ __launch_bounds__(256, 4) void k_kvconv(const unsigned short* __restrict__ xsT,
                                                   const unsigned short* __restrict__ wbf,
                                                   const float* __restrict__ kbias,
                                                   const float* __restrict__ vbias,
                                                   unsigned short* __restrict__ kbf,
                                                   unsigned short* __restrict__ vbf) {
  int t = threadIdx.x, w = t >> 6, l = t & 63, lg = l >> 4, lo = l & 15;
  int n0 = blockIdx.x * 16, b = blockIdx.y, o0 = w * 32;
  const unsigned short* xrow = xsT + ((size_t)(b * HW_) + n0 + lo) * C_ + lg * 8;
  const unsigned short* wk = wbf + 16384;
  const unsigned short* wv = wbf + 32768;
  f32x4 ak[2] = {{0.f,0.f,0.f,0.f},{0.f,0.f,0.f,0.f}};
  f32x4 av[2] = {{0.f,0.f,0.f,0.f},{0.f,0.f,0.f,0.f}};
#pragma unroll
  for (int kb = 0; kb < 4; kb++) {
    short8 xf = *(const short8*)(xrow + kb * 32);
#pragma unroll
    for (int os = 0; os < 2; os++) {
      size_t wo = (size_t)(o0 + os * 16 + lo) * C_ + kb * 32 + lg * 8;
      short8 wkf = *(const short8*)(wk + wo);
      short8 wvf = *(const short8*)(wv + wo);
      ak[os] = __builtin_amdgcn_mfma_f32_16x16x32_bf16(xf, wkf, ak[os], 0, 0, 0);
      av[os] = __builtin_amdgcn_mfma_f32_16x16x32_bf16(wvf, xf, av[os], 0, 0, 0);
    }
  }
  int o32 = (n0 & 16) + lo;
  int vpos = (n0 & ~31) + ((o32 & 12) << 1) + (o32 & 3) + ((o32 >> 4) << 2);
#pragma unroll
  for (int os = 0; os < 2; os++) {
    int ok = o0 + os * 16 + lo;
    float bk_ = kbias[ok];
#pragma unroll
    for (int r = 0; r < 4; r++) {
      int n = n0 + lg * 4 + r;
      kbf[((size_t)(b * HW_) + n) * C_ + ok] = f2bf(ak[os][r] + bk_);
      int ov = o0 + os * 16 + lg * 4 + r;
      vbf[((size_t)(b * C_) + ov) * HW_ + vpos] = f2bf(av[os][r] + vbias[ov]);
    }
  }
}

// ---------------- MFMA flash attention v5: 32 m-rows/wave, staggered dual-tile ----------------
#define EXPROW(SV, RS)                                                              \
  _Pragma("unroll")                                                                 \
  for (int r = 0; r < 4; r++) {                                                     \
    float e0, e1, e2, e3;                                                           \
    asm("v_exp_f32 %0, %1" : "=v"(e0) : "v"(SV##0[r]));                             \
    asm("v_exp_f32 %0, %1" : "=v"(e1) : "v"(SV##1[r]));                             \
    asm("v_exp_f32 %0, %1" : "=v"(e2) : "v"(SV##2[r]));                             \
    asm("v_exp_f32 %0, %1" : "=v"(e3) : "v"(SV##3[r]));                             \
    SV##0[r] = e0; SV##1[r] = e1; SV##2[r] = e2; SV##3[r] = e3;                     \
    RS += (e0 + e1) + (e2 + e3);                                                    \
  }

#define ATTN_BODY5(BK, BKN, DOPREF)                                                 \
  {                                                                                 \
    short8 bv0 = *(const short8*)(vr0 + n0);                                        \
    short8 bv1 = *(const short8*)(vr0 + n0 + 32);                                   \
    short8 bv2 = *(const short8*)(vr1 + n0);                                        \
    short8 bv3 = *(const short8*)(vr1 + n0 + 32);                                   \
    if (DOPREF) {                                                                   \
      _Pragma("unroll")                                                             \
      for (int sub = 0; sub < 4; sub++)                                             \
        BKN[sub] = *(const short8*)(kb_ + (size_t)(n0 + 64 + sub * 16 + lo) * C_);  \
    }                                                                               \
    f32x4 z = {0.f, 0.f, 0.f, 0.f};                                                 \
    __builtin_amdgcn_s_setprio(1);                                                  \
    f32x4 s0 = __builtin_amdgcn_mfma_f32_16x16x32_bf16(BK[0], aq0, z, 0, 0, 0);     \
    f32x4 s1 = __builtin_amdgcn_mfma_f32_16x16x32_bf16(BK[1], aq0, z, 0, 0, 0);     \
    f32x4 s2 = __builtin_amdgcn_mfma_f32_16x16x32_bf16(BK[2], aq0, z, 0, 0, 0);     \
    f32x4 s3 = __builtin_amdgcn_mfma_f32_16x16x32_bf16(BK[3], aq0, z, 0, 0, 0);     \
    __builtin_amdgcn_s_setprio(0);                                                  \
    EXPROW(s, rsum0)                                                                \
    short8 pa0 = pack8(s0, s1), pa1 = pack8(s2, s3);                                \
    __builtin_amdgcn_s_setprio(1);                                                  \
    f32x4 t0 = __builtin_amdgcn_mfma_f32_16x16x32_bf16(BK[0], aq1, z, 0, 0, 0);     \
    f32x4 t1 = __builtin_amdgcn_mfma_f32_16x16x32_bf16(BK[1], aq1, z, 0, 0, 0);     \
    f32x4 t2 = __builtin_amdgcn_mfma_f32_16x16x32_bf16(BK[2], aq1, z, 0, 0, 0);     \
    f32x4 t3 = __builtin_amdgcn_mfma_f32_16x16x32_bf16(BK[3], aq1, z, 0, 0, 0);     \
    acc00 = __builtin_amdgcn_mfma_f32_16x16x32_bf16(pa0, bv0, acc00, 0, 0, 0);      \
    acc00 = __builtin_amdgcn_mfma_f32_16x16x32_bf16(pa1, bv1, acc00, 0, 0, 0);      \
    acc01 = __builtin_amdgcn_mfma_f32_16x16x32_bf16(pa0, bv2, acc01, 0, 0, 0);      \
    acc01 = __builtin_amdgcn_mfma_f32_16x16x32_bf16(pa1, bv3, acc01, 0, 0, 0);      \
    __builtin_amdgcn_s_setprio(0);                                                  \
    EXPROW(t, rsum1)                                                                \
    short8 pb0 = pack8(t0, t1), pb1 = pack8(t2, t3);                                \
    __builtin_amdgcn_s_setprio(1);                                                  \
    acc10 = __builtin_amdgcn_mfma_f32_16x16x32_bf16(pb0, bv0, acc10, 0, 0, 0);      \
    acc10 = __builtin_amdgcn_mfma_f32_16x16x32_bf16(pb1, bv1, acc10, 0, 0, 0);      \
    acc11 = __builtin_amdgcn_mfma_f32_16x16x32_bf16(pb0, bv2, acc11, 0, 0, 0);      \
    acc11 = __builtin_amdgcn_mfma_f32_16x16x32_bf16(pb1, bv3, acc11, 0, 0, 0);      \
    __builtin_amdgcn_s_setprio(0);                                                  \
    n0 += 64;                                                                       \
  }

__global__ __launch_bounds__(256, 3) void k_attn5(const unsigned short* __restrict__ qbf,
                                                  const unsigned short* __restrict__ kbf,
                                                  const unsigned short* __restrict__ vpf,
                                                  _Float16* __restrict__ prOh,
                                                  float* __restrict__ prS) {
  int t = threadIdx.x, w = t >> 6, l = t & 63, lg = l >> 4, lo = l & 15;
  int bh = blockIdx.y, b = bh >> 2, hd = bh & 3, nz = blockIdx.z;
  int cb = hd * 32;
  int m0 = blockIdx.x * 128 + w * 32;
  const unsigned short* qrow = qbf + ((size_t)(b * HW_) + m0 + lo) * C_ + cb + lg * 8;
  short8 aq0 = *(const short8*)qrow;
  short8 aq1 = *(const short8*)(qrow + (size_t)16 * C_);
  const unsigned short* kb_ = kbf + (size_t)(b * HW_) * C_ + cb + lg * 8;
  const unsigned short* vr0 = vpf + (size_t)(b * C_ + cb + lo) * HW_ + lg * 8;
  const unsigned short* vr1 = vr0 + (size_t)16 * HW_;
  f32x4 acc00 = {0.f,0.f,0.f,0.f}, acc01 = {0.f,0.f,0.f,0.f};
  f32x4 acc10 = {0.f,0.f,0.f,0.f}, acc11 = {0.f,0.f,0.f,0.f};
  float rsum0 = 0.f, rsum1 = 0.f;
  int n0 = nz * 576;
  short8 bkA[4], bkB[4];
#pragma unroll
  for (int sub = 0; sub < 4; sub++)
    bkA[sub] = *(const short8*)(kb_ + (size_t)(n0 + sub * 16 + lo) * C_);
  for (int i4 = 0; i4 < 4; i4++) {
    ATTN_BODY5(bkA, bkB, true)
    ATTN_BODY5(bkB, bkA, (i4 < 3))
  }
  ATTN_BODY5(bkA, bkB, false)
  rsum0 += __shfl_xor(rsum0, 16, 64);
  rsum0 += __shfl_xor(rsum0, 32, 64);
  rsum1 += __shfl_xor(rsum1, 16, 64);
  rsum1 += __shfl_xor(rsum1, 32, 64);
  _Float16* pr = prOh + (size_t)nz * (B_ * HW_ * C_);
#pragma unroll
  for (int r = 0; r < 4; r++) {
    int m = m0 + lg * 4 + r;
    size_t oi = ((size_t)(b * HW_) + m) * C_ + cb;
    pr[oi + lo] = (_Float16)acc00[r];
    pr[oi + 16 + lo] = (_Float16)acc01[r];
    size_t oi2 = oi + (size_t)16 * C_;
    pr[oi2 + lo] = (_Float16)acc10[r];
    pr[oi2 + 16 + lo] = (_Float16)acc11[r];
  }
  if (l < 16) {
    prS[((size_t)(nz * 16) + bh) * HW_ + m0 + lo] = rsum0;
    prS[((size_t)(nz * 16) + bh) * HW_ + m0 + 16 + lo] = rsum1;
  }
}

// ---------------- combine + inline LEPE: aoutT[m][c] = bf16(ΣO/Σr + lepe) ----------------
__global__ __launch_bounds__(256) void k_combine2(const _Float16* __restrict__ prOh,
                                                  const float* __restrict__ prS,
                                                  const unsigned short* __restrict__ qbf,
                                                  const float* __restrict__ rpe_w,
                                                  const float* __restrict__ rpe_b,
                                                  unsigned short* __restrict__ aoutT) {
  size_t oi = ((size_t)blockIdx.x * 256 + threadIdx.x) * 4;
  int c = (int)(oi & 127);
  size_t bm = oi >> 7;                 // b*HW + m
  int b = (int)(bm / HW_);
  int m = (int)(bm - (size_t)b * HW_);
  int hd = c >> 5;
  int bh = b * 4 + hd;
  float rs = 0.f;
  float o[4] = {0.f, 0.f, 0.f, 0.f};
#pragma unroll
  for (int nz = 0; nz < 4; nz++) {
    rs += prS[((size_t)(nz * 16) + bh) * HW_ + m];
    f16x4 v = *(const f16x4*)(prOh + (size_t)nz * (B_ * HW_ * C_) + oi);
#pragma unroll
    for (int j = 0; j < 4; j++) o[j] += (float)v[j];
  }
  float inv = 1.0f / rs;
  // LEPE: depthwise 3x3 over q at (h,w), channels c..c+3
  int h = m / W_, w = m - (m / W_) * W_;
  float lp[4] = {rpe_b[c], rpe_b[c + 1], rpe_b[c + 2], rpe_b[c + 3]};
#pragma unroll
  for (int dy = -1; dy <= 1; dy++)
#pragma unroll
    for (int dx = -1; dx <= 1; dx++) {
      int hh = h + dy, ww = w + dx;
      if (hh >= 0 && hh < H_ && ww >= 0 && ww < W_) {
        int idx = (dy + 1) * 3 + (dx + 1);
        ushort4 q4 = *(const ushort4*)(qbf + ((size_t)(b * HW_) + hh * W_ + ww) * C_ + c);
        lp[0] += rpe_w[(c + 0) * 9 + idx] * INVQ_ * bf2f(q4.x);
        lp[1] += rpe_w[(c + 1) * 9 + idx] * INVQ_ * bf2f(q4.y);
        lp[2] += rpe_w[(c + 2) * 9 + idx] * INVQ_ * bf2f(q4.z);
        lp[3] += rpe_w[(c + 3) * 9 + idx] * INVQ_ * bf2f(q4.w);
      }
    }
  ushort4 pk;
  pk.x = f2bf(o[0] * inv + lp[0]);
  pk.y = f2bf(o[1] * inv + lp[1]);
  pk.z = f2bf(o[2] * inv + lp[2]);
  pk.w = f2bf(o[3] * inv + lp[3]);
  *(ushort4*)(aoutT + oi) = pk;
}

// ---------------- o-conv (MFMA): y[c][m] = oW·aoutT + ob ----------------
__global__ __launch_bounds__(256, 4) void k_oconv(const unsigned short* __restrict__ aoutT,
                                                  const unsigned short* __restrict__ wbf,
                                                  const float* __restrict__ ob_,
                                                  float* __restrict__ y) {
  int t = threadIdx.x, w = t >> 6, l = t & 63, lg = l >> 4, lo = l & 15;
  int m0 = blockIdx.x * 16, b = blockIdx.y, o0 = w * 32;
  const unsigned short* xrow = aoutT + ((size_t)(b * HW_) + m0 + lo) * C_ + lg * 8;
  const unsigned short* wo = wbf + 49152;
  f32x4 acc[2] = {{0.f,0.f,0.f,0.f},{0.f,0.f,0.f,0.f}};
#pragma unroll
  for (int kb = 0; kb < 4; kb++) {
    short8 xf = *(const short8*)(xrow + kb * 32);
#pragma unroll
    for (int os = 0; os < 2; os++) {
      short8 wf = *(const short8*)(wo + (size_t)(o0 + os * 16 + lo) * C_ + kb * 32 + lg * 8);
      acc[os] = __builtin_amdgcn_mfma_f32_16x16x32_bf16(wf, xf, acc[os], 0, 0, 0);
    }
  }
#pragma unroll
  for (int os = 0; os < 2; os++)
#pragma unroll
    for (int r = 0; r < 4; r++) {
      int o = o0 + os * 16 + lg * 4 + r;
      y[((size_t)(b * C_) + o) * HW_ + m0 + lo] = acc[os][r] + ob_[o];
    }
}

extern "C" void kernel_launch(void* const* d_in, const int* in_sizes, int n_in,
                              void* d_out, int out_size, void* d_ws, size_t ws_size,
                              hipStream_t stream) {
  const float* x        = (const float*)d_in[0];
  const float* qW       = (const float*)d_in[1];
  const float* qb       = (const float*)d_in[2];
  const float* kW       = (const float*)d_in[3];
  const float* kb       = (const float*)d_in[4];
  const float* vW       = (const float*)d_in[5];
  const float* vb       = (const float*)d_in[6];
  const float* oW       = (const float*)d_in[7];
  const float* ob       = (const float*)d_in[8];
  const float* off_dw_w = (const float*)d_in[9];
  const float* off_dw_b = (const float*)d_in[10];
  const float* ln_g     = (const float*)d_in[11];
  const float* ln_b     = (const float*)d_in[12];
  const float* off_pw_w = (const float*)d_in[13];
  const float* sob_w    = (const float*)d_in[14];
  const float* sob_b    = (const float*)d_in[15];
  const float* rpe_w    = (const float*)d_in[16];
  const float* rpe_b    = (const float*)d_in[17];
  float* out = (float*)d_out;
  float* wsf = (float*)d_ws;
  unsigned short* xTbf  = (unsigned short*)(wsf + OFF_XTBF);
  unsigned short* qbf   = (unsigned short*)(wsf + OFF_QBF);
  unsigned short* kbf   = (unsigned short*)(wsf + OFF_KBF);
  unsigned short* vbf   = (unsigned short*)(wsf + OFF_VBF);
  unsigned short* xsT   = (unsigned short*)(wsf + OFF_XST);
  unsigned short* wbf   = (unsigned short*)(wsf + OFF_WBF);
  unsigned short* aoutT = (unsigned short*)(wsf + OFF_AOUTT);
  float* prS   = wsf + OFF_PRS;
  _Float16* prOh = (_Float16*)(wsf + OFF_PROH);
  double* smapd = (double*)(wsf + OFF_SMAPD);
  double* weff  = (double*)(wsf + OFF_WEFF);

  k_pre          <<<545,             256, 0, stream>>>(x, qW, kW, vW, oW, qb, sob_w, sob_b,
                                                       xTbf, wbf, weff);
  k_qconv_smapd  <<<648,             256, 0, stream>>>(xTbf, wbf, qb, x, weff, qbf, smapd);
  k_offpos_sample<<<4608,            256, 0, stream>>>(qbf, smapd, off_dw_w, off_dw_b,
                                                       ln_g, ln_b, off_pw_w, xTbf, out, xsT);
  k_kvconv       <<<dim3(144, 4),    256, 0, stream>>>(xsT, wbf, kb, vb, kbf, vbf);
  k_attn5        <<<dim3(18, 16, 4), 256, 0, stream>>>(qbf, kbf, vbf, prOh, prS);
  k_combine2     <<<1152,            256, 0, stream>>>(prOh, prS, qbf, rpe_w, rpe_b, aoutT);
  k_oconv        <<<dim3(144, 4),    256, 0, stream>>>(aoutT, wbf, ob, out + Y_OFF);
}

// Round 9
// 119.819 us; speedup vs baseline: 3.5860x; 1.0403x over previous
//
#include <hip/hip_runtime.h>
#include <hip/hip_bf16.h>
#include <math.h>

#define B_   4
#define C_   128
#define H_   48
#define W_   48
#define HW_  2304
#define CG_  64
#define DH_  32
#define SCALE_ 0.17677669529663687f   // 32^-0.5
#define QS_    (0.17677669529663687f * 1.4426950408889634f)  // SCALE * log2(e)
#define INVQ_  (1.0f / QS_)

// d_out layout (floats)
#define Y_OFF   0
#define POS_OFF 1179648
#define REF_OFF 1216512

// workspace layout (float offsets)
#define OFF_XTBF  0         // ushort[4][2304][128]  x^T bf16
#define OFF_QBF   589824    // ushort[4][2304][128]  q*QS bf16 [m][c]
#define OFF_KBF   1179648   // ushort[4][2304][128]  k bf16 [n][c]
#define OFF_VBF   1769472   // ushort[4][128][2304]  v bf16 [c][n] (k-slot permuted per 32-n group)
#define OFF_XST   2359296   // ushort[4][2304][128]  xs bf16 [p][c]
#define OFF_WBF   2949120   // ushort[4][16384]      qW,kW,vW,oW bf16
#define OFF_PRS   2981888   // float[4][16][2304]    partial rowsums
#define OFF_PROH  4161536   // _Float16[4][4·2304·128] partial O (fp16), 2359296 float-space
#define OFF_SMAPD 7184384   // double[8][2304]
#define OFF_WEFF  7221248   // double[258]

typedef __attribute__((ext_vector_type(8))) short short8;
typedef __attribute__((ext_vector_type(4))) float f32x4;
typedef __attribute__((ext_vector_type(4))) _Float16 f16x4;
typedef __attribute__((ext_vector_type(8))) _Float16 f16x8;

__device__ inline unsigned short f2bf(float f) {
  unsigned u = __float_as_uint(f);
  u += 0x7fff + ((u >> 16) & 1);     // RNE
  return (unsigned short)(u >> 16);
}
__device__ inline float bf2f(unsigned short s) {
  return __uint_as_float(((unsigned)s) << 16);
}

// pack 8 f32 -> short8 of bf16 via v_cvt_pk_bf16_f32 (RNE), 4 ops
__device__ inline short8 pack8(const f32x4 a, const f32x4 b) {
  union { unsigned u[4]; short8 s; } r;
  asm("v_cvt_pk_bf16_f32 %0, %1, %2" : "=v"(r.u[0]) : "v"(a[0]), "v"(a[1]));
  asm("v_cvt_pk_bf16_f32 %0, %1, %2" : "=v"(r.u[1]) : "v"(a[2]), "v"(a[3]));
  asm("v_cvt_pk_bf16_f32 %0, %1, %2" : "=v"(r.u[2]) : "v"(b[0]), "v"(b[1]));
  asm("v_cvt_pk_bf16_f32 %0, %1, %2" : "=v"(r.u[3]) : "v"(b[2]), "v"(b[3]));
  return r.s;
}

// ---------------- fused: transpose x -> xTbf (blocks 0..287), weights->bf16 (288..543), weff (544) ----------------
__global__ __launch_bounds__(256) void k_pre(const float* __restrict__ x,
                                             const float* __restrict__ qW, const float* __restrict__ kW,
                                             const float* __restrict__ vW, const float* __restrict__ oW,
                                             const float* __restrict__ qb,
                                             const float* __restrict__ sob_w, const float* __restrict__ sob_b,
                                             unsigned short* __restrict__ xTbf,
                                             unsigned short* __restrict__ wbf,
                                             double* __restrict__ weff) {
  int bx = blockIdx.x;
  if (bx < 288) {
    __shared__ float tile[64][65];
    int p0 = (bx % 36) * 64, c0 = ((bx / 36) & 1) * 64, b = bx / 72;
    for (int idx = threadIdx.x; idx < 4096; idx += 256) {
      int cr = idx >> 6, pc = idx & 63;
      tile[cr][pc] = x[((size_t)(b * C_) + c0 + cr) * HW_ + p0 + pc];
    }
    __syncthreads();
    for (int idx = threadIdx.x; idx < 4096; idx += 256) {
      int pr = idx >> 6, cc = idx & 63;
      xTbf[((size_t)(b * HW_) + p0 + pr) * C_ + c0 + cc] = f2bf(tile[cc][pr]);
    }
  } else if (bx < 544) {
    int t = (bx - 288) * 256 + threadIdx.x;   // 65536
    int which = t >> 14, i = t & 16383;
    const float* src = which == 0 ? qW : which == 1 ? kW : which == 2 ? vW : oW;
    wbf[t] = f2bf(src[i]);
  } else {
    int t = threadIdx.x;
    int g = t >> 7, i = t & 127;
    double acc = 0.0;
    for (int c = 0; c < 64; c++)
      acc += (double)sob_w[c] * (double)qW[(size_t)(g * 64 + c) * C_ + i];
    weff[t] = acc;
    if (t < 2) {
      double bb = (double)sob_b[0];
      for (int c = 0; c < 64; c++) bb += (double)sob_w[c] * (double)qb[t * 64 + c];
      weff[256 + t] = bb;
    }
  }
}

// ---------------- fused: q-conv MFMA (blocks 0..575) + fp64 sobel s-map (576..647) ----------------
__global__ __launch_bounds__(256, 4) void k_qconv_smapd(const unsigned short* __restrict__ xTbf,
                                                        const unsigned short* __restrict__ wbf,
                                                        const float* __restrict__ qb,
                                                        const float* __restrict__ x,
                                                        const double* __restrict__ weff,
                                                        unsigned short* __restrict__ qbf,
                                                        double* __restrict__ smapd) {
  int bx = blockIdx.x;
  if (bx < 576) {
    int t = threadIdx.x, w = t >> 6, l = t & 63, lg = l >> 4, lo = l & 15;
    int m0 = (bx % 144) * 16, b = bx / 144, o0 = w * 32;
    const unsigned short* xrow = xTbf + ((size_t)(b * HW_) + m0 + lo) * C_ + lg * 8;
    f32x4 acc[2] = {{0.f,0.f,0.f,0.f},{0.f,0.f,0.f,0.f}};
#pragma unroll
    for (int kb = 0; kb < 4; kb++) {
      short8 xf = *(const short8*)(xrow + kb * 32);
#pragma unroll
      for (int os = 0; os < 2; os++) {
        short8 wf = *(const short8*)(wbf + (size_t)(o0 + os * 16 + lo) * C_ + kb * 32 + lg * 8);
        acc[os] = __builtin_amdgcn_mfma_f32_16x16x32_bf16(xf, wf, acc[os], 0, 0, 0);
      }
    }
#pragma unroll
    for (int os = 0; os < 2; os++) {
      int o = o0 + os * 16 + lo;
      float bi = qb[o];
#pragma unroll
      for (int r = 0; r < 4; r++) {
        int m = m0 + lg * 4 + r;
        qbf[((size_t)(b * HW_) + m) * C_ + o] = f2bf((acc[os][r] + bi) * QS_);
      }
    }
  } else {
    int bb = bx - 576;
    int p = (bb % 9) * 256 + threadIdx.x;
    int bg = bb / 9;
    int b = bg >> 1, g = bg & 1;
    const float* xb = x + (size_t)b * C_ * HW_ + p;
    const double* wv = weff + g * 128;
    double acc = weff[256 + g];
#pragma unroll 8
    for (int i = 0; i < 128; i++) acc += wv[i] * (double)xb[(size_t)i * HW_];
    smapd[bg * HW_ + p] = acc;
  }
}

// ---------------- fused offset branch + sobel gate + pos/ref + bilinear sample ----------------
__global__ __launch_bounds__(256) void k_offpos_sample(const unsigned short* __restrict__ qbf,
                                                       const double* __restrict__ s_map,
                                                       const float* __restrict__ dw_w,
                                                       const float* __restrict__ dw_b,
                                                       const float* __restrict__ ln_g,
                                                       const float* __restrict__ ln_b,
                                                       const float* __restrict__ pw_w,
                                                       const unsigned short* __restrict__ xTbf,
                                                       float* __restrict__ out,
                                                       unsigned short* __restrict__ xsT) {
  int widx = blockIdx.x * 4 + (threadIdx.x >> 6);
  int lane = threadIdx.x & 63;
  int bg = widx / HW_;
  int p = widx - bg * HW_;
  int h = p / W_, w = p - h * W_;
  int b = bg >> 1, g = bg & 1;
  const unsigned short* qc = qbf + (size_t)(b * HW_) * C_ + g * 64 + lane;
  float tv = dw_b[lane];
#pragma unroll
  for (int dy = -1; dy <= 1; dy++)
#pragma unroll
    for (int dx = -1; dx <= 1; dx++) {
      int hh = h + dy, ww = w + dx;
      if (hh >= 0 && hh < H_ && ww >= 0 && ww < W_) {
        float wgt = dw_w[lane * 9 + (dy + 1) * 3 + (dx + 1)] * INVQ_;
        tv += wgt * bf2f(qc[(size_t)(hh * W_ + ww) * C_]);
      }
    }
  float ssum = tv, ssq = tv * tv;
#pragma unroll
  for (int msk = 32; msk; msk >>= 1) {
    ssum += __shfl_xor(ssum, msk, 64);
    ssq  += __shfl_xor(ssq,  msk, 64);
  }
  float mu  = ssum * (1.0f / 64.0f);
  float var = ssq * (1.0f / 64.0f) - mu * mu;
  float uu  = (tv - mu) * rsqrtf(var + 1e-5f) * ln_g[lane] + ln_b[lane];
  float gl = 0.5f * uu * (1.0f + erff(uu * 0.70710678118654752f));
  float p0 = pw_w[lane] * gl, p1 = pw_w[64 + lane] * gl;
#pragma unroll
  for (int msk = 32; msk; msk >>= 1) {
    p0 += __shfl_xor(p0, msk, 64);
    p1 += __shfl_xor(p1, msk, 64);
  }
  // all lanes now hold full sums; compute gate redundantly (broadcast loads)
  const double sobx[9] = {-1., 0., 1., -2., 0., 2., -1., 0., 1.};
  const double soby[9] = {-1., -2., -1., 0., 0., 0., 1., 2., 1.};
  float off_y = tanhf(p0) * (1.0f / 47.0f);
  float off_x = tanhf(p1) * (1.0f / 47.0f);
  const double* sm = s_map + bg * HW_;
  double gx = 0., gy = 0.;
#pragma unroll
  for (int dy = -1; dy <= 1; dy++)
#pragma unroll
    for (int dx = -1; dx <= 1; dx++) {
      int hh = h + dy, ww = w + dx;
      if (hh >= 0 && hh < H_ && ww >= 0 && ww < W_) {
        double sv = sm[hh * W_ + ww];
        gx += sobx[(dy + 1) * 3 + dx + 1] * sv;
        gy += soby[(dy + 1) * 3 + dx + 1] * sv;
      }
    }
  double mag = sqrt(gx * gx + gy * gy);
  float bin = mag > 0.5 ? 1.0f : 0.0f;
  float ry = ((h + 0.5f) / 47.0f) * 2.0f - 1.0f;
  float rx = ((w + 0.5f) / 47.0f) * 2.0f - 1.0f;
  float py = off_y + ry * bin;
  float px = off_x + rx * bin;
  if (lane == 0) {
    int pi = (bg * HW_ + p) * 2;
    out[POS_OFF + pi]     = py;
    out[POS_OFF + pi + 1] = px;
    out[REF_OFF + pi]     = ry;
    out[REF_OFF + pi + 1] = rx;
  }
  // bilinear sample with in-register pos
  float gxf = (px + 1.0f) * 0.5f * 47.0f;
  float gyf = (py + 1.0f) * 0.5f * 47.0f;
  float x0 = floorf(gxf), y0 = floorf(gyf);
  float wx1 = gxf - x0, wy1 = gyf - y0;
  float wx0 = 1.0f - wx1, wy0 = 1.0f - wy1;
  const unsigned short* base = xTbf + (size_t)(b * HW_) * C_ + g * 64 + lane;
  float acc = 0.0f;
#pragma unroll
  for (int cy = 0; cy < 2; cy++)
#pragma unroll
    for (int cx = 0; cx < 2; cx++) {
      float yy = y0 + (float)cy, xx = x0 + (float)cx;
      bool valid = (yy >= 0.f) && (yy < 48.f) && (xx >= 0.f) && (xx < 48.f);
      int yc = min(max((int)yy, 0), 47);
      int xc = min(max((int)xx, 0), 47);
      float wgt = (cy ? wy1 : wy0) * (cx ? wx1 : wx0);
      float vv = valid ? bf2f(base[(size_t)(yc * 48 + xc) * C_]) : 0.0f;
      acc += wgt * vv;
    }
  xsT[((size_t)(b * HW_) + p) * C_ + g * 64 + lane] = f2bf(acc);
}

// ---------------- k/v conv (MFMA): kbf[n][c]; vbf[c][n] written k-slot-permuted ----------------
__global__ __launch_bounds__(256, 4) void k_kvconv(const unsigned short* __restrict__ xsT,
                                                   const unsigned short* __restrict__ wbf,
                                                   const float* __restrict__ kbias,
                                                   const float* __restrict__ vbias,
                                                   unsigned short* __restrict__ kbf,
                                                   unsigned short* __restrict__ vbf) {
  int t = threadIdx.x, w = t >> 6, l = t & 63, lg = l >> 4, lo = l & 15;
  int n0 = blockIdx.x * 16, b = blockIdx.y, o0 = w * 32;
  const unsigned short* xrow = xsT + ((size_t)(b * HW_) + n0 + lo) * C_ + lg * 8;
  const unsigned short* wk = wbf + 16384;
  const unsigned short* wv = wbf + 32768;
  f32x4 ak[2] = {{0.f,0.f,0.f,0.f},{0.f,0.f,0.f,0.f}};
  f32x4 av[2] = {{0.f,0.f,0.f,0.f},{0.f,0.f,0.f,0.f}};
#pragma unroll
  for (int kb = 0; kb < 4; kb++) {
    short8 xf = *(const short8*)(xrow + kb * 32);
#pragma unroll
    for (int os = 0; os < 2; os++) {
      size_t wo = (size_t)(o0 + os * 16 + lo) * C_ + kb * 32 + lg * 8;
      short8 wkf = *(const short8*)(wk + wo);
      short8 wvf = *(const short8*)(wv + wo);
      ak[os] = __builtin_amdgcn_mfma_f32_16x16x32_bf16(xf, wkf, ak[os], 0, 0, 0);
      av[os] = __builtin_amdgcn_mfma_f32_16x16x32_bf16(wvf, xf, av[os], 0, 0, 0);
    }
  }
  int o32 = (n0 & 16) + lo;
  int vpos = (n0 & ~31) + ((o32 & 12) << 1) + (o32 & 3) + ((o32 >> 4) << 2);
#pragma unroll
  for (int os = 0; os < 2; os++) {
    int ok = o0 + os * 16 + lo;
    float bk_ = kbias[ok];
#pragma unroll
    for (int r = 0; r < 4; r++) {
      int n = n0 + lg * 4 + r;
      kbf[((size_t)(b * HW_) + n) * C_ + ok] = f2bf(ak[os][r] + bk_);
      int ov = o0 + os * 16 + lg * 4 + r;
      vbf[((size_t)(b * C_) + ov) * HW_ + vpos] = f2bf(av[os][r] + vbias[ov]);
    }
  }
}

// ---------------- MFMA flash attention v6: 64 m-rows/wave, 4-stage stagger ----------------
#define EXPROW2(S0, S1, S2, S3, RS)                                                 \
  _Pragma("unroll")                                                                 \
  for (int r = 0; r < 4; r++) {                                                     \
    float e0, e1, e2, e3;                                                           \
    asm("v_exp_f32 %0, %1" : "=v"(e0) : "v"(S0[r]));                                \
    asm("v_exp_f32 %0, %1" : "=v"(e1) : "v"(S1[r]));                                \
    asm("v_exp_f32 %0, %1" : "=v"(e2) : "v"(S2[r]));                                \
    asm("v_exp_f32 %0, %1" : "=v"(e3) : "v"(S3[r]));                                \
    S0[r] = e0; S1[r] = e1; S2[r] = e2; S3[r] = e3;                                 \
    RS += (e0 + e1) + (e2 + e3);                                                    \
  }

#define QKT(BK, AQ, S0, S1, S2, S3)                                                 \
    S0 = __builtin_amdgcn_mfma_f32_16x16x32_bf16(BK[0], AQ, z, 0, 0, 0);            \
    S1 = __builtin_amdgcn_mfma_f32_16x16x32_bf16(BK[1], AQ, z, 0, 0, 0);            \
    S2 = __builtin_amdgcn_mfma_f32_16x16x32_bf16(BK[2], AQ, z, 0, 0, 0);            \
    S3 = __builtin_amdgcn_mfma_f32_16x16x32_bf16(BK[3], AQ, z, 0, 0, 0);

#define PVT(PA0, PA1, AL, AH)                                                       \
    AL = __builtin_amdgcn_mfma_f32_16x16x32_bf16(PA0, bv0, AL, 0, 0, 0);            \
    AL = __builtin_amdgcn_mfma_f32_16x16x32_bf16(PA1, bv1, AL, 0, 0, 0);            \
    AH = __builtin_amdgcn_mfma_f32_16x16x32_bf16(PA0, bv2, AH, 0, 0, 0);            \
    AH = __builtin_amdgcn_mfma_f32_16x16x32_bf16(PA1, bv3, AH, 0, 0, 0);

#define ATTN_BODY6(BK, BKN, DOPREF)                                                 \
  {                                                                                 \
    short8 bv0 = *(const short8*)(vr0 + n0);                                        \
    short8 bv1 = *(const short8*)(vr0 + n0 + 32);                                   \
    short8 bv2 = *(const short8*)(vr1 + n0);                                        \
    short8 bv3 = *(const short8*)(vr1 + n0 + 32);                                   \
    if (DOPREF) {                                                                   \
      _Pragma("unroll")                                                             \
      for (int sub = 0; sub < 4; sub++)                                             \
        BKN[sub] = *(const short8*)(kb_ + (size_t)(n0 + 64 + sub * 16 + lo) * C_);  \
    }                                                                               \
    f32x4 z = {0.f, 0.f, 0.f, 0.f};                                                 \
    f32x4 s0, s1, s2, s3, t0, t1, t2, t3;                                           \
    __builtin_amdgcn_s_setprio(1);                                                  \
    QKT(BK, aq0, s0, s1, s2, s3)                                                    \
    __builtin_amdgcn_s_setprio(0);                                                  \
    EXPROW2(s0, s1, s2, s3, rsv[0])                                                 \
    short8 pa0 = pack8(s0, s1), pa1 = pack8(s2, s3);                                \
    __builtin_amdgcn_s_setprio(1);                                                  \
    QKT(BK, aq1, t0, t1, t2, t3)                                                    \
    PVT(pa0, pa1, aL[0], aH[0])                                                     \
    __builtin_amdgcn_s_setprio(0);                                                  \
    EXPROW2(t0, t1, t2, t3, rsv[1])                                                 \
    short8 pb0 = pack8(t0, t1), pb1 = pack8(t2, t3);                                \
    __builtin_amdgcn_s_setprio(1);                                                  \
    QKT(BK, aq2, s0, s1, s2, s3)                                                    \
    PVT(pb0, pb1, aL[1], aH[1])                                                     \
    __builtin_amdgcn_s_setprio(0);                                                  \
    EXPROW2(s0, s1, s2, s3, rsv[2])                                                 \
    short8 pc0 = pack8(s0, s1), pc1 = pack8(s2, s3);                                \
    __builtin_amdgcn_s_setprio(1);                                                  \
    QKT(BK, aq3, t0, t1, t2, t3)                                                    \
    PVT(pc0, pc1, aL[2], aH[2])                                                     \
    __builtin_amdgcn_s_setprio(0);                                                  \
    EXPROW2(t0, t1, t2, t3, rsv[3])                                                 \
    short8 pd0 = pack8(t0, t1), pd1 = pack8(t2, t3);                                \
    __builtin_amdgcn_s_setprio(1);                                                  \
    PVT(pd0, pd1, aL[3], aH[3])                                                     \
    __builtin_amdgcn_s_setprio(0);                                                  \
    n0 += 64;                                                                       \
  }

__global__ __launch_bounds__(128, 2) void k_attn6(const unsigned short* __restrict__ qbf,
                                                  const unsigned short* __restrict__ kbf,
                                                  const unsigned short* __restrict__ vpf,
                                                  _Float16* __restrict__ prOh,
                                                  float* __restrict__ prS) {
  int t = threadIdx.x, w = t >> 6, l = t & 63, lg = l >> 4, lo = l & 15;
  int bh = blockIdx.y, b = bh >> 2, hd = bh & 3, nz = blockIdx.z;
  int cb = hd * 32;
  int m0 = blockIdx.x * 128 + w * 64;
  const unsigned short* qrow = qbf + ((size_t)(b * HW_) + m0 + lo) * C_ + cb + lg * 8;
  short8 aq0 = *(const short8*)qrow;
  short8 aq1 = *(const short8*)(qrow + (size_t)16 * C_);
  short8 aq2 = *(const short8*)(qrow + (size_t)32 * C_);
  short8 aq3 = *(const short8*)(qrow + (size_t)48 * C_);
  const unsigned short* kb_ = kbf + (size_t)(b * HW_) * C_ + cb + lg * 8;
  const unsigned short* vr0 = vpf + (size_t)(b * C_ + cb + lo) * HW_ + lg * 8;
  const unsigned short* vr1 = vr0 + (size_t)16 * HW_;
  f32x4 aL[4] = {{0.f,0.f,0.f,0.f},{0.f,0.f,0.f,0.f},{0.f,0.f,0.f,0.f},{0.f,0.f,0.f,0.f}};
  f32x4 aH[4] = {{0.f,0.f,0.f,0.f},{0.f,0.f,0.f,0.f},{0.f,0.f,0.f,0.f},{0.f,0.f,0.f,0.f}};
  f32x4 rsv = {0.f, 0.f, 0.f, 0.f};
  int n0 = nz * 576;
  short8 bkA[4], bkB[4];
#pragma unroll
  for (int sub = 0; sub < 4; sub++)
    bkA[sub] = *(const short8*)(kb_ + (size_t)(n0 + sub * 16 + lo) * C_);
  for (int i4 = 0; i4 < 4; i4++) {
    ATTN_BODY6(bkA, bkB, true)
    ATTN_BODY6(bkB, bkA, (i4 < 3))
  }
  ATTN_BODY6(bkA, bkB, false)
#pragma unroll
  for (int qi = 0; qi < 4; qi++) {
    rsv[qi] += __shfl_xor(rsv[qi], 16, 64);
    rsv[qi] += __shfl_xor(rsv[qi], 32, 64);
  }
  _Float16* pr = prOh + (size_t)nz * (B_ * HW_ * C_);
#pragma unroll
  for (int qi = 0; qi < 4; qi++) {
#pragma unroll
    for (int r = 0; r < 4; r++) {
      int m = m0 + qi * 16 + lg * 4 + r;
      size_t oi = ((size_t)(b * HW_) + m) * C_ + cb;
      pr[oi + lo] = (_Float16)aL[qi][r];
      pr[oi + 16 + lo] = (_Float16)aH[qi][r];
    }
  }
  if (l < 16) {
#pragma unroll
    for (int qi = 0; qi < 4; qi++)
      prS[((size_t)(nz * 16) + bh) * HW_ + m0 + qi * 16 + lo] = rsv[qi];
  }
}

// ---------------- fused combine + LEPE + o-conv: y = oW·(ΣO/Σr + lepe) + ob ----------------
__global__ __launch_bounds__(256) void k_out(const _Float16* __restrict__ prOh,
                                             const float* __restrict__ prS,
                                             const unsigned short* __restrict__ qbf,
                                             const float* __restrict__ rpe_w,
                                             const float* __restrict__ rpe_b,
                                             const unsigned short* __restrict__ wbf,
                                             const float* __restrict__ ob_,
                                             float* __restrict__ y) {
  __shared__ __align__(16) unsigned short lds[16][136];
  int t = threadIdx.x;
  int m0 = blockIdx.x * 16, b = blockIdx.y;
  // phase 1: combine partials + LEPE for [16 m][128 c] slab
  {
    int mi = t >> 4, c8 = (t & 15) * 8;
    int m = m0 + mi;
    int hd = c8 >> 5;
    size_t oi = ((size_t)(b * HW_) + m) * C_ + c8;
    float rs = 0.f;
    float o[8] = {0.f,0.f,0.f,0.f,0.f,0.f,0.f,0.f};
#pragma unroll
    for (int nz = 0; nz < 4; nz++) {
      rs += prS[((size_t)(nz * 16) + b * 4 + hd) * HW_ + m];
      f16x8 v = *(const f16x8*)(prOh + (size_t)nz * (B_ * HW_ * C_) + oi);
#pragma unroll
      for (int j = 0; j < 8; j++) o[j] += (float)v[j];
    }
    float inv = 1.0f / rs;
    int h = m / W_, ww0 = m - h * W_;
    float lp[8];
#pragma unroll
    for (int j = 0; j < 8; j++) lp[j] = rpe_b[c8 + j];
#pragma unroll
    for (int dy = -1; dy <= 1; dy++)
#pragma unroll
      for (int dx = -1; dx <= 1; dx++) {
        int hh = h + dy, ww = ww0 + dx;
        if (hh >= 0 && hh < H_ && ww >= 0 && ww < W_) {
          int idx = (dy + 1) * 3 + (dx + 1);
          short8 q8 = *(const short8*)(qbf + ((size_t)(b * HW_) + hh * W_ + ww) * C_ + c8);
#pragma unroll
          for (int j = 0; j < 8; j++)
            lp[j] += rpe_w[(c8 + j) * 9 + idx] * INVQ_ * bf2f((unsigned short)q8[j]);
        }
      }
    short8 res;
#pragma unroll
    for (int j = 0; j < 8; j++) res[j] = (short)f2bf(o[j] * inv + lp[j]);
    *(short8*)&lds[mi][c8] = res;
  }
  __syncthreads();
  // phase 2: o-conv from LDS
  int w = t >> 6, l = t & 63, lg = l >> 4, lo = l & 15;
  int o0 = w * 32;
  const unsigned short* wo = wbf + 49152;
  f32x4 acc[2] = {{0.f,0.f,0.f,0.f},{0.f,0.f,0.f,0.f}};
#pragma unroll
  for (int kb = 0; kb < 4; kb++) {
    short8 xf = *(const short8*)&lds[lo][kb * 32 + lg * 8];
#pragma unroll
    for (int os = 0; os < 2; os++) {
      short8 wf = *(const short8*)(wo + (size_t)(o0 + os * 16 + lo) * C_ + kb * 32 + lg * 8);
      acc[os] = __builtin_amdgcn_mfma_f32_16x16x32_bf16(wf, xf, acc[os], 0, 0, 0);
    }
  }
#pragma unroll
  for (int os = 0; os < 2; os++)
#pragma unroll
    for (int r = 0; r < 4; r++) {
      int o = o0 + os * 16 + lg * 4 + r;
      y[((size_t)(b * C_) + o) * HW_ + m0 + lo] = acc[os][r] + ob_[o];
    }
}

extern "C" void kernel_launch(void* const* d_in, const int* in_sizes, int n_in,
                              void* d_out, int out_size, void* d_ws, size_t ws_size,
                              hipStream_t stream) {
  const float* x        = (const float*)d_in[0];
  const float* qW       = (const float*)d_in[1];
  const float* qb       = (const float*)d_in[2];
  const float* kW       = (const float*)d_in[3];
  const float* kb       = (const float*)d_in[4];
  const float* vW       = (const float*)d_in[5];
  const float* vb       = (const float*)d_in[6];
  const float* oW       = (const float*)d_in[7];
  const float* ob       = (const float*)d_in[8];
  const float* off_dw_w = (const float*)d_in[9];
  const float* off_dw_b = (const float*)d_in[10];
  const float* ln_g     = (const float*)d_in[11];
  const float* ln_b     = (const float*)d_in[12];
  const float* off_pw_w = (const float*)d_in[13];
  const float* sob_w    = (const float*)d_in[14];
  const float* sob_b    = (const float*)d_in[15];
  const float* rpe_w    = (const float*)d_in[16];
  const float* rpe_b    = (const float*)d_in[17];
  float* out = (float*)d_out;
  float* wsf = (float*)d_ws;
  unsigned short* xTbf  = (unsigned short*)(wsf + OFF_XTBF);
  unsigned short* qbf   = (unsigned short*)(wsf + OFF_QBF);
  unsigned short* kbf   = (unsigned short*)(wsf + OFF_KBF);
  unsigned short* vbf   = (unsigned short*)(wsf + OFF_VBF);
  unsigned short* xsT   = (unsigned short*)(wsf + OFF_XST);
  unsigned short* wbf   = (unsigned short*)(wsf + OFF_WBF);
  float* prS   = wsf + OFF_PRS;
  _Float16* prOh = (_Float16*)(wsf + OFF_PROH);
  double* smapd = (double*)(wsf + OFF_SMAPD);
  double* weff  = (double*)(wsf + OFF_WEFF);

  k_pre          <<<545,             256, 0, stream>>>(x, qW, kW, vW, oW, qb, sob_w, sob_b,
                                                       xTbf, wbf, weff);
  k_qconv_smapd  <<<648,             256, 0, stream>>>(xTbf, wbf, qb, x, weff, qbf, smapd);
  k_offpos_sample<<<4608,            256, 0, stream>>>(qbf, smapd, off_dw_w, off_dw_b,
                                                       ln_g, ln_b, off_pw_w, xTbf, out, xsT);
  k_kvconv       <<<dim3(144, 4),    256, 0, stream>>>(xsT, wbf, kb, vb, kbf, vbf);
  k_attn6        <<<dim3(18, 16, 4), 128, 0, stream>>>(qbf, kbf, vbf, prOh, prS);
  k_out          <<<dim3(144, 4),    256, 0, stream>>>(prOh, prS, qbf, rpe_w, rpe_b,
                                                       wbf, ob, out + Y_OFF);
}